// Round 9
// baseline (1352.828 us; speedup 1.0000x reference)
//
#include <hip/hip_runtime.h>
#include <cmath>

#define B_   128
#define N_   39
#define KNN_ 10
#define H_   256
#define K1_  32
#define K2_  26
#define K3_  21

static inline int cdiv(int a, int b) { return (a + b - 1) / b; }

typedef __attribute__((ext_vector_type(8))) short short8;
typedef __attribute__((ext_vector_type(4))) float floatx4;

__device__ inline short f2b(float f) {   // fp32 -> bf16 RNE
  unsigned u = __float_as_uint(f);
  u += 0x7fff + ((u >> 16) & 1);
  return (short)(u >> 16);
}
__device__ inline float b2f(short h) {
  return __uint_as_float(((unsigned)(unsigned short)h) << 16);
}
__device__ inline void f2b2(float v, short& hi, short& lo) {  // split: v ~= hi + lo
  hi = f2b(v);
  lo = f2b(v - b2f(hi));
}

// ---------- wave-wide argmax/argmin (64 lanes), ties -> lowest index ----------
__device__ inline void wave_argmax64(float& v, int& j) {
#pragma unroll
  for (int off = 32; off; off >>= 1) {
    float ov = __shfl_down(v, off, 64);
    int   oj = __shfl_down(j, off, 64);
    if (ov > v || (ov == v && oj < j)) { v = ov; j = oj; }
  }
  v = __shfl(v, 0, 64);
  j = __shfl(j, 0, 64);
}
__device__ inline void wave_argmin64(float& v, int& j) {
#pragma unroll
  for (int off = 32; off; off >>= 1) {
    float ov = __shfl_down(v, off, 64);
    int   oj = __shfl_down(j, off, 64);
    if (ov < v || (ov == v && oj < j)) { v = ov; j = oj; }
  }
  v = __shfl(v, 0, 64);
  j = __shfl(j, 0, 64);
}

// ---------------- one-shot weight prep + degree (7 tasks on blockIdx.y) ----------------
__global__ void prep_kernel(const float* __restrict__ w1, const float* __restrict__ w2,
                            const float* __restrict__ w3, const float* __restrict__ w6,
                            const float* __restrict__ l4, const float* __restrict__ l5,
                            const float* __restrict__ adj,
                            float* __restrict__ wcat1, float* __restrict__ wcat2,
                            float* __restrict__ wcat3,
                            short* __restrict__ w2h, short* __restrict__ w2l,
                            short* __restrict__ w3h, short* __restrict__ w3l,
                            short* __restrict__ w6h, short* __restrict__ w6l,
                            short* __restrict__ l4h, short* __restrict__ l4l,
                            short* __restrict__ l5h, short* __restrict__ l5l,
                            float* __restrict__ deg) {
  int task = blockIdx.y;
  int t = blockIdx.x * 256 + threadIdx.x;
  if (task == 0) {                        // wcat1 fp32 only (F=39, Hc=256)
    if (t >= 39 * 512) return;
    int k = t >> 9, c = t & 511;
    wcat1[t] = (c < 256) ? w1[k * 256 + c] - w1[(39 + k) * 256 + c]
                         : w1[(39 + k) * 256 + (c - 256)];
  } else if (task == 1) {                 // wcat2 fp32 + splitT (F=256, Hc=256)
    if (t >= 256 * 512) return;
    int k = t >> 9, c = t & 511;
    float v = (c < 256) ? w2[k * 256 + c] - w2[(256 + k) * 256 + c]
                        : w2[(256 + k) * 256 + (c - 256)];
    wcat2[t] = v;
    short hi, lo; f2b2(v, hi, lo);
    w2h[(size_t)c * 256 + k] = hi; w2l[(size_t)c * 256 + k] = lo;
  } else if (task == 2) {                 // wcat3 fp32 + splitT
    if (t >= 256 * 512) return;
    int k = t >> 9, c = t & 511;
    float v = (c < 256) ? w3[k * 256 + c] - w3[(256 + k) * 256 + c]
                        : w3[(256 + k) * 256 + (c - 256)];
    wcat3[t] = v;
    short hi, lo; f2b2(v, hi, lo);
    w3h[(size_t)c * 256 + k] = hi; w3l[(size_t)c * 256 + k] = lo;
  } else if (task == 3) {                 // wcat6 splitT only (F=256, Hc=39)
    if (t >= 256 * 78) return;
    int k = t / 78, c = t - k * 78;
    float v = (c < 39) ? w6[k * 39 + c] - w6[(256 + k) * 39 + c]
                       : w6[(256 + k) * 39 + (c - 39)];
    short hi, lo; f2b2(v, hi, lo);
    w6h[(size_t)c * 256 + k] = hi; w6l[(size_t)c * 256 + k] = lo;
  } else if (task == 4) {                 // lin4 splitT (256 x 256)
    if (t >= 256 * 256) return;
    int k = t >> 8, n = t & 255;
    short hi, lo; f2b2(l4[t], hi, lo);
    l4h[(size_t)n * 256 + k] = hi; l4l[(size_t)n * 256 + k] = lo;
  } else if (task == 5) {                 // lin5 splitT (256 x 128)
    if (t >= 256 * 128) return;
    int k = t >> 7, n = t & 127;
    short hi, lo; f2b2(l5[t], hi, lo);
    l5h[(size_t)n * 256 + k] = hi; l5l[(size_t)n * 256 + k] = lo;
  } else {                                // degree
    if (t >= B_ * N_) return;
    const float* row = adj + (size_t)t * N_;
    float s = 0.f;
    for (int j = 0; j < N_; ++j) s += row[j];
    deg[t] = s;
  }
}

// ---------------- quad KNN: one wave per 4 output rows ----------------
// lane j holds column j: loads xj once (divergent, L1-hot) and dots it against
// 4 wave-uniform xi rows (broadcast loads). Per-row accumulation order identical
// to the previous per-row kernel -> bitwise-identical distances & tie behavior.
__global__ __launch_bounds__(256) void knn_quad_kernel(const float* __restrict__ x,
                                                       int n, int F, int n_graphs,
                                                       int* __restrict__ idx) {
  int w = (blockIdx.x * blockDim.x + threadIdx.x) >> 6;
  int lane = threadIdx.x & 63;
  int qpg = (n + 3) >> 2;
  if (w >= n_graphs * qpg) return;
  int b = w / qpg, q = w - b * qpg;
  int i0 = q * 4;
  int nr = n - i0; if (nr > 4) nr = 4;
  const float* xb = x + (size_t)b * n * F;
  int jr = (lane < n) ? lane : 0;
  const float* xj = xb + (size_t)jr * F;
  const float* xi[4];
#pragma unroll
  for (int r = 0; r < 4; ++r) {
    int row = i0 + r; if (row >= n) row = n - 1;   // clamp: avoid OOB, values unused
    xi[r] = xb + (size_t)row * F;
  }
  float d0[4] = {0.f, 0.f, 0.f, 0.f}, d1[4] = {0.f, 0.f, 0.f, 0.f};
  float s0 = 0.f, s1 = 0.f;
  if ((F & 7) == 0) {
    for (int f = 0; f < F; f += 8) {
      float4 b0 = *(const float4*)&xj[f];
      float4 b1 = *(const float4*)&xj[f + 4];
      s0 += b0.x * b0.x + b0.y * b0.y + b0.z * b0.z + b0.w * b0.w;
      s1 += b1.x * b1.x + b1.y * b1.y + b1.z * b1.z + b1.w * b1.w;
#pragma unroll
      for (int r = 0; r < 4; ++r) {
        float4 a0 = *(const float4*)&xi[r][f];
        float4 a1 = *(const float4*)&xi[r][f + 4];
        d0[r] += a0.x * b0.x + a0.y * b0.y + a0.z * b0.z + a0.w * b0.w;
        d1[r] += a1.x * b1.x + a1.y * b1.y + a1.z * b1.z + a1.w * b1.w;
      }
    }
  } else {
    for (int f = 0; f < F; ++f) {
      float bv = xj[f];
      s0 += bv * bv;
#pragma unroll
      for (int r = 0; r < 4; ++r) d0[r] += xi[r][f] * bv;
    }
  }
  float sq = s0 + s1;
#pragma unroll
  for (int r = 0; r < 4; ++r) {
    if (r >= nr) break;
    float sqi = __shfl(sq, i0 + r, 64);
    float d = (lane < n) ? (sqi + sq - 2.f * (d0[r] + d1[r])) : INFINITY;
    int* outp = idx + (size_t)(b * n + i0 + r) * KNN_;
    for (int kk = 0; kk < KNN_; ++kk) {
      float rv = d;
      int rj = (lane < n) ? lane : (1 << 20);
      wave_argmin64(rv, rj);
      if (lane == 0) outp[kk] = rj;
      if (lane == rj) d = INFINITY;
    }
  }
}

// ---------------- fp32 trunk GEMM: 64x64 tile, register-staged pipeline ----------------
#define BM 64
#define BN 64
#define BK 16
__global__ __launch_bounds__(256) void gemm_kernel(
    const float* __restrict__ A, const float* __restrict__ W, const float* __restrict__ bias,
    float* __restrict__ C, int M, int N, int K, int act) {
  __shared__ float As[BK][BM + 4];
  __shared__ float Bs[BK][BN + 4];
  int tid = threadIdx.x;
  int tx = tid & 15, ty = tid >> 4;
  int row0 = blockIdx.y * BM, col0 = blockIdx.x * BN;
  float c[4][4] = {};
  float ra[4], rb[4];
#pragma unroll
  for (int v = 0; v < 4; ++v) {
    int e = tid + v * 256;
    int m = e >> 4, kk = e & 15;
    int row = row0 + m;
    ra[v] = (row < M && kk < K) ? A[(size_t)row * K + kk] : 0.f;
    int kk2 = e >> 6, nn = e & 63;
    int col = col0 + nn;
    rb[v] = (kk2 < K && col < N) ? W[(size_t)kk2 * N + col] : 0.f;
  }
  for (int k0 = 0; k0 < K; k0 += BK) {
#pragma unroll
    for (int v = 0; v < 4; ++v) {
      int e = tid + v * 256;
      As[e & 15][e >> 4] = ra[v];
      Bs[e >> 6][e & 63] = rb[v];
    }
    __syncthreads();
    int k1 = k0 + BK;
    if (k1 < K) {
#pragma unroll
      for (int v = 0; v < 4; ++v) {
        int e = tid + v * 256;
        int m = e >> 4, kk = e & 15;
        int row = row0 + m, k = k1 + kk;
        ra[v] = (row < M && k < K) ? A[(size_t)row * K + k] : 0.f;
        int kk2 = e >> 6, nn = e & 63;
        int k2 = k1 + kk2, col = col0 + nn;
        rb[v] = (k2 < K && col < N) ? W[(size_t)k2 * N + col] : 0.f;
      }
    }
#pragma unroll
    for (int kk = 0; kk < BK; ++kk) {
      float4 av = *(const float4*)&As[kk][ty * 4];
      float4 bv = *(const float4*)&Bs[kk][tx * 4];
      float a[4] = {av.x, av.y, av.z, av.w};
      float b[4] = {bv.x, bv.y, bv.z, bv.w};
#pragma unroll
      for (int i2 = 0; i2 < 4; ++i2)
#pragma unroll
        for (int j = 0; j < 4; ++j) c[i2][j] += a[i2] * b[j];
    }
    __syncthreads();
  }
#pragma unroll
  for (int i2 = 0; i2 < 4; ++i2) {
    int row = row0 + ty * 4 + i2;
    if (row >= M) continue;
#pragma unroll
    for (int j = 0; j < 4; ++j) {
      int col = col0 + tx * 4 + j;
      if (col >= N) continue;
      float v = c[i2][j] + (bias ? bias[col] : 0.f);
      if (act == 1) v = fmaxf(v, 0.f);
      C[(size_t)row * N + col] = v;
    }
  }
}

// ------------- split-bf16 3-pass MFMA GEMM (near-fp32 accuracy, ~2^-16 rel) -------------
__global__ __launch_bounds__(256) void mfma_gemm_split_kernel(
    const short* __restrict__ Ah, const short* __restrict__ Al,
    const short* __restrict__ Wth, const short* __restrict__ Wtl,
    const float* __restrict__ bias,
    float* __restrict__ C, short* __restrict__ Ch, short* __restrict__ Cl,
    int M, int N, int K, int act) {
  __shared__ short Ash[128 * 40];
  __shared__ short Asl[128 * 40];
  __shared__ short Bsh[128 * 40];
  __shared__ short Bsl[128 * 40];
  int tid = threadIdx.x;
  int wave = tid >> 6, lane = tid & 63;
  int wm = wave & 1, wn = wave >> 1;
  int row0 = blockIdx.y * 128, col0 = blockIdx.x * 128;
  floatx4 acc[4][4] = {};
  int lm = lane & 15, lk = (lane >> 4) * 8;
  for (int k0 = 0; k0 < K; k0 += 32) {
    for (int c = tid; c < 512; c += 256) {
      int r = c >> 2, kc = (c & 3) * 8;
      int grow = row0 + r;
      short8 vh = {}, vl = {};
      if (grow < M) {
        vh = *(const short8*)&Ah[(size_t)grow * K + k0 + kc];
        vl = *(const short8*)&Al[(size_t)grow * K + k0 + kc];
      }
      *(short8*)&Ash[r * 40 + kc] = vh;
      *(short8*)&Asl[r * 40 + kc] = vl;
    }
    for (int c = tid; c < 512; c += 256) {
      int r = c >> 2, kc = (c & 3) * 8;
      int gn = col0 + r;
      short8 vh = {}, vl = {};
      if (gn < N) {
        vh = *(const short8*)&Wth[(size_t)gn * K + k0 + kc];
        vl = *(const short8*)&Wtl[(size_t)gn * K + k0 + kc];
      }
      *(short8*)&Bsh[r * 40 + kc] = vh;
      *(short8*)&Bsl[r * 40 + kc] = vl;
    }
    __syncthreads();
    short8 afh[4], afl[4], bfh[4], bfl[4];
#pragma unroll
    for (int mi = 0; mi < 4; ++mi) {
      int ro = (wm * 64 + mi * 16 + lm) * 40 + lk;
      afh[mi] = *(const short8*)&Ash[ro];
      afl[mi] = *(const short8*)&Asl[ro];
    }
#pragma unroll
    for (int ni = 0; ni < 4; ++ni) {
      int ro = (wn * 64 + ni * 16 + lm) * 40 + lk;
      bfh[ni] = *(const short8*)&Bsh[ro];
      bfl[ni] = *(const short8*)&Bsl[ro];
    }
#pragma unroll
    for (int mi = 0; mi < 4; ++mi)
#pragma unroll
      for (int ni = 0; ni < 4; ++ni) {
        acc[mi][ni] = __builtin_amdgcn_mfma_f32_16x16x32_bf16(afh[mi], bfh[ni], acc[mi][ni], 0, 0, 0);
        acc[mi][ni] = __builtin_amdgcn_mfma_f32_16x16x32_bf16(afh[mi], bfl[ni], acc[mi][ni], 0, 0, 0);
        acc[mi][ni] = __builtin_amdgcn_mfma_f32_16x16x32_bf16(afl[mi], bfh[ni], acc[mi][ni], 0, 0, 0);
      }
    __syncthreads();
  }
  int lr = (lane >> 4) * 4;
#pragma unroll
  for (int mi = 0; mi < 4; ++mi)
#pragma unroll
    for (int ni = 0; ni < 4; ++ni) {
      int colg = col0 + wn * 64 + ni * 16 + lm;
      if (colg >= N) continue;
      float bv = bias ? bias[colg] : 0.f;
#pragma unroll
      for (int r = 0; r < 4; ++r) {
        int rowg = row0 + wm * 64 + mi * 16 + lr + r;
        if (rowg >= M) continue;
        float v = acc[mi][ni][r] + bv;
        if (act == 1) v = fmaxf(v, 0.f);
        C[(size_t)rowg * N + colg] = v;
        if (Ch) {
          short hi, lo;
          f2b2(v, hi, lo);
          Ch[(size_t)rowg * N + colg] = hi;
          Cl[(size_t)rowg * N + colg] = lo;
        }
      }
    }
}

// Thin GEMM (small M): one block per row.
__global__ __launch_bounds__(256) void rowgemm_kernel(
    const float* __restrict__ A, const float* __restrict__ W, const float* __restrict__ bias,
    float* __restrict__ C, int N, int K, int act) {
  __shared__ float a[512];
  int row = blockIdx.x;
  for (int k = threadIdx.x; k < K; k += 256) a[k] = A[(size_t)row * K + k];
  __syncthreads();
  for (int c = threadIdx.x; c < N; c += 256) {
    float s = 0.f;
    for (int k = 0; k < K; k += 4) {
      float4 av = *(const float4*)&a[k];
      s += av.x * W[(size_t)k * N + c];
      s += av.y * W[(size_t)(k + 1) * N + c];
      s += av.z * W[(size_t)(k + 2) * N + c];
      s += av.w * W[(size_t)(k + 3) * N + c];
    }
    float v = s + (bias ? bias[c] : 0.f);
    if (act == 1) v = fmaxf(v, 0.f);
    C[(size_t)row * N + c] = v;
  }
}

// one wave per output element (for very small M*N)
__global__ void wavedot_gemm_kernel(const float* __restrict__ A, const float* __restrict__ W,
                                    const float* __restrict__ bias, float* __restrict__ C,
                                    int M, int N, int K, int act) {
  int wid = (blockIdx.x * blockDim.x + threadIdx.x) >> 6;
  int lane = threadIdx.x & 63;
  if (wid >= M * N) return;
  int row = wid / N, col = wid - row * N;
  const float* ar = A + (size_t)row * K;
  float s = 0.f;
  for (int k = lane; k < K; k += 64) s += ar[k] * W[(size_t)k * N + col];
  for (int off = 32; off; off >>= 1) s += __shfl_down(s, off, 64);
  if (lane == 0) {
    float v = s + (bias ? bias[col] : 0.f);
    if (act == 1) v = fmaxf(v, 0.f);
    C[(size_t)row * N + col] = v;
  }
}

// AB row r: [0..Hc) = xi@(Wt-Wb), [Hc..2Hc) = xi@Wb.  out = max_k relu(Ai + b + Bm[nbr]) [tanh]
__global__ void edge_agg_kernel(const float* __restrict__ AB, const float* __restrict__ bias,
                                const int* __restrict__ idx, int n, int Hc, int act,
                                float* __restrict__ out,
                                short* __restrict__ outh, short* __restrict__ outl) {
  int t = blockIdx.x * blockDim.x + threadIdx.x;
  if (t >= B_ * n * Hc) return;
  int r = t / Hc, h = t - r * Hc;
  int b = r / n;
  int s2 = 2 * Hc;
  float av = AB[(size_t)r * s2 + h] + bias[h];
  const int* ir = idx + (size_t)r * KNN_;
  int base = b * n;
  float m = -INFINITY;
  for (int k = 0; k < KNN_; ++k) {
    float v = av + AB[(size_t)(base + ir[k]) * s2 + Hc + h];
    v = fmaxf(v, 0.f);
    m = fmaxf(m, v);
  }
  if (act == 2) m = tanhf(m);
  out[t] = m;
  if (outh) {
    short hi, lo;
    f2b2(m, hi, lo);
    outh[t] = hi;
    outl[t] = lo;
  }
}

__global__ void bn_stats_kernel(const float* __restrict__ x, int M, float* __restrict__ mv) {
  int c = blockIdx.x;
  double s = 0.0, s2 = 0.0;
  for (int r = threadIdx.x; r < M; r += 256) {
    double v = (double)x[(size_t)r * H_ + c];
    s += v; s2 += v * v;
  }
  __shared__ double sh[256], sh2[256];
  sh[threadIdx.x] = s; sh2[threadIdx.x] = s2;
  __syncthreads();
  for (int o = 128; o; o >>= 1) {
    if (threadIdx.x < o) { sh[threadIdx.x] += sh[threadIdx.x + o]; sh2[threadIdx.x] += sh2[threadIdx.x + o]; }
    __syncthreads();
  }
  if (threadIdx.x == 0) {
    double mean = sh[0] / M;
    double var = sh2[0] / M - mean * mean;
    mv[c] = (float)mean;
    mv[H_ + c] = (float)var;
  }
}

__global__ void bn_apply_kernel(const float* __restrict__ x, const float* __restrict__ mv,
                                const float* __restrict__ g, const float* __restrict__ bb,
                                int M, float* __restrict__ out) {
  int t = blockIdx.x * blockDim.x + threadIdx.x;
  if (t >= M * H_) return;
  int h = t & (H_ - 1);
  float mean = mv[h], var = mv[H_ + h];
  float v = (x[t] - mean) * (1.f / sqrtf(var + 1e-5f)) * g[h] + bb[h];
  out[t] = fmaxf(v, 0.f);
}

// one wave per row: y[r] = dot(x[r,:K], w) [+bias] [relu]
__global__ void rowdot_kernel(const float* __restrict__ x, const float* __restrict__ w,
                              int M, int K, const float* __restrict__ bias, int act,
                              float* __restrict__ y) {
  int wid = (blockIdx.x * blockDim.x + threadIdx.x) >> 6;
  int lane = threadIdx.x & 63;
  if (wid >= M) return;
  const float* xr = x + (size_t)wid * K;
  float s = 0.f;
  for (int k = lane; k < K; k += 64) s += xr[k] * w[k];
  for (int off = 32; off; off >>= 1) s += __shfl_down(s, off, 64);
  if (lane == 0) {
    float v = s + (bias ? bias[0] : 0.f);
    if (act == 1) v = fmaxf(v, 0.f);
    y[wid] = v;
  }
}

// ---------------- fused SAG pool: rowdot + gcn score + topk + gather (block per graph) ----------------
__global__ __launch_bounds__(256) void sag_kernel(
    const float* __restrict__ h, const float* __restrict__ adj_in, int n, int k,
    const float* __restrict__ pw, const float* __restrict__ pb,
    int* __restrict__ perm, float* __restrict__ xp, float* __restrict__ adjp) {
  __shared__ float ys[40], dinv[40], sc[40], topv[40];
  __shared__ int locs[40];
  int b = blockIdx.x;
  int wave = threadIdx.x >> 6, lane = threadIdx.x & 63;
  // rowdot: y[i] = h[b,i,:] . pw
  for (int i = wave; i < n; i += 4) {
    const float* xr = h + (size_t)(b * n + i) * H_;
    float s = 0.f;
    for (int kk = lane; kk < H_; kk += 64) s += xr[kk] * pw[kk];
    for (int off = 32; off; off >>= 1) s += __shfl_down(s, off, 64);
    if (lane == 0) ys[i] = s;
  }
  __syncthreads();
  int i = threadIdx.x;
  if (i < n) {
    const float* ar = adj_in + ((size_t)b * n + i) * n;
    float sum = 1.f;
    for (int j = 0; j < n; ++j) sum += ar[j];
    dinv[i] = 1.f / sqrtf(sum);
  }
  __syncthreads();
  if (i < n) {
    const float* ar = adj_in + ((size_t)b * n + i) * n;
    float acc = 0.f;
    for (int j = 0; j < n; ++j) {
      float a = ar[j] + (i == j ? 1.f : 0.f);
      acc += a * dinv[j] * ys[j];
    }
    sc[i] = dinv[i] * acc + pb[0];
  }
  __syncthreads();
  if (wave == 0) {
    float cur = (lane < n) ? sc[lane] : -INFINITY;
    for (int t = 0; t < k; ++t) {
      float rv = cur;
      int rj = (lane < n) ? lane : (1 << 20);
      wave_argmax64(rv, rj);
      if (lane == 0) { topv[t] = rv; locs[t] = rj; perm[b * k + t] = b * n + rj; }
      if (lane == rj) cur = -INFINITY;
    }
  }
  __syncthreads();
  for (int e = threadIdx.x; e < k * H_; e += 256) {
    int r = e >> 8, hh = e & 255;
    xp[((size_t)b * k + r) * H_ + hh] =
        h[((size_t)(b * n + locs[r])) * H_ + hh] * tanhf(topv[r]);
  }
  if (adjp) {
    for (int e = threadIdx.x; e < k * k; e += 256) {
      int t1 = e / k, t2 = e - t1 * k;
      adjp[(size_t)b * k * k + e] = adj_in[((size_t)b * n + locs[t1]) * n + locs[t2]];
    }
  }
}

// dst[i1[i2[r]] or i1[r]] = src[r]; fp32 + split-bf16 (all pre-zeroed)
__global__ void scatter_kernel(const float* __restrict__ src, const int* __restrict__ i1,
                               const int* __restrict__ i2, int rows,
                               float* __restrict__ dst,
                               short* __restrict__ dsth, short* __restrict__ dstl) {
  int t = blockIdx.x * blockDim.x + threadIdx.x;
  if (t >= rows * H_) return;
  int r = t / H_, h = t - r * H_;
  int tgt = i2 ? i1[i2[r]] : i1[r];
  float v = src[t];
  dst[(size_t)tgt * H_ + h] = v;
  short hi, lo;
  f2b2(v, hi, lo);
  dsth[(size_t)tgt * H_ + h] = hi;
  dstl[(size_t)tgt * H_ + h] = lo;
}

__global__ void gtpred_kernel(const float* __restrict__ deg, const float* __restrict__ xdeg,
                              const int* __restrict__ perm, int M,
                              float* __restrict__ gt, float* __restrict__ pred) {
  int t = blockIdx.x * blockDim.x + threadIdx.x;
  if (t >= M) return;
  int p = perm[t];
  gt[t] = deg[p];
  pred[t] = xdeg[p];
}

__global__ void readout_kernel(const float* __restrict__ xp, int k, int acc, float* __restrict__ z) {
  int t = blockIdx.x * blockDim.x + threadIdx.x;
  if (t >= B_ * H_) return;
  int b = t / H_, h = t - b * H_;
  float mx = -INFINITY, sm = 0.f;
  for (int tt = 0; tt < k; ++tt) {
    float v = xp[((size_t)b * k + tt) * H_ + h];
    mx = fmaxf(mx, v);
    sm += v;
  }
  float* zb = z + (size_t)b * 2 * H_;
  float mean = sm / (float)k;
  if (acc) { zb[h] += mx; zb[H_ + h] += mean; }
  else     { zb[h] = mx;  zb[H_ + h] = mean; }
}

__global__ void softmax2_kernel(const float* __restrict__ logits, float* __restrict__ probs) {
  int b = blockIdx.x * blockDim.x + threadIdx.x;
  if (b >= B_) return;
  float a = logits[2 * b], c = logits[2 * b + 1];
  float m = fmaxf(a, c);
  float ea = expf(a - m), ec = expf(c - m);
  float inv = 1.f / (ea + ec);
  probs[2 * b] = ea * inv;
  probs[2 * b + 1] = ec * inv;
}

extern "C" void kernel_launch(void* const* d_in, const int* in_sizes, int n_in,
                              void* d_out, int out_size, void* d_ws, size_t ws_size,
                              hipStream_t stream) {
  auto in = [&](int i) { return (const float*)d_in[i]; };
  const float* x      = in(0);
  const float* adj    = in(1);
  const float* w_mlp1 = in(2);  const float* b_mlp1 = in(3);
  const float* w_mlp2 = in(4);  const float* b_mlp2 = in(5);
  const float* w_mlp3 = in(6);  const float* b_mlp3 = in(7);
  const float* w_mlp6 = in(8);  const float* b_mlp6 = in(9);
  const float* bn1_g = in(10);  const float* bn1_b = in(11);
  const float* bn2_g = in(12);  const float* bn2_b = in(13);
  const float* bn3_g = in(14);  const float* bn3_b = in(15);
  const float* p1_w = in(16);   const float* p1_b = in(17);
  const float* p2_w = in(18);   const float* p2_b = in(19);
  const float* p3_w = in(20);   const float* p3_b = in(21);
  const float* lin1_w = in(22); const float* lin1_b = in(23);
  const float* lin2_w = in(24); const float* lin2_b = in(25);
  const float* lin3_w = in(26); const float* lin3_b = in(27);
  const float* lin4_w = in(28); const float* lin4_b = in(29);
  const float* lin5_w = in(30); const float* lin5_b = in(31);
  const float* lin6_w = in(32); const float* lin6_b = in(33);

  float* out = (float*)d_out;
  float* out_probs = out;                      // 128*2
  float* out_dec1  = out_probs + 256;          // 4992*39
  float* out_dec2  = out_dec1 + 4992 * 39;
  float* out_dec3  = out_dec2 + 4992 * 39;
  float* out_gt1   = out_dec3 + 4992 * 39;     // 4096
  float* out_pred1 = out_gt1 + 4096;           // 4096
  float* out_gt2   = out_pred1 + 4096;         // 3328
  float* out_pred2 = out_gt2 + 3328;
  float* out_gt3   = out_pred2 + 3328;         // 2688
  float* out_pred3 = out_gt3 + 2688;

  char* base = (char*)d_ws;
  size_t off = 0;
  auto allocf = [&](size_t n) -> float* {
    float* p = (float*)(base + off);
    off += ((n * sizeof(float) + 255) & ~(size_t)255);
    return p;
  };
  auto alloci = [&](size_t n) -> int* {
    int* p = (int*)(base + off);
    off += ((n * sizeof(int) + 255) & ~(size_t)255);
    return p;
  };
  auto allocs = [&](size_t n) -> short* {
    short* p = (short*)(base + off);
    off += ((n * sizeof(short) + 255) & ~(size_t)255);
    return p;
  };

  float* wcat1 = allocf(39 * 512);
  float* wcat2 = allocf(256 * 512);
  float* wcat3 = allocf(256 * 512);
  short* wcat2t_h = allocs(512 * 256); short* wcat2t_l = allocs(512 * 256);
  short* wcat3t_h = allocs(512 * 256); short* wcat3t_l = allocs(512 * 256);
  short* wcat6t_h = allocs(78 * 256);  short* wcat6t_l = allocs(78 * 256);
  short* lin4t_h  = allocs(256 * 256); short* lin4t_l  = allocs(256 * 256);
  short* lin5t_h  = allocs(128 * 256); short* lin5t_l  = allocs(128 * 256);
  float* deg   = allocf(4992);
  float* xdeg  = allocf(4992);
  int*   idxb  = alloci(4992 * KNN_);
  float* AB    = allocf((size_t)4992 * 512);
  float* t1    = allocf((size_t)4992 * 256);
  float* t2    = allocf((size_t)4992 * 256);
  float* hbuf  = allocf((size_t)4992 * 256);
  float* xp    = allocf((size_t)4096 * 256);
  size_t ms0 = off;                             // contiguous memset region start
  float* xout  = allocf((size_t)4992 * 256);
  short* xout_h = allocs((size_t)4992 * 256);
  short* xout_l = allocs((size_t)4992 * 256);
  size_t msz = off - ms0;                       // one memset covers xout + both bf16 copies
  short* t1_h   = allocs((size_t)4992 * 256); short* t1_l   = allocs((size_t)4992 * 256);
  short* t2_h   = allocs((size_t)4992 * 256); short* t2_l   = allocs((size_t)4992 * 256);
  float* adj1  = allocf(128 * 32 * 32);
  float* adj2  = allocf(128 * 26 * 26);
  float* stats = allocf(512);
  int* perm1 = alloci(4096); int* perm2 = alloci(3328); int* perm3 = alloci(2688);
  float* z  = allocf(128 * 512);
  float* z1 = allocf(128 * 256);
  float* z2 = allocf(128 * 128);
  float* logits = allocf(256);
  if (off > ws_size) return;

  auto knn = [&](const float* xin, int n, int F) {
    int qpg = (n + 3) >> 2;
    int waves = B_ * qpg;
    knn_quad_kernel<<<cdiv(waves * 64, 256), 256, 0, stream>>>(xin, n, F, B_, idxb);
  };

  // fp32 trunk edge conv (feeds top-k; exact)
  auto edge_conv = [&](const float* xin, int n, int F, const float* wcat, const float* bias,
                       int Hout, float* outbuf) {
    int M = B_ * n;
    knn(xin, n, F);
    dim3 gg(cdiv(2 * Hout, BN), cdiv(M, BM));
    gemm_kernel<<<gg, 256, 0, stream>>>(xin, wcat, nullptr, AB, M, 2 * Hout, F, 0);
    edge_agg_kernel<<<cdiv(M * Hout, 256), 256, 0, stream>>>(AB, bias, idxb, n, Hout, 0, outbuf, nullptr, nullptr);
  };
  // split-bf16 decoder edge conv
  auto edge_conv_bf = [&](const float* xin, const short* xh, const short* xl,
                          const short* wth, const short* wtl,
                          const float* bias, int Hout, int act,
                          float* outbuf, short* outh, short* outl) {
    int M = 4992, F = 256;
    knn(xin, N_, F);
    dim3 gg(cdiv(2 * Hout, 128), cdiv(M, 128));
    mfma_gemm_split_kernel<<<gg, 256, 0, stream>>>(xh, xl, wth, wtl, nullptr, AB, nullptr, nullptr,
                                                   M, 2 * Hout, F, 0);
    edge_agg_kernel<<<cdiv(M * Hout, 256), 256, 0, stream>>>(AB, bias, idxb, N_, Hout, act, outbuf, outh, outl);
  };
  auto decoder = [&](const float* xin, const short* xh, const short* xl, float* decout) {
    edge_conv_bf(xin, xh, xl, wcat3t_h, wcat3t_l, b_mlp3, H_, 2, t1, t1_h, t1_l);
    edge_conv_bf(t1, t1_h, t1_l, wcat2t_h, wcat2t_l, b_mlp2, H_, 2, t2, t2_h, t2_l);
    edge_conv_bf(t2, t2_h, t2_l, wcat6t_h, wcat6t_l, b_mlp6, N_, 0, decout, nullptr, nullptr);
  };

  // ---- one-shot prep ----
  prep_kernel<<<dim3(512, 7), 256, 0, stream>>>(
      w_mlp1, w_mlp2, w_mlp3, w_mlp6, lin4_w, lin5_w, adj,
      wcat1, wcat2, wcat3,
      wcat2t_h, wcat2t_l, wcat3t_h, wcat3t_l, wcat6t_h, wcat6t_l,
      lin4t_h, lin4t_l, lin5t_h, lin5t_l, deg);

  // ---- level 1 ----
  edge_conv(x, N_, N_, wcat1, b_mlp1, H_, t1);
  bn_stats_kernel<<<H_, 256, 0, stream>>>(t1, 4992, stats);
  bn_apply_kernel<<<cdiv(4992 * 256, 256), 256, 0, stream>>>(t1, stats, bn1_g, bn1_b, 4992, hbuf);
  sag_kernel<<<B_, 256, 0, stream>>>(hbuf, adj, N_, K1_, p1_w, p1_b, perm1, xp, adj1);
  hipMemsetAsync(xout, 0, msz, stream);
  scatter_kernel<<<cdiv(4096 * 256, 256), 256, 0, stream>>>(xp, perm1, nullptr, 4096, xout, xout_h, xout_l);
  {
    dim3 g4(2, 39);
    mfma_gemm_split_kernel<<<g4, 256, 0, stream>>>(xout_h, xout_l, lin4t_h, lin4t_l, lin4_b,
                                                   t1, t1_h, t1_l, 4992, 256, 256, 1);
    dim3 g5(1, 39);
    mfma_gemm_split_kernel<<<g5, 256, 0, stream>>>(t1_h, t1_l, lin5t_h, lin5t_l, lin5_b,
                                                   t2, nullptr, nullptr, 4992, 128, 256, 1);
  }
  rowdot_kernel<<<cdiv(4992 * 64, 256), 256, 0, stream>>>(t2, lin6_w, 4992, 128, lin6_b, 1, xdeg);
  gtpred_kernel<<<cdiv(4096, 256), 256, 0, stream>>>(deg, xdeg, perm1, 4096, out_gt1, out_pred1);
  readout_kernel<<<cdiv(128 * 256, 256), 256, 0, stream>>>(xp, K1_, 0, z);
  decoder(xout, xout_h, xout_l, out_dec1);

  // ---- level 2 ----
  edge_conv(xp, K1_, H_, wcat2, b_mlp2, H_, t1);
  bn_stats_kernel<<<H_, 256, 0, stream>>>(t1, 4096, stats);
  bn_apply_kernel<<<cdiv(4096 * 256, 256), 256, 0, stream>>>(t1, stats, bn2_g, bn2_b, 4096, hbuf);
  sag_kernel<<<B_, 256, 0, stream>>>(hbuf, adj1, K1_, K2_, p2_w, p2_b, perm2, xp, adj2);
  hipMemsetAsync(xout, 0, msz, stream);
  scatter_kernel<<<cdiv(3328 * 256, 256), 256, 0, stream>>>(xp, perm1, perm2, 3328, xout, xout_h, xout_l);
  gtpred_kernel<<<cdiv(3328, 256), 256, 0, stream>>>(deg, xdeg, perm2, 3328, out_gt2, out_pred2);
  readout_kernel<<<cdiv(128 * 256, 256), 256, 0, stream>>>(xp, K2_, 1, z);
  decoder(xout, xout_h, xout_l, out_dec2);

  // ---- level 3 ----
  edge_conv(xp, K2_, H_, wcat3, b_mlp3, H_, t1);
  bn_stats_kernel<<<H_, 256, 0, stream>>>(t1, 3328, stats);
  bn_apply_kernel<<<cdiv(3328 * 256, 256), 256, 0, stream>>>(t1, stats, bn3_g, bn3_b, 3328, hbuf);
  sag_kernel<<<B_, 256, 0, stream>>>(hbuf, adj2, K2_, K3_, p3_w, p3_b, perm3, xp, nullptr);
  hipMemsetAsync(xout, 0, msz, stream);
  scatter_kernel<<<cdiv(2688 * 256, 256), 256, 0, stream>>>(xp, perm2, perm3, 2688, xout, xout_h, xout_l);
  gtpred_kernel<<<cdiv(2688, 256), 256, 0, stream>>>(deg, xdeg, perm3, 2688, out_gt3, out_pred3);
  readout_kernel<<<cdiv(128 * 256, 256), 256, 0, stream>>>(xp, K3_, 1, z);
  decoder(xout, xout_h, xout_l, out_dec3);

  // ---- classifier head (thin: M=128) ----
  rowgemm_kernel<<<128, 256, 0, stream>>>(z, lin1_w, lin1_b, z1, 256, 512, 1);
  rowgemm_kernel<<<128, 256, 0, stream>>>(z1, lin2_w, lin2_b, z2, 128, 256, 1);
  wavedot_gemm_kernel<<<cdiv(128 * 2 * 64, 256), 256, 0, stream>>>(z2, lin3_w, lin3_b, logits, 128, 2, 128, 0);
  softmax2_kernel<<<1, 128, 0, stream>>>(logits, out_probs);
}

// Round 10
// 1235.757 us; speedup vs baseline: 1.0947x; 1.0947x over previous
//
#include <hip/hip_runtime.h>
#include <cmath>

#define B_   128
#define N_   39
#define KNN_ 10
#define H_   256
#define K1_  32
#define K2_  26
#define K3_  21

static inline int cdiv(int a, int b) { return (a + b - 1) / b; }

typedef __attribute__((ext_vector_type(8))) short short8;
typedef __attribute__((ext_vector_type(4))) float floatx4;

__device__ inline short f2b(float f) {   // fp32 -> bf16 RNE
  unsigned u = __float_as_uint(f);
  u += 0x7fff + ((u >> 16) & 1);
  return (short)(u >> 16);
}
__device__ inline float b2f(short h) {
  return __uint_as_float(((unsigned)(unsigned short)h) << 16);
}
__device__ inline void f2b2(float v, short& hi, short& lo) {  // split: v ~= hi + lo
  hi = f2b(v);
  lo = f2b(v - b2f(hi));
}

// ---------- wave-wide argmax/argmin (64 lanes), ties -> lowest index ----------
__device__ inline void wave_argmax64(float& v, int& j) {
#pragma unroll
  for (int off = 32; off; off >>= 1) {
    float ov = __shfl_down(v, off, 64);
    int   oj = __shfl_down(j, off, 64);
    if (ov > v || (ov == v && oj < j)) { v = ov; j = oj; }
  }
  v = __shfl(v, 0, 64);
  j = __shfl(j, 0, 64);
}
__device__ inline void wave_argmin64(float& v, int& j) {
#pragma unroll
  for (int off = 32; off; off >>= 1) {
    float ov = __shfl_down(v, off, 64);
    int   oj = __shfl_down(j, off, 64);
    if (ov < v || (ov == v && oj < j)) { v = ov; j = oj; }
  }
  v = __shfl(v, 0, 64);
  j = __shfl(j, 0, 64);
}

// ---------------- one-shot weight prep + degree (7 tasks on blockIdx.y) ----------------
__global__ void prep_kernel(const float* __restrict__ w1, const float* __restrict__ w2,
                            const float* __restrict__ w3, const float* __restrict__ w6,
                            const float* __restrict__ l4, const float* __restrict__ l5,
                            const float* __restrict__ adj,
                            float* __restrict__ wcat1, float* __restrict__ wcat2,
                            float* __restrict__ wcat3,
                            short* __restrict__ w2h, short* __restrict__ w2l,
                            short* __restrict__ w3h, short* __restrict__ w3l,
                            short* __restrict__ w6h, short* __restrict__ w6l,
                            short* __restrict__ l4h, short* __restrict__ l4l,
                            short* __restrict__ l5h, short* __restrict__ l5l,
                            float* __restrict__ deg) {
  int task = blockIdx.y;
  int t = blockIdx.x * 256 + threadIdx.x;
  if (task == 0) {                        // wcat1 fp32 only (F=39, Hc=256)
    if (t >= 39 * 512) return;
    int k = t >> 9, c = t & 511;
    wcat1[t] = (c < 256) ? w1[k * 256 + c] - w1[(39 + k) * 256 + c]
                         : w1[(39 + k) * 256 + (c - 256)];
  } else if (task == 1) {                 // wcat2 fp32 + splitT (F=256, Hc=256)
    if (t >= 256 * 512) return;
    int k = t >> 9, c = t & 511;
    float v = (c < 256) ? w2[k * 256 + c] - w2[(256 + k) * 256 + c]
                        : w2[(256 + k) * 256 + (c - 256)];
    wcat2[t] = v;
    short hi, lo; f2b2(v, hi, lo);
    w2h[(size_t)c * 256 + k] = hi; w2l[(size_t)c * 256 + k] = lo;
  } else if (task == 2) {                 // wcat3 fp32 + splitT
    if (t >= 256 * 512) return;
    int k = t >> 9, c = t & 511;
    float v = (c < 256) ? w3[k * 256 + c] - w3[(256 + k) * 256 + c]
                        : w3[(256 + k) * 256 + (c - 256)];
    wcat3[t] = v;
    short hi, lo; f2b2(v, hi, lo);
    w3h[(size_t)c * 256 + k] = hi; w3l[(size_t)c * 256 + k] = lo;
  } else if (task == 3) {                 // wcat6 splitT only (F=256, Hc=39)
    if (t >= 256 * 78) return;
    int k = t / 78, c = t - k * 78;
    float v = (c < 39) ? w6[k * 39 + c] - w6[(256 + k) * 39 + c]
                       : w6[(256 + k) * 39 + (c - 39)];
    short hi, lo; f2b2(v, hi, lo);
    w6h[(size_t)c * 256 + k] = hi; w6l[(size_t)c * 256 + k] = lo;
  } else if (task == 4) {                 // lin4 splitT (256 x 256)
    if (t >= 256 * 256) return;
    int k = t >> 8, n = t & 255;
    short hi, lo; f2b2(l4[t], hi, lo);
    l4h[(size_t)n * 256 + k] = hi; l4l[(size_t)n * 256 + k] = lo;
  } else if (task == 5) {                 // lin5 splitT (256 x 128)
    if (t >= 256 * 128) return;
    int k = t >> 7, n = t & 127;
    short hi, lo; f2b2(l5[t], hi, lo);
    l5h[(size_t)n * 256 + k] = hi; l5l[(size_t)n * 256 + k] = lo;
  } else {                                // degree
    if (t >= B_ * N_) return;
    const float* row = adj + (size_t)t * N_;
    float s = 0.f;
    for (int j = 0; j < N_; ++j) s += row[j];
    deg[t] = s;
  }
}

// ---------------- coalesced KNN: one wave per output row; lanes split features ----------------
// lane L holds x_i[4L..4L+3] in regs; loop j: coalesced 1KB load of x_j, butterfly-reduce
// (dot, sq) across 64 lanes; lane j keeps its pair; sq_i captured at j==i.
// Exact-zero rows still give d == 0 exactly -> stable lowest-index ties like lax.top_k.
__global__ __launch_bounds__(256) void knn_coal_kernel(const float* __restrict__ x,
                                                       int n, int F, int M,
                                                       int* __restrict__ idx) {
  int w = (blockIdx.x * blockDim.x + threadIdx.x) >> 6;
  int lane = threadIdx.x & 63;
  if (w >= M) return;
  int b = w / n, i = w - b * n;
  const float* xb = x + (size_t)b * n * F;
  float sqi = 0.f, dstore = 0.f, sqstore = 0.f;
  if (F == 256) {
    float4 xi4 = *(const float4*)&xb[(size_t)i * F + lane * 4];
    for (int j = 0; j < n; ++j) {
      float4 xj4 = *(const float4*)&xb[(size_t)j * F + lane * 4];
      float pd = xi4.x * xj4.x + xi4.y * xj4.y + xi4.z * xj4.z + xi4.w * xj4.w;
      float ps = xj4.x * xj4.x + xj4.y * xj4.y + xj4.z * xj4.z + xj4.w * xj4.w;
#pragma unroll
      for (int off = 32; off; off >>= 1) {
        pd += __shfl_xor(pd, off, 64);
        ps += __shfl_xor(ps, off, 64);
      }
      if (j == i) sqi = ps;
      if (lane == j) { dstore = pd; sqstore = ps; }
    }
  } else if (F <= 64) {
    float xis = (lane < F) ? xb[(size_t)i * F + lane] : 0.f;
    for (int j = 0; j < n; ++j) {
      float xjs = (lane < F) ? xb[(size_t)j * F + lane] : 0.f;
      float pd = xis * xjs;
      float ps = xjs * xjs;
#pragma unroll
      for (int off = 32; off; off >>= 1) {
        pd += __shfl_xor(pd, off, 64);
        ps += __shfl_xor(ps, off, 64);
      }
      if (j == i) sqi = ps;
      if (lane == j) { dstore = pd; sqstore = ps; }
    }
  } else {
    for (int j = 0; j < n; ++j) {
      float pd = 0.f, ps = 0.f;
      for (int f = lane; f < F; f += 64) {
        float a = xb[(size_t)i * F + f];
        float bv = xb[(size_t)j * F + f];
        pd += a * bv;
        ps += bv * bv;
      }
#pragma unroll
      for (int off = 32; off; off >>= 1) {
        pd += __shfl_xor(pd, off, 64);
        ps += __shfl_xor(ps, off, 64);
      }
      if (j == i) sqi = ps;
      if (lane == j) { dstore = pd; sqstore = ps; }
    }
  }
  float d = (lane < n) ? (sqi + sqstore - 2.f * dstore) : INFINITY;
  int* outp = idx + (size_t)w * KNN_;
  for (int kk = 0; kk < KNN_; ++kk) {
    float rv = d;
    int rj = (lane < n) ? lane : (1 << 20);
    wave_argmin64(rv, rj);
    if (lane == 0) outp[kk] = rj;
    if (lane == rj) d = INFINITY;
  }
}

// ---------------- fp32 trunk GEMM: 64x64 tile, register-staged pipeline ----------------
#define BM 64
#define BN 64
#define BK 16
__global__ __launch_bounds__(256) void gemm_kernel(
    const float* __restrict__ A, const float* __restrict__ W, const float* __restrict__ bias,
    float* __restrict__ C, int M, int N, int K, int act) {
  __shared__ float As[BK][BM + 4];
  __shared__ float Bs[BK][BN + 4];
  int tid = threadIdx.x;
  int tx = tid & 15, ty = tid >> 4;
  int row0 = blockIdx.y * BM, col0 = blockIdx.x * BN;
  float c[4][4] = {};
  float ra[4], rb[4];
#pragma unroll
  for (int v = 0; v < 4; ++v) {
    int e = tid + v * 256;
    int m = e >> 4, kk = e & 15;
    int row = row0 + m;
    ra[v] = (row < M && kk < K) ? A[(size_t)row * K + kk] : 0.f;
    int kk2 = e >> 6, nn = e & 63;
    int col = col0 + nn;
    rb[v] = (kk2 < K && col < N) ? W[(size_t)kk2 * N + col] : 0.f;
  }
  for (int k0 = 0; k0 < K; k0 += BK) {
#pragma unroll
    for (int v = 0; v < 4; ++v) {
      int e = tid + v * 256;
      As[e & 15][e >> 4] = ra[v];
      Bs[e >> 6][e & 63] = rb[v];
    }
    __syncthreads();
    int k1 = k0 + BK;
    if (k1 < K) {
#pragma unroll
      for (int v = 0; v < 4; ++v) {
        int e = tid + v * 256;
        int m = e >> 4, kk = e & 15;
        int row = row0 + m, k = k1 + kk;
        ra[v] = (row < M && k < K) ? A[(size_t)row * K + k] : 0.f;
        int kk2 = e >> 6, nn = e & 63;
        int k2 = k1 + kk2, col = col0 + nn;
        rb[v] = (k2 < K && col < N) ? W[(size_t)k2 * N + col] : 0.f;
      }
    }
#pragma unroll
    for (int kk = 0; kk < BK; ++kk) {
      float4 av = *(const float4*)&As[kk][ty * 4];
      float4 bv = *(const float4*)&Bs[kk][tx * 4];
      float a[4] = {av.x, av.y, av.z, av.w};
      float b[4] = {bv.x, bv.y, bv.z, bv.w};
#pragma unroll
      for (int i2 = 0; i2 < 4; ++i2)
#pragma unroll
        for (int j = 0; j < 4; ++j) c[i2][j] += a[i2] * b[j];
    }
    __syncthreads();
  }
#pragma unroll
  for (int i2 = 0; i2 < 4; ++i2) {
    int row = row0 + ty * 4 + i2;
    if (row >= M) continue;
#pragma unroll
    for (int j = 0; j < 4; ++j) {
      int col = col0 + tx * 4 + j;
      if (col >= N) continue;
      float v = c[i2][j] + (bias ? bias[col] : 0.f);
      if (act == 1) v = fmaxf(v, 0.f);
      C[(size_t)row * N + col] = v;
    }
  }
}

// ------------- split-bf16 3-pass MFMA GEMM (near-fp32 accuracy, ~2^-16 rel) -------------
__global__ __launch_bounds__(256) void mfma_gemm_split_kernel(
    const short* __restrict__ Ah, const short* __restrict__ Al,
    const short* __restrict__ Wth, const short* __restrict__ Wtl,
    const float* __restrict__ bias,
    float* __restrict__ C, short* __restrict__ Ch, short* __restrict__ Cl,
    int M, int N, int K, int act) {
  __shared__ short Ash[128 * 40];
  __shared__ short Asl[128 * 40];
  __shared__ short Bsh[128 * 40];
  __shared__ short Bsl[128 * 40];
  int tid = threadIdx.x;
  int wave = tid >> 6, lane = tid & 63;
  int wm = wave & 1, wn = wave >> 1;
  int row0 = blockIdx.y * 128, col0 = blockIdx.x * 128;
  floatx4 acc[4][4] = {};
  int lm = lane & 15, lk = (lane >> 4) * 8;
  for (int k0 = 0; k0 < K; k0 += 32) {
    for (int c = tid; c < 512; c += 256) {
      int r = c >> 2, kc = (c & 3) * 8;
      int grow = row0 + r;
      short8 vh = {}, vl = {};
      if (grow < M) {
        vh = *(const short8*)&Ah[(size_t)grow * K + k0 + kc];
        vl = *(const short8*)&Al[(size_t)grow * K + k0 + kc];
      }
      *(short8*)&Ash[r * 40 + kc] = vh;
      *(short8*)&Asl[r * 40 + kc] = vl;
    }
    for (int c = tid; c < 512; c += 256) {
      int r = c >> 2, kc = (c & 3) * 8;
      int gn = col0 + r;
      short8 vh = {}, vl = {};
      if (gn < N) {
        vh = *(const short8*)&Wth[(size_t)gn * K + k0 + kc];
        vl = *(const short8*)&Wtl[(size_t)gn * K + k0 + kc];
      }
      *(short8*)&Bsh[r * 40 + kc] = vh;
      *(short8*)&Bsl[r * 40 + kc] = vl;
    }
    __syncthreads();
    short8 afh[4], afl[4], bfh[4], bfl[4];
#pragma unroll
    for (int mi = 0; mi < 4; ++mi) {
      int ro = (wm * 64 + mi * 16 + lm) * 40 + lk;
      afh[mi] = *(const short8*)&Ash[ro];
      afl[mi] = *(const short8*)&Asl[ro];
    }
#pragma unroll
    for (int ni = 0; ni < 4; ++ni) {
      int ro = (wn * 64 + ni * 16 + lm) * 40 + lk;
      bfh[ni] = *(const short8*)&Bsh[ro];
      bfl[ni] = *(const short8*)&Bsl[ro];
    }
#pragma unroll
    for (int mi = 0; mi < 4; ++mi)
#pragma unroll
      for (int ni = 0; ni < 4; ++ni) {
        acc[mi][ni] = __builtin_amdgcn_mfma_f32_16x16x32_bf16(afh[mi], bfh[ni], acc[mi][ni], 0, 0, 0);
        acc[mi][ni] = __builtin_amdgcn_mfma_f32_16x16x32_bf16(afh[mi], bfl[ni], acc[mi][ni], 0, 0, 0);
        acc[mi][ni] = __builtin_amdgcn_mfma_f32_16x16x32_bf16(afl[mi], bfh[ni], acc[mi][ni], 0, 0, 0);
      }
    __syncthreads();
  }
  int lr = (lane >> 4) * 4;
#pragma unroll
  for (int mi = 0; mi < 4; ++mi)
#pragma unroll
    for (int ni = 0; ni < 4; ++ni) {
      int colg = col0 + wn * 64 + ni * 16 + lm;
      if (colg >= N) continue;
      float bv = bias ? bias[colg] : 0.f;
#pragma unroll
      for (int r = 0; r < 4; ++r) {
        int rowg = row0 + wm * 64 + mi * 16 + lr + r;
        if (rowg >= M) continue;
        float v = acc[mi][ni][r] + bv;
        if (act == 1) v = fmaxf(v, 0.f);
        C[(size_t)rowg * N + colg] = v;
        if (Ch) {
          short hi, lo;
          f2b2(v, hi, lo);
          Ch[(size_t)rowg * N + colg] = hi;
          Cl[(size_t)rowg * N + colg] = lo;
        }
      }
    }
}

// Thin GEMM (small M): one block per row.
__global__ __launch_bounds__(256) void rowgemm_kernel(
    const float* __restrict__ A, const float* __restrict__ W, const float* __restrict__ bias,
    float* __restrict__ C, int N, int K, int act) {
  __shared__ float a[512];
  int row = blockIdx.x;
  for (int k = threadIdx.x; k < K; k += 256) a[k] = A[(size_t)row * K + k];
  __syncthreads();
  for (int c = threadIdx.x; c < N; c += 256) {
    float s = 0.f;
    for (int k = 0; k < K; k += 4) {
      float4 av = *(const float4*)&a[k];
      s += av.x * W[(size_t)k * N + c];
      s += av.y * W[(size_t)(k + 1) * N + c];
      s += av.z * W[(size_t)(k + 2) * N + c];
      s += av.w * W[(size_t)(k + 3) * N + c];
    }
    float v = s + (bias ? bias[c] : 0.f);
    if (act == 1) v = fmaxf(v, 0.f);
    C[(size_t)row * N + c] = v;
  }
}

// one wave per output element (for very small M*N)
__global__ void wavedot_gemm_kernel(const float* __restrict__ A, const float* __restrict__ W,
                                    const float* __restrict__ bias, float* __restrict__ C,
                                    int M, int N, int K, int act) {
  int wid = (blockIdx.x * blockDim.x + threadIdx.x) >> 6;
  int lane = threadIdx.x & 63;
  if (wid >= M * N) return;
  int row = wid / N, col = wid - row * N;
  const float* ar = A + (size_t)row * K;
  float s = 0.f;
  for (int k = lane; k < K; k += 64) s += ar[k] * W[(size_t)k * N + col];
  for (int off = 32; off; off >>= 1) s += __shfl_down(s, off, 64);
  if (lane == 0) {
    float v = s + (bias ? bias[col] : 0.f);
    if (act == 1) v = fmaxf(v, 0.f);
    C[(size_t)row * N + col] = v;
  }
}

// AB row r: [0..Hc) = xi@(Wt-Wb), [Hc..2Hc) = xi@Wb.  out = max_k relu(Ai + b + Bm[nbr]) [tanh]
__global__ void edge_agg_kernel(const float* __restrict__ AB, const float* __restrict__ bias,
                                const int* __restrict__ idx, int n, int Hc, int act,
                                float* __restrict__ out,
                                short* __restrict__ outh, short* __restrict__ outl) {
  int t = blockIdx.x * blockDim.x + threadIdx.x;
  if (t >= B_ * n * Hc) return;
  int r = t / Hc, h = t - r * Hc;
  int b = r / n;
  int s2 = 2 * Hc;
  float av = AB[(size_t)r * s2 + h] + bias[h];
  const int* ir = idx + (size_t)r * KNN_;
  int base = b * n;
  float m = -INFINITY;
  for (int k = 0; k < KNN_; ++k) {
    float v = av + AB[(size_t)(base + ir[k]) * s2 + Hc + h];
    v = fmaxf(v, 0.f);
    m = fmaxf(m, v);
  }
  if (act == 2) m = tanhf(m);
  out[t] = m;
  if (outh) {
    short hi, lo;
    f2b2(m, hi, lo);
    outh[t] = hi;
    outl[t] = lo;
  }
}

__global__ void bn_stats_kernel(const float* __restrict__ x, int M, float* __restrict__ mv) {
  int c = blockIdx.x;
  double s = 0.0, s2 = 0.0;
  for (int r = threadIdx.x; r < M; r += 256) {
    double v = (double)x[(size_t)r * H_ + c];
    s += v; s2 += v * v;
  }
  __shared__ double sh[256], sh2[256];
  sh[threadIdx.x] = s; sh2[threadIdx.x] = s2;
  __syncthreads();
  for (int o = 128; o; o >>= 1) {
    if (threadIdx.x < o) { sh[threadIdx.x] += sh[threadIdx.x + o]; sh2[threadIdx.x] += sh2[threadIdx.x + o]; }
    __syncthreads();
  }
  if (threadIdx.x == 0) {
    double mean = sh[0] / M;
    double var = sh2[0] / M - mean * mean;
    mv[c] = (float)mean;
    mv[H_ + c] = (float)var;
  }
}

__global__ void bn_apply_kernel(const float* __restrict__ x, const float* __restrict__ mv,
                                const float* __restrict__ g, const float* __restrict__ bb,
                                int M, float* __restrict__ out) {
  int t = blockIdx.x * blockDim.x + threadIdx.x;
  if (t >= M * H_) return;
  int h = t & (H_ - 1);
  float mean = mv[h], var = mv[H_ + h];
  float v = (x[t] - mean) * (1.f / sqrtf(var + 1e-5f)) * g[h] + bb[h];
  out[t] = fmaxf(v, 0.f);
}

// one wave per row: y[r] = dot(x[r,:K], w) [+bias] [relu]
__global__ void rowdot_kernel(const float* __restrict__ x, const float* __restrict__ w,
                              int M, int K, const float* __restrict__ bias, int act,
                              float* __restrict__ y) {
  int wid = (blockIdx.x * blockDim.x + threadIdx.x) >> 6;
  int lane = threadIdx.x & 63;
  if (wid >= M) return;
  const float* xr = x + (size_t)wid * K;
  float s = 0.f;
  for (int k = lane; k < K; k += 64) s += xr[k] * w[k];
  for (int off = 32; off; off >>= 1) s += __shfl_down(s, off, 64);
  if (lane == 0) {
    float v = s + (bias ? bias[0] : 0.f);
    if (act == 1) v = fmaxf(v, 0.f);
    y[wid] = v;
  }
}

// ---------------- fused SAG pool: rowdot + gcn score + topk + gather (block per graph) ----------------
__global__ __launch_bounds__(256) void sag_kernel(
    const float* __restrict__ h, const float* __restrict__ adj_in, int n, int k,
    const float* __restrict__ pw, const float* __restrict__ pb,
    int* __restrict__ perm, float* __restrict__ xp, float* __restrict__ adjp) {
  __shared__ float ys[40], dinv[40], sc[40], topv[40];
  __shared__ int locs[40];
  int b = blockIdx.x;
  int wave = threadIdx.x >> 6, lane = threadIdx.x & 63;
  // rowdot: y[i] = h[b,i,:] . pw
  for (int i = wave; i < n; i += 4) {
    const float* xr = h + (size_t)(b * n + i) * H_;
    float s = 0.f;
    for (int kk = lane; kk < H_; kk += 64) s += xr[kk] * pw[kk];
    for (int off = 32; off; off >>= 1) s += __shfl_down(s, off, 64);
    if (lane == 0) ys[i] = s;
  }
  __syncthreads();
  int i = threadIdx.x;
  if (i < n) {
    const float* ar = adj_in + ((size_t)b * n + i) * n;
    float sum = 1.f;
    for (int j = 0; j < n; ++j) sum += ar[j];
    dinv[i] = 1.f / sqrtf(sum);
  }
  __syncthreads();
  if (i < n) {
    const float* ar = adj_in + ((size_t)b * n + i) * n;
    float acc = 0.f;
    for (int j = 0; j < n; ++j) {
      float a = ar[j] + (i == j ? 1.f : 0.f);
      acc += a * dinv[j] * ys[j];
    }
    sc[i] = dinv[i] * acc + pb[0];
  }
  __syncthreads();
  if (wave == 0) {
    float cur = (lane < n) ? sc[lane] : -INFINITY;
    for (int t = 0; t < k; ++t) {
      float rv = cur;
      int rj = (lane < n) ? lane : (1 << 20);
      wave_argmax64(rv, rj);
      if (lane == 0) { topv[t] = rv; locs[t] = rj; perm[b * k + t] = b * n + rj; }
      if (lane == rj) cur = -INFINITY;
    }
  }
  __syncthreads();
  for (int e = threadIdx.x; e < k * H_; e += 256) {
    int r = e >> 8, hh = e & 255;
    xp[((size_t)b * k + r) * H_ + hh] =
        h[((size_t)(b * n + locs[r])) * H_ + hh] * tanhf(topv[r]);
  }
  if (adjp) {
    for (int e = threadIdx.x; e < k * k; e += 256) {
      int t1 = e / k, t2 = e - t1 * k;
      adjp[(size_t)b * k * k + e] = adj_in[((size_t)b * n + locs[t1]) * n + locs[t2]];
    }
  }
}

// dst[i1[i2[r]] or i1[r]] = src[r]; fp32 + split-bf16 (all pre-zeroed)
__global__ void scatter_kernel(const float* __restrict__ src, const int* __restrict__ i1,
                               const int* __restrict__ i2, int rows,
                               float* __restrict__ dst,
                               short* __restrict__ dsth, short* __restrict__ dstl) {
  int t = blockIdx.x * blockDim.x + threadIdx.x;
  if (t >= rows * H_) return;
  int r = t / H_, h = t - r * H_;
  int tgt = i2 ? i1[i2[r]] : i1[r];
  float v = src[t];
  dst[(size_t)tgt * H_ + h] = v;
  short hi, lo;
  f2b2(v, hi, lo);
  dsth[(size_t)tgt * H_ + h] = hi;
  dstl[(size_t)tgt * H_ + h] = lo;
}

__global__ void gtpred_kernel(const float* __restrict__ deg, const float* __restrict__ xdeg,
                              const int* __restrict__ perm, int M,
                              float* __restrict__ gt, float* __restrict__ pred) {
  int t = blockIdx.x * blockDim.x + threadIdx.x;
  if (t >= M) return;
  int p = perm[t];
  gt[t] = deg[p];
  pred[t] = xdeg[p];
}

__global__ void readout_kernel(const float* __restrict__ xp, int k, int acc, float* __restrict__ z) {
  int t = blockIdx.x * blockDim.x + threadIdx.x;
  if (t >= B_ * H_) return;
  int b = t / H_, h = t - b * H_;
  float mx = -INFINITY, sm = 0.f;
  for (int tt = 0; tt < k; ++tt) {
    float v = xp[((size_t)b * k + tt) * H_ + h];
    mx = fmaxf(mx, v);
    sm += v;
  }
  float* zb = z + (size_t)b * 2 * H_;
  float mean = sm / (float)k;
  if (acc) { zb[h] += mx; zb[H_ + h] += mean; }
  else     { zb[h] = mx;  zb[H_ + h] = mean; }
}

__global__ void softmax2_kernel(const float* __restrict__ logits, float* __restrict__ probs) {
  int b = blockIdx.x * blockDim.x + threadIdx.x;
  if (b >= B_) return;
  float a = logits[2 * b], c = logits[2 * b + 1];
  float m = fmaxf(a, c);
  float ea = expf(a - m), ec = expf(c - m);
  float inv = 1.f / (ea + ec);
  probs[2 * b] = ea * inv;
  probs[2 * b + 1] = ec * inv;
}

extern "C" void kernel_launch(void* const* d_in, const int* in_sizes, int n_in,
                              void* d_out, int out_size, void* d_ws, size_t ws_size,
                              hipStream_t stream) {
  auto in = [&](int i) { return (const float*)d_in[i]; };
  const float* x      = in(0);
  const float* adj    = in(1);
  const float* w_mlp1 = in(2);  const float* b_mlp1 = in(3);
  const float* w_mlp2 = in(4);  const float* b_mlp2 = in(5);
  const float* w_mlp3 = in(6);  const float* b_mlp3 = in(7);
  const float* w_mlp6 = in(8);  const float* b_mlp6 = in(9);
  const float* bn1_g = in(10);  const float* bn1_b = in(11);
  const float* bn2_g = in(12);  const float* bn2_b = in(13);
  const float* bn3_g = in(14);  const float* bn3_b = in(15);
  const float* p1_w = in(16);   const float* p1_b = in(17);
  const float* p2_w = in(18);   const float* p2_b = in(19);
  const float* p3_w = in(20);   const float* p3_b = in(21);
  const float* lin1_w = in(22); const float* lin1_b = in(23);
  const float* lin2_w = in(24); const float* lin2_b = in(25);
  const float* lin3_w = in(26); const float* lin3_b = in(27);
  const float* lin4_w = in(28); const float* lin4_b = in(29);
  const float* lin5_w = in(30); const float* lin5_b = in(31);
  const float* lin6_w = in(32); const float* lin6_b = in(33);

  float* out = (float*)d_out;
  float* out_probs = out;                      // 128*2
  float* out_dec1  = out_probs + 256;          // 4992*39
  float* out_dec2  = out_dec1 + 4992 * 39;
  float* out_dec3  = out_dec2 + 4992 * 39;
  float* out_gt1   = out_dec3 + 4992 * 39;     // 4096
  float* out_pred1 = out_gt1 + 4096;           // 4096
  float* out_gt2   = out_pred1 + 4096;         // 3328
  float* out_pred2 = out_gt2 + 3328;
  float* out_gt3   = out_pred2 + 3328;         // 2688
  float* out_pred3 = out_gt3 + 2688;

  char* base = (char*)d_ws;
  size_t off = 0;
  auto allocf = [&](size_t n) -> float* {
    float* p = (float*)(base + off);
    off += ((n * sizeof(float) + 255) & ~(size_t)255);
    return p;
  };
  auto alloci = [&](size_t n) -> int* {
    int* p = (int*)(base + off);
    off += ((n * sizeof(int) + 255) & ~(size_t)255);
    return p;
  };
  auto allocs = [&](size_t n) -> short* {
    short* p = (short*)(base + off);
    off += ((n * sizeof(short) + 255) & ~(size_t)255);
    return p;
  };

  float* wcat1 = allocf(39 * 512);
  float* wcat2 = allocf(256 * 512);
  float* wcat3 = allocf(256 * 512);
  short* wcat2t_h = allocs(512 * 256); short* wcat2t_l = allocs(512 * 256);
  short* wcat3t_h = allocs(512 * 256); short* wcat3t_l = allocs(512 * 256);
  short* wcat6t_h = allocs(78 * 256);  short* wcat6t_l = allocs(78 * 256);
  short* lin4t_h  = allocs(256 * 256); short* lin4t_l  = allocs(256 * 256);
  short* lin5t_h  = allocs(128 * 256); short* lin5t_l  = allocs(128 * 256);
  float* deg   = allocf(4992);
  float* xdeg  = allocf(4992);
  int*   idxb  = alloci(4992 * KNN_);
  float* AB    = allocf((size_t)4992 * 512);
  float* t1    = allocf((size_t)4992 * 256);
  float* t2    = allocf((size_t)4992 * 256);
  float* hbuf  = allocf((size_t)4992 * 256);
  float* xp    = allocf((size_t)4096 * 256);
  size_t ms0 = off;                             // contiguous memset region start
  float* xout  = allocf((size_t)4992 * 256);
  short* xout_h = allocs((size_t)4992 * 256);
  short* xout_l = allocs((size_t)4992 * 256);
  size_t msz = off - ms0;                       // one memset covers xout + both bf16 copies
  short* t1_h   = allocs((size_t)4992 * 256); short* t1_l   = allocs((size_t)4992 * 256);
  short* t2_h   = allocs((size_t)4992 * 256); short* t2_l   = allocs((size_t)4992 * 256);
  float* adj1  = allocf(128 * 32 * 32);
  float* adj2  = allocf(128 * 26 * 26);
  float* stats = allocf(512);
  int* perm1 = alloci(4096); int* perm2 = alloci(3328); int* perm3 = alloci(2688);
  float* z  = allocf(128 * 512);
  float* z1 = allocf(128 * 256);
  float* z2 = allocf(128 * 128);
  float* logits = allocf(256);
  if (off > ws_size) return;

  auto knn = [&](const float* xin, int n, int F) {
    int M = B_ * n;
    knn_coal_kernel<<<cdiv(M * 64, 256), 256, 0, stream>>>(xin, n, F, M, idxb);
  };

  // fp32 trunk edge conv (feeds top-k; exact)
  auto edge_conv = [&](const float* xin, int n, int F, const float* wcat, const float* bias,
                       int Hout, float* outbuf) {
    int M = B_ * n;
    knn(xin, n, F);
    dim3 gg(cdiv(2 * Hout, BN), cdiv(M, BM));
    gemm_kernel<<<gg, 256, 0, stream>>>(xin, wcat, nullptr, AB, M, 2 * Hout, F, 0);
    edge_agg_kernel<<<cdiv(M * Hout, 256), 256, 0, stream>>>(AB, bias, idxb, n, Hout, 0, outbuf, nullptr, nullptr);
  };
  // split-bf16 decoder edge conv
  auto edge_conv_bf = [&](const float* xin, const short* xh, const short* xl,
                          const short* wth, const short* wtl,
                          const float* bias, int Hout, int act,
                          float* outbuf, short* outh, short* outl) {
    int M = 4992, F = 256;
    knn(xin, N_, F);
    dim3 gg(cdiv(2 * Hout, 128), cdiv(M, 128));
    mfma_gemm_split_kernel<<<gg, 256, 0, stream>>>(xh, xl, wth, wtl, nullptr, AB, nullptr, nullptr,
                                                   M, 2 * Hout, F, 0);
    edge_agg_kernel<<<cdiv(M * Hout, 256), 256, 0, stream>>>(AB, bias, idxb, N_, Hout, act, outbuf, outh, outl);
  };
  auto decoder = [&](const float* xin, const short* xh, const short* xl, float* decout) {
    edge_conv_bf(xin, xh, xl, wcat3t_h, wcat3t_l, b_mlp3, H_, 2, t1, t1_h, t1_l);
    edge_conv_bf(t1, t1_h, t1_l, wcat2t_h, wcat2t_l, b_mlp2, H_, 2, t2, t2_h, t2_l);
    edge_conv_bf(t2, t2_h, t2_l, wcat6t_h, wcat6t_l, b_mlp6, N_, 0, decout, nullptr, nullptr);
  };

  // ---- one-shot prep ----
  prep_kernel<<<dim3(512, 7), 256, 0, stream>>>(
      w_mlp1, w_mlp2, w_mlp3, w_mlp6, lin4_w, lin5_w, adj,
      wcat1, wcat2, wcat3,
      wcat2t_h, wcat2t_l, wcat3t_h, wcat3t_l, wcat6t_h, wcat6t_l,
      lin4t_h, lin4t_l, lin5t_h, lin5t_l, deg);

  // ---- level 1 ----
  edge_conv(x, N_, N_, wcat1, b_mlp1, H_, t1);
  bn_stats_kernel<<<H_, 256, 0, stream>>>(t1, 4992, stats);
  bn_apply_kernel<<<cdiv(4992 * 256, 256), 256, 0, stream>>>(t1, stats, bn1_g, bn1_b, 4992, hbuf);
  sag_kernel<<<B_, 256, 0, stream>>>(hbuf, adj, N_, K1_, p1_w, p1_b, perm1, xp, adj1);
  hipMemsetAsync(xout, 0, msz, stream);
  scatter_kernel<<<cdiv(4096 * 256, 256), 256, 0, stream>>>(xp, perm1, nullptr, 4096, xout, xout_h, xout_l);
  {
    dim3 g4(2, 39);
    mfma_gemm_split_kernel<<<g4, 256, 0, stream>>>(xout_h, xout_l, lin4t_h, lin4t_l, lin4_b,
                                                   t1, t1_h, t1_l, 4992, 256, 256, 1);
    dim3 g5(1, 39);
    mfma_gemm_split_kernel<<<g5, 256, 0, stream>>>(t1_h, t1_l, lin5t_h, lin5t_l, lin5_b,
                                                   t2, nullptr, nullptr, 4992, 128, 256, 1);
  }
  rowdot_kernel<<<cdiv(4992 * 64, 256), 256, 0, stream>>>(t2, lin6_w, 4992, 128, lin6_b, 1, xdeg);
  gtpred_kernel<<<cdiv(4096, 256), 256, 0, stream>>>(deg, xdeg, perm1, 4096, out_gt1, out_pred1);
  readout_kernel<<<cdiv(128 * 256, 256), 256, 0, stream>>>(xp, K1_, 0, z);
  decoder(xout, xout_h, xout_l, out_dec1);

  // ---- level 2 ----
  edge_conv(xp, K1_, H_, wcat2, b_mlp2, H_, t1);
  bn_stats_kernel<<<H_, 256, 0, stream>>>(t1, 4096, stats);
  bn_apply_kernel<<<cdiv(4096 * 256, 256), 256, 0, stream>>>(t1, stats, bn2_g, bn2_b, 4096, hbuf);
  sag_kernel<<<B_, 256, 0, stream>>>(hbuf, adj1, K1_, K2_, p2_w, p2_b, perm2, xp, adj2);
  hipMemsetAsync(xout, 0, msz, stream);
  scatter_kernel<<<cdiv(3328 * 256, 256), 256, 0, stream>>>(xp, perm1, perm2, 3328, xout, xout_h, xout_l);
  gtpred_kernel<<<cdiv(3328, 256), 256, 0, stream>>>(deg, xdeg, perm2, 3328, out_gt2, out_pred2);
  readout_kernel<<<cdiv(128 * 256, 256), 256, 0, stream>>>(xp, K2_, 1, z);
  decoder(xout, xout_h, xout_l, out_dec2);

  // ---- level 3 ----
  edge_conv(xp, K2_, H_, wcat3, b_mlp3, H_, t1);
  bn_stats_kernel<<<H_, 256, 0, stream>>>(t1, 3328, stats);
  bn_apply_kernel<<<cdiv(3328 * 256, 256), 256, 0, stream>>>(t1, stats, bn3_g, bn3_b, 3328, hbuf);
  sag_kernel<<<B_, 256, 0, stream>>>(hbuf, adj2, K2_, K3_, p3_w, p3_b, perm3, xp, nullptr);
  hipMemsetAsync(xout, 0, msz, stream);
  scatter_kernel<<<cdiv(2688 * 256, 256), 256, 0, stream>>>(xp, perm2, perm3, 2688, xout, xout_h, xout_l);
  gtpred_kernel<<<cdiv(2688, 256), 256, 0, stream>>>(deg, xdeg, perm3, 2688, out_gt3, out_pred3);
  readout_kernel<<<cdiv(128 * 256, 256), 256, 0, stream>>>(xp, K3_, 1, z);
  decoder(xout, xout_h, xout_l, out_dec3);

  // ---- classifier head (thin: M=128) ----
  rowgemm_kernel<<<128, 256, 0, stream>>>(z, lin1_w, lin1_b, z1, 256, 512, 1);
  rowgemm_kernel<<<128, 256, 0, stream>>>(z1, lin2_w, lin2_b, z2, 128, 256, 1);
  wavedot_gemm_kernel<<<cdiv(128 * 2 * 64, 256), 256, 0, stream>>>(z2, lin3_w, lin3_b, logits, 128, 2, 128, 0);
  softmax2_kernel<<<1, 128, 0, stream>>>(logits, out_probs);
}

// Round 11
// 1228.476 us; speedup vs baseline: 1.1012x; 1.0059x over previous
//
#include <hip/hip_runtime.h>
#include <cmath>

#define B_   128
#define N_   39
#define KNN_ 10
#define H_   256
#define K1_  32
#define K2_  26
#define K3_  21

static inline int cdiv(int a, int b) { return (a + b - 1) / b; }

typedef __attribute__((ext_vector_type(8))) short short8;
typedef __attribute__((ext_vector_type(4))) float floatx4;

__device__ inline short f2b(float f) {   // fp32 -> bf16 RNE
  unsigned u = __float_as_uint(f);
  u += 0x7fff + ((u >> 16) & 1);
  return (short)(u >> 16);
}
__device__ inline float b2f(short h) {
  return __uint_as_float(((unsigned)(unsigned short)h) << 16);
}
__device__ inline void f2b2(float v, short& hi, short& lo) {  // split: v ~= hi + lo
  hi = f2b(v);
  lo = f2b(v - b2f(hi));
}

// ---------- wave-wide argmax (64 lanes), ties -> lowest index ----------
__device__ inline void wave_argmax64(float& v, int& j) {
#pragma unroll
  for (int off = 32; off; off >>= 1) {
    float ov = __shfl_down(v, off, 64);
    int   oj = __shfl_down(j, off, 64);
    if (ov > v || (ov == v && oj < j)) { v = ov; j = oj; }
  }
  v = __shfl(v, 0, 64);
  j = __shfl(j, 0, 64);
}

// ---------------- one-shot weight prep + degree (7 tasks on blockIdx.y) ----------------
__global__ void prep_kernel(const float* __restrict__ w1, const float* __restrict__ w2,
                            const float* __restrict__ w3, const float* __restrict__ w6,
                            const float* __restrict__ l4, const float* __restrict__ l5,
                            const float* __restrict__ adj,
                            float* __restrict__ wcat1, float* __restrict__ wcat2,
                            float* __restrict__ wcat3,
                            short* __restrict__ w2h, short* __restrict__ w2l,
                            short* __restrict__ w3h, short* __restrict__ w3l,
                            short* __restrict__ w6h, short* __restrict__ w6l,
                            short* __restrict__ l4h, short* __restrict__ l4l,
                            short* __restrict__ l5h, short* __restrict__ l5l,
                            float* __restrict__ deg) {
  int task = blockIdx.y;
  int t = blockIdx.x * 256 + threadIdx.x;
  if (task == 0) {                        // wcat1 fp32 only (F=39, Hc=256)
    if (t >= 39 * 512) return;
    int k = t >> 9, c = t & 511;
    wcat1[t] = (c < 256) ? w1[k * 256 + c] - w1[(39 + k) * 256 + c]
                         : w1[(39 + k) * 256 + (c - 256)];
  } else if (task == 1) {                 // wcat2 fp32 + splitT (F=256, Hc=256)
    if (t >= 256 * 512) return;
    int k = t >> 9, c = t & 511;
    float v = (c < 256) ? w2[k * 256 + c] - w2[(256 + k) * 256 + c]
                        : w2[(256 + k) * 256 + (c - 256)];
    wcat2[t] = v;
    short hi, lo; f2b2(v, hi, lo);
    w2h[(size_t)c * 256 + k] = hi; w2l[(size_t)c * 256 + k] = lo;
  } else if (task == 2) {                 // wcat3 fp32 + splitT
    if (t >= 256 * 512) return;
    int k = t >> 9, c = t & 511;
    float v = (c < 256) ? w3[k * 256 + c] - w3[(256 + k) * 256 + c]
                        : w3[(256 + k) * 256 + (c - 256)];
    wcat3[t] = v;
    short hi, lo; f2b2(v, hi, lo);
    w3h[(size_t)c * 256 + k] = hi; w3l[(size_t)c * 256 + k] = lo;
  } else if (task == 3) {                 // wcat6 splitT only (F=256, Hc=39)
    if (t >= 256 * 78) return;
    int k = t / 78, c = t - k * 78;
    float v = (c < 39) ? w6[k * 39 + c] - w6[(256 + k) * 39 + c]
                       : w6[(256 + k) * 39 + (c - 39)];
    short hi, lo; f2b2(v, hi, lo);
    w6h[(size_t)c * 256 + k] = hi; w6l[(size_t)c * 256 + k] = lo;
  } else if (task == 4) {                 // lin4 splitT (256 x 256)
    if (t >= 256 * 256) return;
    int k = t >> 8, n = t & 255;
    short hi, lo; f2b2(l4[t], hi, lo);
    l4h[(size_t)n * 256 + k] = hi; l4l[(size_t)n * 256 + k] = lo;
  } else if (task == 5) {                 // lin5 splitT (256 x 128)
    if (t >= 256 * 128) return;
    int k = t >> 7, n = t & 127;
    short hi, lo; f2b2(l5[t], hi, lo);
    l5h[(size_t)n * 256 + k] = hi; l5l[(size_t)n * 256 + k] = lo;
  } else {                                // degree
    if (t >= B_ * N_) return;
    const float* row = adj + (size_t)t * N_;
    float s = 0.f;
    for (int j = 0; j < N_; ++j) s += row[j];
    deg[t] = s;
  }
}

// ---------------- MFMA gram + in-LDS KNN selection (block per graph) ----------------
// Triple-bf16 split (24 mantissa bits): G = X.X^T via 6-term MFMA — fp32-level accuracy;
// exact-zero rows give exactly-zero distances (stable lax.top_k tie semantics).
// Selection: lane owns a row; branchless mask-scan, strict < -> lowest-index ties.
__global__ __launch_bounds__(256) void gram_knn_mfma_kernel(const float* __restrict__ x,
                                                            int n, int F,
                                                            int* __restrict__ idx) {
  __shared__ short xh[48 * 40], xm[48 * 40], xl[48 * 40];
  __shared__ float Gs[48][49];
  __shared__ float diag[48];
  int b = blockIdx.x;
  int tid = threadIdx.x;
  int wave = tid >> 6, lane = tid & 63;
  int lm = lane & 15, lk = (lane >> 4) * 8;
  const float* xb = x + (size_t)b * n * F;
  int Kp = ((F + 31) >> 5) << 5;
  floatx4 acc[3] = {};
  for (int k0 = 0; k0 < Kp; k0 += 32) {
    // stage + triple-split 48x32 chunk
    for (int e = tid; e < 48 * 32; e += 256) {
      int r = e >> 5, kk = e & 31;
      float v = 0.f;
      if (r < n && (k0 + kk) < F) v = xb[(size_t)r * F + k0 + kk];
      short h = f2b(v);
      float r1 = v - b2f(h);
      short m = f2b(r1);
      short l = f2b(r1 - b2f(m));
      xh[r * 40 + kk] = h;
      xm[r * 40 + kk] = m;
      xl[r * 40 + kk] = l;
    }
    __syncthreads();
#pragma unroll
    for (int ai = 0; ai < 3; ++ai) {
      int t = wave + ai * 4;
      if (t < 9) {
        int ti = t / 3, tj = t - ti * 3;
        int ra = (ti * 16 + lm) * 40 + lk;
        int rb = (tj * 16 + lm) * 40 + lk;
        short8 ah = *(const short8*)&xh[ra];
        short8 am = *(const short8*)&xm[ra];
        short8 al = *(const short8*)&xl[ra];
        short8 bh = *(const short8*)&xh[rb];
        short8 bm = *(const short8*)&xm[rb];
        short8 bl = *(const short8*)&xl[rb];
        floatx4 a = acc[ai];
        a = __builtin_amdgcn_mfma_f32_16x16x32_bf16(ah, bh, a, 0, 0, 0);
        a = __builtin_amdgcn_mfma_f32_16x16x32_bf16(ah, bm, a, 0, 0, 0);
        a = __builtin_amdgcn_mfma_f32_16x16x32_bf16(am, bh, a, 0, 0, 0);
        a = __builtin_amdgcn_mfma_f32_16x16x32_bf16(ah, bl, a, 0, 0, 0);
        a = __builtin_amdgcn_mfma_f32_16x16x32_bf16(al, bh, a, 0, 0, 0);
        a = __builtin_amdgcn_mfma_f32_16x16x32_bf16(am, bm, a, 0, 0, 0);
        acc[ai] = a;
      }
    }
    __syncthreads();
  }
  // write G tiles to LDS (C layout: col = lane&15, row = (lane>>4)*4 + r)
#pragma unroll
  for (int ai = 0; ai < 3; ++ai) {
    int t = wave + ai * 4;
    if (t < 9) {
      int ti = t / 3, tj = t - ti * 3;
      int col = tj * 16 + lm;
      int rbase = ti * 16 + (lane >> 4) * 4;
#pragma unroll
      for (int r = 0; r < 4; ++r) Gs[rbase + r][col] = acc[ai][r];
    }
  }
  __syncthreads();
  if (tid < n) diag[tid] = Gs[tid][tid];
  __syncthreads();
  // selection: row = lane*4 + wave (each active lane scans its own row)
  int row = lane * 4 + wave;
  if (row < n) {
    float gii = diag[row];
    unsigned long long mask = 0;
    int* outp = idx + (size_t)(b * n + row) * KNN_;
    for (int kk = 0; kk < KNN_; ++kk) {
      float best = INFINITY;
      int bj = 0;
      for (int j = 0; j < n; ++j) {
        float d = gii + diag[j] - 2.f * Gs[row][j];
        d = ((mask >> j) & 1ull) ? INFINITY : d;
        if (d < best) { best = d; bj = j; }
      }
      outp[kk] = bj;
      mask |= (1ull << bj);
    }
  }
}

// ---------------- fp32 trunk GEMM: 64x64 tile, register-staged pipeline ----------------
#define BM 64
#define BN 64
#define BK 16
__global__ __launch_bounds__(256) void gemm_kernel(
    const float* __restrict__ A, const float* __restrict__ W, const float* __restrict__ bias,
    float* __restrict__ C, int M, int N, int K, int act) {
  __shared__ float As[BK][BM + 4];
  __shared__ float Bs[BK][BN + 4];
  int tid = threadIdx.x;
  int tx = tid & 15, ty = tid >> 4;
  int row0 = blockIdx.y * BM, col0 = blockIdx.x * BN;
  float c[4][4] = {};
  float ra[4], rb[4];
#pragma unroll
  for (int v = 0; v < 4; ++v) {
    int e = tid + v * 256;
    int m = e >> 4, kk = e & 15;
    int row = row0 + m;
    ra[v] = (row < M && kk < K) ? A[(size_t)row * K + kk] : 0.f;
    int kk2 = e >> 6, nn = e & 63;
    int col = col0 + nn;
    rb[v] = (kk2 < K && col < N) ? W[(size_t)kk2 * N + col] : 0.f;
  }
  for (int k0 = 0; k0 < K; k0 += BK) {
#pragma unroll
    for (int v = 0; v < 4; ++v) {
      int e = tid + v * 256;
      As[e & 15][e >> 4] = ra[v];
      Bs[e >> 6][e & 63] = rb[v];
    }
    __syncthreads();
    int k1 = k0 + BK;
    if (k1 < K) {
#pragma unroll
      for (int v = 0; v < 4; ++v) {
        int e = tid + v * 256;
        int m = e >> 4, kk = e & 15;
        int row = row0 + m, k = k1 + kk;
        ra[v] = (row < M && k < K) ? A[(size_t)row * K + k] : 0.f;
        int kk2 = e >> 6, nn = e & 63;
        int k2 = k1 + kk2, col = col0 + nn;
        rb[v] = (k2 < K && col < N) ? W[(size_t)k2 * N + col] : 0.f;
      }
    }
#pragma unroll
    for (int kk = 0; kk < BK; ++kk) {
      float4 av = *(const float4*)&As[kk][ty * 4];
      float4 bv = *(const float4*)&Bs[kk][tx * 4];
      float a[4] = {av.x, av.y, av.z, av.w};
      float b[4] = {bv.x, bv.y, bv.z, bv.w};
#pragma unroll
      for (int i2 = 0; i2 < 4; ++i2)
#pragma unroll
        for (int j = 0; j < 4; ++j) c[i2][j] += a[i2] * b[j];
    }
    __syncthreads();
  }
#pragma unroll
  for (int i2 = 0; i2 < 4; ++i2) {
    int row = row0 + ty * 4 + i2;
    if (row >= M) continue;
#pragma unroll
    for (int j = 0; j < 4; ++j) {
      int col = col0 + tx * 4 + j;
      if (col >= N) continue;
      float v = c[i2][j] + (bias ? bias[col] : 0.f);
      if (act == 1) v = fmaxf(v, 0.f);
      C[(size_t)row * N + col] = v;
    }
  }
}

// ------------- split-bf16 3-pass MFMA GEMM (near-fp32 accuracy, ~2^-16 rel) -------------
__global__ __launch_bounds__(256) void mfma_gemm_split_kernel(
    const short* __restrict__ Ah, const short* __restrict__ Al,
    const short* __restrict__ Wth, const short* __restrict__ Wtl,
    const float* __restrict__ bias,
    float* __restrict__ C, short* __restrict__ Ch, short* __restrict__ Cl,
    int M, int N, int K, int act) {
  __shared__ short Ash[128 * 40];
  __shared__ short Asl[128 * 40];
  __shared__ short Bsh[128 * 40];
  __shared__ short Bsl[128 * 40];
  int tid = threadIdx.x;
  int wave = tid >> 6, lane = tid & 63;
  int wm = wave & 1, wn = wave >> 1;
  int row0 = blockIdx.y * 128, col0 = blockIdx.x * 128;
  floatx4 acc[4][4] = {};
  int lm = lane & 15, lk = (lane >> 4) * 8;
  for (int k0 = 0; k0 < K; k0 += 32) {
    for (int c = tid; c < 512; c += 256) {
      int r = c >> 2, kc = (c & 3) * 8;
      int grow = row0 + r;
      short8 vh = {}, vl = {};
      if (grow < M) {
        vh = *(const short8*)&Ah[(size_t)grow * K + k0 + kc];
        vl = *(const short8*)&Al[(size_t)grow * K + k0 + kc];
      }
      *(short8*)&Ash[r * 40 + kc] = vh;
      *(short8*)&Asl[r * 40 + kc] = vl;
    }
    for (int c = tid; c < 512; c += 256) {
      int r = c >> 2, kc = (c & 3) * 8;
      int gn = col0 + r;
      short8 vh = {}, vl = {};
      if (gn < N) {
        vh = *(const short8*)&Wth[(size_t)gn * K + k0 + kc];
        vl = *(const short8*)&Wtl[(size_t)gn * K + k0 + kc];
      }
      *(short8*)&Bsh[r * 40 + kc] = vh;
      *(short8*)&Bsl[r * 40 + kc] = vl;
    }
    __syncthreads();
    short8 afh[4], afl[4], bfh[4], bfl[4];
#pragma unroll
    for (int mi = 0; mi < 4; ++mi) {
      int ro = (wm * 64 + mi * 16 + lm) * 40 + lk;
      afh[mi] = *(const short8*)&Ash[ro];
      afl[mi] = *(const short8*)&Asl[ro];
    }
#pragma unroll
    for (int ni = 0; ni < 4; ++ni) {
      int ro = (wn * 64 + ni * 16 + lm) * 40 + lk;
      bfh[ni] = *(const short8*)&Bsh[ro];
      bfl[ni] = *(const short8*)&Bsl[ro];
    }
#pragma unroll
    for (int mi = 0; mi < 4; ++mi)
#pragma unroll
      for (int ni = 0; ni < 4; ++ni) {
        acc[mi][ni] = __builtin_amdgcn_mfma_f32_16x16x32_bf16(afh[mi], bfh[ni], acc[mi][ni], 0, 0, 0);
        acc[mi][ni] = __builtin_amdgcn_mfma_f32_16x16x32_bf16(afh[mi], bfl[ni], acc[mi][ni], 0, 0, 0);
        acc[mi][ni] = __builtin_amdgcn_mfma_f32_16x16x32_bf16(afl[mi], bfh[ni], acc[mi][ni], 0, 0, 0);
      }
    __syncthreads();
  }
  int lr = (lane >> 4) * 4;
#pragma unroll
  for (int mi = 0; mi < 4; ++mi)
#pragma unroll
    for (int ni = 0; ni < 4; ++ni) {
      int colg = col0 + wn * 64 + ni * 16 + lm;
      if (colg >= N) continue;
      float bv = bias ? bias[colg] : 0.f;
#pragma unroll
      for (int r = 0; r < 4; ++r) {
        int rowg = row0 + wm * 64 + mi * 16 + lr + r;
        if (rowg >= M) continue;
        float v = acc[mi][ni][r] + bv;
        if (act == 1) v = fmaxf(v, 0.f);
        C[(size_t)rowg * N + colg] = v;
        if (Ch) {
          short hi, lo;
          f2b2(v, hi, lo);
          Ch[(size_t)rowg * N + colg] = hi;
          Cl[(size_t)rowg * N + colg] = lo;
        }
      }
    }
}

// Thin GEMM (small M): one block per row.
__global__ __launch_bounds__(256) void rowgemm_kernel(
    const float* __restrict__ A, const float* __restrict__ W, const float* __restrict__ bias,
    float* __restrict__ C, int N, int K, int act) {
  __shared__ float a[512];
  int row = blockIdx.x;
  for (int k = threadIdx.x; k < K; k += 256) a[k] = A[(size_t)row * K + k];
  __syncthreads();
  for (int c = threadIdx.x; c < N; c += 256) {
    float s = 0.f;
    for (int k = 0; k < K; k += 4) {
      float4 av = *(const float4*)&a[k];
      s += av.x * W[(size_t)k * N + c];
      s += av.y * W[(size_t)(k + 1) * N + c];
      s += av.z * W[(size_t)(k + 2) * N + c];
      s += av.w * W[(size_t)(k + 3) * N + c];
    }
    float v = s + (bias ? bias[c] : 0.f);
    if (act == 1) v = fmaxf(v, 0.f);
    C[(size_t)row * N + c] = v;
  }
}

// one wave per output element (for very small M*N)
__global__ void wavedot_gemm_kernel(const float* __restrict__ A, const float* __restrict__ W,
                                    const float* __restrict__ bias, float* __restrict__ C,
                                    int M, int N, int K, int act) {
  int wid = (blockIdx.x * blockDim.x + threadIdx.x) >> 6;
  int lane = threadIdx.x & 63;
  if (wid >= M * N) return;
  int row = wid / N, col = wid - row * N;
  const float* ar = A + (size_t)row * K;
  float s = 0.f;
  for (int k = lane; k < K; k += 64) s += ar[k] * W[(size_t)k * N + col];
  for (int off = 32; off; off >>= 1) s += __shfl_down(s, off, 64);
  if (lane == 0) {
    float v = s + (bias ? bias[col] : 0.f);
    if (act == 1) v = fmaxf(v, 0.f);
    C[(size_t)row * N + col] = v;
  }
}

// AB row r: [0..Hc) = xi@(Wt-Wb), [Hc..2Hc) = xi@Wb.  out = max_k relu(Ai + b + Bm[nbr]) [tanh]
__global__ void edge_agg_kernel(const float* __restrict__ AB, const float* __restrict__ bias,
                                const int* __restrict__ idx, int n, int Hc, int act,
                                float* __restrict__ out,
                                short* __restrict__ outh, short* __restrict__ outl) {
  int t = blockIdx.x * blockDim.x + threadIdx.x;
  if (t >= B_ * n * Hc) return;
  int r = t / Hc, h = t - r * Hc;
  int b = r / n;
  int s2 = 2 * Hc;
  float av = AB[(size_t)r * s2 + h] + bias[h];
  const int* ir = idx + (size_t)r * KNN_;
  int base = b * n;
  float m = -INFINITY;
  for (int k = 0; k < KNN_; ++k) {
    float v = av + AB[(size_t)(base + ir[k]) * s2 + Hc + h];
    v = fmaxf(v, 0.f);
    m = fmaxf(m, v);
  }
  if (act == 2) m = tanhf(m);
  out[t] = m;
  if (outh) {
    short hi, lo;
    f2b2(m, hi, lo);
    outh[t] = hi;
    outl[t] = lo;
  }
}

__global__ void bn_stats_kernel(const float* __restrict__ x, int M, float* __restrict__ mv) {
  int c = blockIdx.x;
  double s = 0.0, s2 = 0.0;
  for (int r = threadIdx.x; r < M; r += 256) {
    double v = (double)x[(size_t)r * H_ + c];
    s += v; s2 += v * v;
  }
  __shared__ double sh[256], sh2[256];
  sh[threadIdx.x] = s; sh2[threadIdx.x] = s2;
  __syncthreads();
  for (int o = 128; o; o >>= 1) {
    if (threadIdx.x < o) { sh[threadIdx.x] += sh[threadIdx.x + o]; sh2[threadIdx.x] += sh2[threadIdx.x + o]; }
    __syncthreads();
  }
  if (threadIdx.x == 0) {
    double mean = sh[0] / M;
    double var = sh2[0] / M - mean * mean;
    mv[c] = (float)mean;
    mv[H_ + c] = (float)var;
  }
}

__global__ void bn_apply_kernel(const float* __restrict__ x, const float* __restrict__ mv,
                                const float* __restrict__ g, const float* __restrict__ bb,
                                int M, float* __restrict__ out) {
  int t = blockIdx.x * blockDim.x + threadIdx.x;
  if (t >= M * H_) return;
  int h = t & (H_ - 1);
  float mean = mv[h], var = mv[H_ + h];
  float v = (x[t] - mean) * (1.f / sqrtf(var + 1e-5f)) * g[h] + bb[h];
  out[t] = fmaxf(v, 0.f);
}

// one wave per row: y[r] = dot(x[r,:K], w) [+bias] [relu]
__global__ void rowdot_kernel(const float* __restrict__ x, const float* __restrict__ w,
                              int M, int K, const float* __restrict__ bias, int act,
                              float* __restrict__ y) {
  int wid = (blockIdx.x * blockDim.x + threadIdx.x) >> 6;
  int lane = threadIdx.x & 63;
  if (wid >= M) return;
  const float* xr = x + (size_t)wid * K;
  float s = 0.f;
  for (int k = lane; k < K; k += 64) s += xr[k] * w[k];
  for (int off = 32; off; off >>= 1) s += __shfl_down(s, off, 64);
  if (lane == 0) {
    float v = s + (bias ? bias[0] : 0.f);
    if (act == 1) v = fmaxf(v, 0.f);
    y[wid] = v;
  }
}

// ---------------- fused SAG pool: rowdot + gcn score + topk + gather (block per graph) ----------------
__global__ __launch_bounds__(256) void sag_kernel(
    const float* __restrict__ h, const float* __restrict__ adj_in, int n, int k,
    const float* __restrict__ pw, const float* __restrict__ pb,
    int* __restrict__ perm, float* __restrict__ xp, float* __restrict__ adjp) {
  __shared__ float ys[40], dinv[40], sc[40], topv[40];
  __shared__ int locs[40];
  int b = blockIdx.x;
  int wave = threadIdx.x >> 6, lane = threadIdx.x & 63;
  // rowdot: y[i] = h[b,i,:] . pw
  for (int i = wave; i < n; i += 4) {
    const float* xr = h + (size_t)(b * n + i) * H_;
    float s = 0.f;
    for (int kk = lane; kk < H_; kk += 64) s += xr[kk] * pw[kk];
    for (int off = 32; off; off >>= 1) s += __shfl_down(s, off, 64);
    if (lane == 0) ys[i] = s;
  }
  __syncthreads();
  int i = threadIdx.x;
  if (i < n) {
    const float* ar = adj_in + ((size_t)b * n + i) * n;
    float sum = 1.f;
    for (int j = 0; j < n; ++j) sum += ar[j];
    dinv[i] = 1.f / sqrtf(sum);
  }
  __syncthreads();
  if (i < n) {
    const float* ar = adj_in + ((size_t)b * n + i) * n;
    float acc = 0.f;
    for (int j = 0; j < n; ++j) {
      float a = ar[j] + (i == j ? 1.f : 0.f);
      acc += a * dinv[j] * ys[j];
    }
    sc[i] = dinv[i] * acc + pb[0];
  }
  __syncthreads();
  if (wave == 0) {
    float cur = (lane < n) ? sc[lane] : -INFINITY;
    for (int t = 0; t < k; ++t) {
      float rv = cur;
      int rj = (lane < n) ? lane : (1 << 20);
      wave_argmax64(rv, rj);
      if (lane == 0) { topv[t] = rv; locs[t] = rj; perm[b * k + t] = b * n + rj; }
      if (lane == rj) cur = -INFINITY;
    }
  }
  __syncthreads();
  for (int e = threadIdx.x; e < k * H_; e += 256) {
    int r = e >> 8, hh = e & 255;
    xp[((size_t)b * k + r) * H_ + hh] =
        h[((size_t)(b * n + locs[r])) * H_ + hh] * tanhf(topv[r]);
  }
  if (adjp) {
    for (int e = threadIdx.x; e < k * k; e += 256) {
      int t1 = e / k, t2 = e - t1 * k;
      adjp[(size_t)b * k * k + e] = adj_in[((size_t)b * n + locs[t1]) * n + locs[t2]];
    }
  }
}

// dst[i1[i2[r]] or i1[r]] = src[r]; fp32 + split-bf16 (all pre-zeroed)
__global__ void scatter_kernel(const float* __restrict__ src, const int* __restrict__ i1,
                               const int* __restrict__ i2, int rows,
                               float* __restrict__ dst,
                               short* __restrict__ dsth, short* __restrict__ dstl) {
  int t = blockIdx.x * blockDim.x + threadIdx.x;
  if (t >= rows * H_) return;
  int r = t / H_, h = t - r * H_;
  int tgt = i2 ? i1[i2[r]] : i1[r];
  float v = src[t];
  dst[(size_t)tgt * H_ + h] = v;
  short hi, lo;
  f2b2(v, hi, lo);
  dsth[(size_t)tgt * H_ + h] = hi;
  dstl[(size_t)tgt * H_ + h] = lo;
}

__global__ void gtpred_kernel(const float* __restrict__ deg, const float* __restrict__ xdeg,
                              const int* __restrict__ perm, int M,
                              float* __restrict__ gt, float* __restrict__ pred) {
  int t = blockIdx.x * blockDim.x + threadIdx.x;
  if (t >= M) return;
  int p = perm[t];
  gt[t] = deg[p];
  pred[t] = xdeg[p];
}

__global__ void readout_kernel(const float* __restrict__ xp, int k, int acc, float* __restrict__ z) {
  int t = blockIdx.x * blockDim.x + threadIdx.x;
  if (t >= B_ * H_) return;
  int b = t / H_, h = t - b * H_;
  float mx = -INFINITY, sm = 0.f;
  for (int tt = 0; tt < k; ++tt) {
    float v = xp[((size_t)b * k + tt) * H_ + h];
    mx = fmaxf(mx, v);
    sm += v;
  }
  float* zb = z + (size_t)b * 2 * H_;
  float mean = sm / (float)k;
  if (acc) { zb[h] += mx; zb[H_ + h] += mean; }
  else     { zb[h] = mx;  zb[H_ + h] = mean; }
}

__global__ void softmax2_kernel(const float* __restrict__ logits, float* __restrict__ probs) {
  int b = blockIdx.x * blockDim.x + threadIdx.x;
  if (b >= B_) return;
  float a = logits[2 * b], c = logits[2 * b + 1];
  float m = fmaxf(a, c);
  float ea = expf(a - m), ec = expf(c - m);
  float inv = 1.f / (ea + ec);
  probs[2 * b] = ea * inv;
  probs[2 * b + 1] = ec * inv;
}

extern "C" void kernel_launch(void* const* d_in, const int* in_sizes, int n_in,
                              void* d_out, int out_size, void* d_ws, size_t ws_size,
                              hipStream_t stream) {
  auto in = [&](int i) { return (const float*)d_in[i]; };
  const float* x      = in(0);
  const float* adj    = in(1);
  const float* w_mlp1 = in(2);  const float* b_mlp1 = in(3);
  const float* w_mlp2 = in(4);  const float* b_mlp2 = in(5);
  const float* w_mlp3 = in(6);  const float* b_mlp3 = in(7);
  const float* w_mlp6 = in(8);  const float* b_mlp6 = in(9);
  const float* bn1_g = in(10);  const float* bn1_b = in(11);
  const float* bn2_g = in(12);  const float* bn2_b = in(13);
  const float* bn3_g = in(14);  const float* bn3_b = in(15);
  const float* p1_w = in(16);   const float* p1_b = in(17);
  const float* p2_w = in(18);   const float* p2_b = in(19);
  const float* p3_w = in(20);   const float* p3_b = in(21);
  const float* lin1_w = in(22); const float* lin1_b = in(23);
  const float* lin2_w = in(24); const float* lin2_b = in(25);
  const float* lin3_w = in(26); const float* lin3_b = in(27);
  const float* lin4_w = in(28); const float* lin4_b = in(29);
  const float* lin5_w = in(30); const float* lin5_b = in(31);
  const float* lin6_w = in(32); const float* lin6_b = in(33);

  float* out = (float*)d_out;
  float* out_probs = out;                      // 128*2
  float* out_dec1  = out_probs + 256;          // 4992*39
  float* out_dec2  = out_dec1 + 4992 * 39;
  float* out_dec3  = out_dec2 + 4992 * 39;
  float* out_gt1   = out_dec3 + 4992 * 39;     // 4096
  float* out_pred1 = out_gt1 + 4096;           // 4096
  float* out_gt2   = out_pred1 + 4096;         // 3328
  float* out_pred2 = out_gt2 + 3328;
  float* out_gt3   = out_pred2 + 3328;         // 2688
  float* out_pred3 = out_gt3 + 2688;

  char* base = (char*)d_ws;
  size_t off = 0;
  auto allocf = [&](size_t n) -> float* {
    float* p = (float*)(base + off);
    off += ((n * sizeof(float) + 255) & ~(size_t)255);
    return p;
  };
  auto alloci = [&](size_t n) -> int* {
    int* p = (int*)(base + off);
    off += ((n * sizeof(int) + 255) & ~(size_t)255);
    return p;
  };
  auto allocs = [&](size_t n) -> short* {
    short* p = (short*)(base + off);
    off += ((n * sizeof(short) + 255) & ~(size_t)255);
    return p;
  };

  float* wcat1 = allocf(39 * 512);
  float* wcat2 = allocf(256 * 512);
  float* wcat3 = allocf(256 * 512);
  short* wcat2t_h = allocs(512 * 256); short* wcat2t_l = allocs(512 * 256);
  short* wcat3t_h = allocs(512 * 256); short* wcat3t_l = allocs(512 * 256);
  short* wcat6t_h = allocs(78 * 256);  short* wcat6t_l = allocs(78 * 256);
  short* lin4t_h  = allocs(256 * 256); short* lin4t_l  = allocs(256 * 256);
  short* lin5t_h  = allocs(128 * 256); short* lin5t_l  = allocs(128 * 256);
  float* deg   = allocf(4992);
  float* xdeg  = allocf(4992);
  int*   idxb  = alloci(4992 * KNN_);
  float* AB    = allocf((size_t)4992 * 512);
  float* t1    = allocf((size_t)4992 * 256);
  float* t2    = allocf((size_t)4992 * 256);
  float* hbuf  = allocf((size_t)4992 * 256);
  float* xp    = allocf((size_t)4096 * 256);
  size_t ms0 = off;                             // contiguous memset region start
  float* xout  = allocf((size_t)4992 * 256);
  short* xout_h = allocs((size_t)4992 * 256);
  short* xout_l = allocs((size_t)4992 * 256);
  size_t msz = off - ms0;                       // one memset covers xout + both bf16 copies
  short* t1_h   = allocs((size_t)4992 * 256); short* t1_l   = allocs((size_t)4992 * 256);
  short* t2_h   = allocs((size_t)4992 * 256); short* t2_l   = allocs((size_t)4992 * 256);
  float* adj1  = allocf(128 * 32 * 32);
  float* adj2  = allocf(128 * 26 * 26);
  float* stats = allocf(512);
  int* perm1 = alloci(4096); int* perm2 = alloci(3328); int* perm3 = alloci(2688);
  float* z  = allocf(128 * 512);
  float* z1 = allocf(128 * 256);
  float* z2 = allocf(128 * 128);
  float* logits = allocf(256);
  if (off > ws_size) return;

  auto knn = [&](const float* xin, int n, int F) {
    gram_knn_mfma_kernel<<<B_, 256, 0, stream>>>(xin, n, F, idxb);
  };

  // fp32 trunk edge conv (feeds top-k; fp32-faithful MFMA gram)
  auto edge_conv = [&](const float* xin, int n, int F, const float* wcat, const float* bias,
                       int Hout, float* outbuf) {
    int M = B_ * n;
    knn(xin, n, F);
    dim3 gg(cdiv(2 * Hout, BN), cdiv(M, BM));
    gemm_kernel<<<gg, 256, 0, stream>>>(xin, wcat, nullptr, AB, M, 2 * Hout, F, 0);
    edge_agg_kernel<<<cdiv(M * Hout, 256), 256, 0, stream>>>(AB, bias, idxb, n, Hout, 0, outbuf, nullptr, nullptr);
  };
  // split-bf16 decoder edge conv
  auto edge_conv_bf = [&](const float* xin, const short* xh, const short* xl,
                          const short* wth, const short* wtl,
                          const float* bias, int Hout, int act,
                          float* outbuf, short* outh, short* outl) {
    int M = 4992, F = 256;
    knn(xin, N_, F);
    dim3 gg(cdiv(2 * Hout, 128), cdiv(M, 128));
    mfma_gemm_split_kernel<<<gg, 256, 0, stream>>>(xh, xl, wth, wtl, nullptr, AB, nullptr, nullptr,
                                                   M, 2 * Hout, F, 0);
    edge_agg_kernel<<<cdiv(M * Hout, 256), 256, 0, stream>>>(AB, bias, idxb, N_, Hout, act, outbuf, outh, outl);
  };
  auto decoder = [&](const float* xin, const short* xh, const short* xl, float* decout) {
    edge_conv_bf(xin, xh, xl, wcat3t_h, wcat3t_l, b_mlp3, H_, 2, t1, t1_h, t1_l);
    edge_conv_bf(t1, t1_h, t1_l, wcat2t_h, wcat2t_l, b_mlp2, H_, 2, t2, t2_h, t2_l);
    edge_conv_bf(t2, t2_h, t2_l, wcat6t_h, wcat6t_l, b_mlp6, N_, 0, decout, nullptr, nullptr);
  };

  // ---- one-shot prep ----
  prep_kernel<<<dim3(512, 7), 256, 0, stream>>>(
      w_mlp1, w_mlp2, w_mlp3, w_mlp6, lin4_w, lin5_w, adj,
      wcat1, wcat2, wcat3,
      wcat2t_h, wcat2t_l, wcat3t_h, wcat3t_l, wcat6t_h, wcat6t_l,
      lin4t_h, lin4t_l, lin5t_h, lin5t_l, deg);

  // ---- level 1 ----
  edge_conv(x, N_, N_, wcat1, b_mlp1, H_, t1);
  bn_stats_kernel<<<H_, 256, 0, stream>>>(t1, 4992, stats);
  bn_apply_kernel<<<cdiv(4992 * 256, 256), 256, 0, stream>>>(t1, stats, bn1_g, bn1_b, 4992, hbuf);
  sag_kernel<<<B_, 256, 0, stream>>>(hbuf, adj, N_, K1_, p1_w, p1_b, perm1, xp, adj1);
  hipMemsetAsync(xout, 0, msz, stream);
  scatter_kernel<<<cdiv(4096 * 256, 256), 256, 0, stream>>>(xp, perm1, nullptr, 4096, xout, xout_h, xout_l);
  {
    dim3 g4(2, 39);
    mfma_gemm_split_kernel<<<g4, 256, 0, stream>>>(xout_h, xout_l, lin4t_h, lin4t_l, lin4_b,
                                                   t1, t1_h, t1_l, 4992, 256, 256, 1);
    dim3 g5(1, 39);
    mfma_gemm_split_kernel<<<g5, 256, 0, stream>>>(t1_h, t1_l, lin5t_h, lin5t_l, lin5_b,
                                                   t2, nullptr, nullptr, 4992, 128, 256, 1);
  }
  rowdot_kernel<<<cdiv(4992 * 64, 256), 256, 0, stream>>>(t2, lin6_w, 4992, 128, lin6_b, 1, xdeg);
  gtpred_kernel<<<cdiv(4096, 256), 256, 0, stream>>>(deg, xdeg, perm1, 4096, out_gt1, out_pred1);
  readout_kernel<<<cdiv(128 * 256, 256), 256, 0, stream>>>(xp, K1_, 0, z);
  decoder(xout, xout_h, xout_l, out_dec1);

  // ---- level 2 ----
  edge_conv(xp, K1_, H_, wcat2, b_mlp2, H_, t1);
  bn_stats_kernel<<<H_, 256, 0, stream>>>(t1, 4096, stats);
  bn_apply_kernel<<<cdiv(4096 * 256, 256), 256, 0, stream>>>(t1, stats, bn2_g, bn2_b, 4096, hbuf);
  sag_kernel<<<B_, 256, 0, stream>>>(hbuf, adj1, K1_, K2_, p2_w, p2_b, perm2, xp, adj2);
  hipMemsetAsync(xout, 0, msz, stream);
  scatter_kernel<<<cdiv(3328 * 256, 256), 256, 0, stream>>>(xp, perm1, perm2, 3328, xout, xout_h, xout_l);
  gtpred_kernel<<<cdiv(3328, 256), 256, 0, stream>>>(deg, xdeg, perm2, 3328, out_gt2, out_pred2);
  readout_kernel<<<cdiv(128 * 256, 256), 256, 0, stream>>>(xp, K2_, 1, z);
  decoder(xout, xout_h, xout_l, out_dec2);

  // ---- level 3 ----
  edge_conv(xp, K2_, H_, wcat3, b_mlp3, H_, t1);
  bn_stats_kernel<<<H_, 256, 0, stream>>>(t1, 3328, stats);
  bn_apply_kernel<<<cdiv(3328 * 256, 256), 256, 0, stream>>>(t1, stats, bn3_g, bn3_b, 3328, hbuf);
  sag_kernel<<<B_, 256, 0, stream>>>(hbuf, adj2, K2_, K3_, p3_w, p3_b, perm3, xp, nullptr);
  hipMemsetAsync(xout, 0, msz, stream);
  scatter_kernel<<<cdiv(2688 * 256, 256), 256, 0, stream>>>(xp, perm2, perm3, 2688, xout, xout_h, xout_l);
  gtpred_kernel<<<cdiv(2688, 256), 256, 0, stream>>>(deg, xdeg, perm3, 2688, out_gt3, out_pred3);
  readout_kernel<<<cdiv(128 * 256, 256), 256, 0, stream>>>(xp, K3_, 1, z);
  decoder(xout, xout_h, xout_l, out_dec3);

  // ---- classifier head (thin: M=128) ----
  rowgemm_kernel<<<128, 256, 0, stream>>>(z, lin1_w, lin1_b, z1, 256, 512, 1);
  rowgemm_kernel<<<128, 256, 0, stream>>>(z1, lin2_w, lin2_b, z2, 128, 256, 1);
  wavedot_gemm_kernel<<<cdiv(128 * 2 * 64, 256), 256, 0, stream>>>(z2, lin3_w, lin3_b, logits, 128, 2, 128, 0);
  softmax2_kernel<<<1, 128, 0, stream>>>(logits, out_probs);
}

// Round 12
// 981.061 us; speedup vs baseline: 1.3789x; 1.2522x over previous
//
#include <hip/hip_runtime.h>
#include <cmath>

#define B_   128
#define N_   39
#define KNN_ 10
#define H_   256
#define K1_  32
#define K2_  26
#define K3_  21

static inline int cdiv(int a, int b) { return (a + b - 1) / b; }

typedef __attribute__((ext_vector_type(8))) short short8;
typedef __attribute__((ext_vector_type(4))) float floatx4;

__device__ inline short f2b(float f) {   // fp32 -> bf16 RNE
  unsigned u = __float_as_uint(f);
  u += 0x7fff + ((u >> 16) & 1);
  return (short)(u >> 16);
}
__device__ inline float b2f(short h) {
  return __uint_as_float(((unsigned)(unsigned short)h) << 16);
}
__device__ inline void f2b2(float v, short& hi, short& lo) {  // split: v ~= hi + lo
  hi = f2b(v);
  lo = f2b(v - b2f(hi));
}

// ---------- wave-wide argmax (64 lanes), ties -> lowest index ----------
__device__ inline void wave_argmax64(float& v, int& j) {
#pragma unroll
  for (int off = 32; off; off >>= 1) {
    float ov = __shfl_down(v, off, 64);
    int   oj = __shfl_down(j, off, 64);
    if (ov > v || (ov == v && oj < j)) { v = ov; j = oj; }
  }
  v = __shfl(v, 0, 64);
  j = __shfl(j, 0, 64);
}

// ---------------- one-shot weight prep + degree (7 tasks on blockIdx.y) ----------------
__global__ void prep_kernel(const float* __restrict__ w1, const float* __restrict__ w2,
                            const float* __restrict__ w3, const float* __restrict__ w6,
                            const float* __restrict__ l4, const float* __restrict__ l5,
                            const float* __restrict__ adj,
                            float* __restrict__ wcat1, float* __restrict__ wcat2,
                            float* __restrict__ wcat3,
                            short* __restrict__ w2h, short* __restrict__ w2l,
                            short* __restrict__ w3h, short* __restrict__ w3l,
                            short* __restrict__ w6h, short* __restrict__ w6l,
                            short* __restrict__ l4h, short* __restrict__ l4l,
                            short* __restrict__ l5h, short* __restrict__ l5l,
                            float* __restrict__ deg) {
  int task = blockIdx.y;
  int t = blockIdx.x * 256 + threadIdx.x;
  if (task == 0) {                        // wcat1 fp32 only (F=39, Hc=256)
    if (t >= 39 * 512) return;
    int k = t >> 9, c = t & 511;
    wcat1[t] = (c < 256) ? w1[k * 256 + c] - w1[(39 + k) * 256 + c]
                         : w1[(39 + k) * 256 + (c - 256)];
  } else if (task == 1) {                 // wcat2 fp32 + splitT (F=256, Hc=256)
    if (t >= 256 * 512) return;
    int k = t >> 9, c = t & 511;
    float v = (c < 256) ? w2[k * 256 + c] - w2[(256 + k) * 256 + c]
                        : w2[(256 + k) * 256 + (c - 256)];
    wcat2[t] = v;
    short hi, lo; f2b2(v, hi, lo);
    w2h[(size_t)c * 256 + k] = hi; w2l[(size_t)c * 256 + k] = lo;
  } else if (task == 2) {                 // wcat3 fp32 + splitT
    if (t >= 256 * 512) return;
    int k = t >> 9, c = t & 511;
    float v = (c < 256) ? w3[k * 256 + c] - w3[(256 + k) * 256 + c]
                        : w3[(256 + k) * 256 + (c - 256)];
    wcat3[t] = v;
    short hi, lo; f2b2(v, hi, lo);
    w3h[(size_t)c * 256 + k] = hi; w3l[(size_t)c * 256 + k] = lo;
  } else if (task == 3) {                 // wcat6 splitT only (F=256, Hc=39)
    if (t >= 256 * 78) return;
    int k = t / 78, c = t - k * 78;
    float v = (c < 39) ? w6[k * 39 + c] - w6[(256 + k) * 39 + c]
                       : w6[(256 + k) * 39 + (c - 39)];
    short hi, lo; f2b2(v, hi, lo);
    w6h[(size_t)c * 256 + k] = hi; w6l[(size_t)c * 256 + k] = lo;
  } else if (task == 4) {                 // lin4 splitT (256 x 256)
    if (t >= 256 * 256) return;
    int k = t >> 8, n = t & 255;
    short hi, lo; f2b2(l4[t], hi, lo);
    l4h[(size_t)n * 256 + k] = hi; l4l[(size_t)n * 256 + k] = lo;
  } else if (task == 5) {                 // lin5 splitT (256 x 128)
    if (t >= 256 * 128) return;
    int k = t >> 7, n = t & 127;
    short hi, lo; f2b2(l5[t], hi, lo);
    l5h[(size_t)n * 256 + k] = hi; l5l[(size_t)n * 256 + k] = lo;
  } else {                                // degree
    if (t >= B_ * N_) return;
    const float* row = adj + (size_t)t * N_;
    float s = 0.f;
    for (int j = 0; j < N_; ++j) s += row[j];
    deg[t] = s;
  }
}

// ---------------- MFMA gram + in-LDS KNN selection (block per graph, 512 thr) ----------------
// Triple-bf16 split (24 mantissa bits) -> fp32-level accuracy; exact-zero rows stay exactly 0
// (stable lax.top_k tie semantics). nt tile-skip for n<=32.
__global__ __launch_bounds__(512) void gram_knn_mfma_kernel(const float* __restrict__ x,
                                                            int n, int F,
                                                            int* __restrict__ idx) {
  __shared__ short xh[48 * 40], xm[48 * 40], xl[48 * 40];
  __shared__ float Gs[48][49];
  __shared__ float diag[48];
  int b = blockIdx.x;
  int tid = threadIdx.x;
  int wave = tid >> 6, lane = tid & 63;
  int lm = lane & 15, lk = (lane >> 4) * 8;
  const float* xb = x + (size_t)b * n * F;
  int nt = (n + 15) >> 4;
  int tasks = nt * nt;
  int Kp = ((F + 31) >> 5) << 5;
  floatx4 acc[2] = {};
  for (int k0 = 0; k0 < Kp; k0 += 32) {
    for (int e = tid; e < 48 * 32; e += 512) {
      int r = e >> 5, kk = e & 31;
      float v = 0.f;
      if (r < n && (k0 + kk) < F) v = xb[(size_t)r * F + k0 + kk];
      short h = f2b(v);
      float r1 = v - b2f(h);
      short m = f2b(r1);
      short l = f2b(r1 - b2f(m));
      xh[r * 40 + kk] = h;
      xm[r * 40 + kk] = m;
      xl[r * 40 + kk] = l;
    }
    __syncthreads();
#pragma unroll
    for (int ai = 0; ai < 2; ++ai) {
      int t = wave + ai * 8;
      if (t < tasks) {
        int ti = t / nt, tj = t - ti * nt;
        int ra = (ti * 16 + lm) * 40 + lk;
        int rb = (tj * 16 + lm) * 40 + lk;
        short8 ah = *(const short8*)&xh[ra];
        short8 am = *(const short8*)&xm[ra];
        short8 al = *(const short8*)&xl[ra];
        short8 bh = *(const short8*)&xh[rb];
        short8 bm = *(const short8*)&xm[rb];
        short8 bl = *(const short8*)&xl[rb];
        floatx4 a = acc[ai];
        a = __builtin_amdgcn_mfma_f32_16x16x32_bf16(ah, bh, a, 0, 0, 0);
        a = __builtin_amdgcn_mfma_f32_16x16x32_bf16(ah, bm, a, 0, 0, 0);
        a = __builtin_amdgcn_mfma_f32_16x16x32_bf16(am, bh, a, 0, 0, 0);
        a = __builtin_amdgcn_mfma_f32_16x16x32_bf16(ah, bl, a, 0, 0, 0);
        a = __builtin_amdgcn_mfma_f32_16x16x32_bf16(al, bh, a, 0, 0, 0);
        a = __builtin_amdgcn_mfma_f32_16x16x32_bf16(am, bm, a, 0, 0, 0);
        acc[ai] = a;
      }
    }
    __syncthreads();
  }
#pragma unroll
  for (int ai = 0; ai < 2; ++ai) {
    int t = wave + ai * 8;
    if (t < tasks) {
      int ti = t / nt, tj = t - ti * nt;
      int col = tj * 16 + lm;
      int rbase = ti * 16 + (lane >> 4) * 4;
#pragma unroll
      for (int r = 0; r < 4; ++r) Gs[rbase + r][col] = acc[ai][r];
    }
  }
  __syncthreads();
  if (tid < 48) diag[tid] = (tid < n) ? Gs[tid][tid] : INFINITY;
  __syncthreads();
  int row = lane * 8 + wave;   // lanes 0..4 active per wave
  if (row < n) {
    float gii = diag[row];
    unsigned long long mask = 0;
    int* outp = idx + (size_t)(b * n + row) * KNN_;
    for (int kk = 0; kk < KNN_; ++kk) {
      float best = INFINITY;
      int bj = 0;
      for (int j = 0; j < n; ++j) {
        float d = gii + diag[j] - 2.f * Gs[row][j];
        d = ((mask >> j) & 1ull) ? INFINITY : d;
        if (d < best) { best = d; bj = j; }
      }
      outp[kk] = bj;
      mask |= (1ull << bj);
    }
  }
}

// ---------------- fp32 trunk GEMM: 64x64 tile, register-staged pipeline ----------------
#define BM 64
#define BN 64
#define BK 16
__global__ __launch_bounds__(256) void gemm_kernel(
    const float* __restrict__ A, const float* __restrict__ W, const float* __restrict__ bias,
    float* __restrict__ C, int M, int N, int K, int act) {
  __shared__ float As[BK][BM + 4];
  __shared__ float Bs[BK][BN + 4];
  int tid = threadIdx.x;
  int tx = tid & 15, ty = tid >> 4;
  int row0 = blockIdx.y * BM, col0 = blockIdx.x * BN;
  float c[4][4] = {};
  float ra[4], rb[4];
#pragma unroll
  for (int v = 0; v < 4; ++v) {
    int e = tid + v * 256;
    int m = e >> 4, kk = e & 15;
    int row = row0 + m;
    ra[v] = (row < M && kk < K) ? A[(size_t)row * K + kk] : 0.f;
    int kk2 = e >> 6, nn = e & 63;
    int col = col0 + nn;
    rb[v] = (kk2 < K && col < N) ? W[(size_t)kk2 * N + col] : 0.f;
  }
  for (int k0 = 0; k0 < K; k0 += BK) {
#pragma unroll
    for (int v = 0; v < 4; ++v) {
      int e = tid + v * 256;
      As[e & 15][e >> 4] = ra[v];
      Bs[e >> 6][e & 63] = rb[v];
    }
    __syncthreads();
    int k1 = k0 + BK;
    if (k1 < K) {
#pragma unroll
      for (int v = 0; v < 4; ++v) {
        int e = tid + v * 256;
        int m = e >> 4, kk = e & 15;
        int row = row0 + m, k = k1 + kk;
        ra[v] = (row < M && k < K) ? A[(size_t)row * K + k] : 0.f;
        int kk2 = e >> 6, nn = e & 63;
        int k2 = k1 + kk2, col = col0 + nn;
        rb[v] = (k2 < K && col < N) ? W[(size_t)k2 * N + col] : 0.f;
      }
    }
#pragma unroll
    for (int kk = 0; kk < BK; ++kk) {
      float4 av = *(const float4*)&As[kk][ty * 4];
      float4 bv = *(const float4*)&Bs[kk][tx * 4];
      float a[4] = {av.x, av.y, av.z, av.w};
      float b[4] = {bv.x, bv.y, bv.z, bv.w};
#pragma unroll
      for (int i2 = 0; i2 < 4; ++i2)
#pragma unroll
        for (int j = 0; j < 4; ++j) c[i2][j] += a[i2] * b[j];
    }
    __syncthreads();
  }
#pragma unroll
  for (int i2 = 0; i2 < 4; ++i2) {
    int row = row0 + ty * 4 + i2;
    if (row >= M) continue;
#pragma unroll
    for (int j = 0; j < 4; ++j) {
      int col = col0 + tx * 4 + j;
      if (col >= N) continue;
      float v = c[i2][j] + (bias ? bias[col] : 0.f);
      if (act == 1) v = fmaxf(v, 0.f);
      C[(size_t)row * N + col] = v;
    }
  }
}

// ------------- split-bf16 3-pass MFMA GEMM (near-fp32 accuracy, ~2^-16 rel) -------------
__global__ __launch_bounds__(256) void mfma_gemm_split_kernel(
    const short* __restrict__ Ah, const short* __restrict__ Al,
    const short* __restrict__ Wth, const short* __restrict__ Wtl,
    const float* __restrict__ bias,
    float* __restrict__ C, short* __restrict__ Ch, short* __restrict__ Cl,
    int M, int N, int K, int act) {
  __shared__ short Ash[128 * 40];
  __shared__ short Asl[128 * 40];
  __shared__ short Bsh[128 * 40];
  __shared__ short Bsl[128 * 40];
  int tid = threadIdx.x;
  int wave = tid >> 6, lane = tid & 63;
  int wm = wave & 1, wn = wave >> 1;
  int row0 = blockIdx.y * 128, col0 = blockIdx.x * 128;
  floatx4 acc[4][4] = {};
  int lm = lane & 15, lk = (lane >> 4) * 8;
  for (int k0 = 0; k0 < K; k0 += 32) {
    for (int c = tid; c < 512; c += 256) {
      int r = c >> 2, kc = (c & 3) * 8;
      int grow = row0 + r;
      short8 vh = {}, vl = {};
      if (grow < M) {
        vh = *(const short8*)&Ah[(size_t)grow * K + k0 + kc];
        vl = *(const short8*)&Al[(size_t)grow * K + k0 + kc];
      }
      *(short8*)&Ash[r * 40 + kc] = vh;
      *(short8*)&Asl[r * 40 + kc] = vl;
    }
    for (int c = tid; c < 512; c += 256) {
      int r = c >> 2, kc = (c & 3) * 8;
      int gn = col0 + r;
      short8 vh = {}, vl = {};
      if (gn < N) {
        vh = *(const short8*)&Wth[(size_t)gn * K + k0 + kc];
        vl = *(const short8*)&Wtl[(size_t)gn * K + k0 + kc];
      }
      *(short8*)&Bsh[r * 40 + kc] = vh;
      *(short8*)&Bsl[r * 40 + kc] = vl;
    }
    __syncthreads();
    short8 afh[4], afl[4], bfh[4], bfl[4];
#pragma unroll
    for (int mi = 0; mi < 4; ++mi) {
      int ro = (wm * 64 + mi * 16 + lm) * 40 + lk;
      afh[mi] = *(const short8*)&Ash[ro];
      afl[mi] = *(const short8*)&Asl[ro];
    }
#pragma unroll
    for (int ni = 0; ni < 4; ++ni) {
      int ro = (wn * 64 + ni * 16 + lm) * 40 + lk;
      bfh[ni] = *(const short8*)&Bsh[ro];
      bfl[ni] = *(const short8*)&Bsl[ro];
    }
#pragma unroll
    for (int mi = 0; mi < 4; ++mi)
#pragma unroll
      for (int ni = 0; ni < 4; ++ni) {
        acc[mi][ni] = __builtin_amdgcn_mfma_f32_16x16x32_bf16(afh[mi], bfh[ni], acc[mi][ni], 0, 0, 0);
        acc[mi][ni] = __builtin_amdgcn_mfma_f32_16x16x32_bf16(afh[mi], bfl[ni], acc[mi][ni], 0, 0, 0);
        acc[mi][ni] = __builtin_amdgcn_mfma_f32_16x16x32_bf16(afl[mi], bfh[ni], acc[mi][ni], 0, 0, 0);
      }
    __syncthreads();
  }
  int lr = (lane >> 4) * 4;
#pragma unroll
  for (int mi = 0; mi < 4; ++mi)
#pragma unroll
    for (int ni = 0; ni < 4; ++ni) {
      int colg = col0 + wn * 64 + ni * 16 + lm;
      if (colg >= N) continue;
      float bv = bias ? bias[colg] : 0.f;
#pragma unroll
      for (int r = 0; r < 4; ++r) {
        int rowg = row0 + wm * 64 + mi * 16 + lr + r;
        if (rowg >= M) continue;
        float v = acc[mi][ni][r] + bv;
        if (act == 1) v = fmaxf(v, 0.f);
        C[(size_t)rowg * N + colg] = v;
        if (Ch) {
          short hi, lo;
          f2b2(v, hi, lo);
          Ch[(size_t)rowg * N + colg] = hi;
          Cl[(size_t)rowg * N + colg] = lo;
        }
      }
    }
}

// Thin GEMM (small M): one block per row.
__global__ __launch_bounds__(256) void rowgemm_kernel(
    const float* __restrict__ A, const float* __restrict__ W, const float* __restrict__ bias,
    float* __restrict__ C, int N, int K, int act) {
  __shared__ float a[512];
  int row = blockIdx.x;
  for (int k = threadIdx.x; k < K; k += 256) a[k] = A[(size_t)row * K + k];
  __syncthreads();
  for (int c = threadIdx.x; c < N; c += 256) {
    float s = 0.f;
    for (int k = 0; k < K; k += 4) {
      float4 av = *(const float4*)&a[k];
      s += av.x * W[(size_t)k * N + c];
      s += av.y * W[(size_t)(k + 1) * N + c];
      s += av.z * W[(size_t)(k + 2) * N + c];
      s += av.w * W[(size_t)(k + 3) * N + c];
    }
    float v = s + (bias ? bias[c] : 0.f);
    if (act == 1) v = fmaxf(v, 0.f);
    C[(size_t)row * N + c] = v;
  }
}

// one wave per output element (for very small M*N)
__global__ void wavedot_gemm_kernel(const float* __restrict__ A, const float* __restrict__ W,
                                    const float* __restrict__ bias, float* __restrict__ C,
                                    int M, int N, int K, int act) {
  int wid = (blockIdx.x * blockDim.x + threadIdx.x) >> 6;
  int lane = threadIdx.x & 63;
  if (wid >= M * N) return;
  int row = wid / N, col = wid - row * N;
  const float* ar = A + (size_t)row * K;
  float s = 0.f;
  for (int k = lane; k < K; k += 64) s += ar[k] * W[(size_t)k * N + col];
  for (int off = 32; off; off >>= 1) s += __shfl_down(s, off, 64);
  if (lane == 0) {
    float v = s + (bias ? bias[col] : 0.f);
    if (act == 1) v = fmaxf(v, 0.f);
    C[(size_t)row * N + col] = v;
  }
}

// AB row r: [0..Hc) = xi@(Wt-Wb), [Hc..2Hc) = xi@Wb.  out = max_k relu(Ai + b + Bm[nbr]) [tanh]
__global__ void edge_agg_kernel(const float* __restrict__ AB, const float* __restrict__ bias,
                                const int* __restrict__ idx, int n, int Hc, int act,
                                float* __restrict__ out,
                                short* __restrict__ outh, short* __restrict__ outl) {
  int t = blockIdx.x * blockDim.x + threadIdx.x;
  if (t >= B_ * n * Hc) return;
  int r = t / Hc, h = t - r * Hc;
  int b = r / n;
  int s2 = 2 * Hc;
  float av = AB[(size_t)r * s2 + h] + bias[h];
  const int* ir = idx + (size_t)r * KNN_;
  int base = b * n;
  float m = -INFINITY;
  for (int k = 0; k < KNN_; ++k) {
    float v = av + AB[(size_t)(base + ir[k]) * s2 + Hc + h];
    v = fmaxf(v, 0.f);
    m = fmaxf(m, v);
  }
  if (act == 2) m = tanhf(m);
  out[t] = m;
  if (outh) {
    short hi, lo;
    f2b2(m, hi, lo);
    outh[t] = hi;
    outl[t] = lo;
  }
}

__global__ void bn_stats_kernel(const float* __restrict__ x, int M, float* __restrict__ mv) {
  int c = blockIdx.x;
  double s = 0.0, s2 = 0.0;
  for (int r = threadIdx.x; r < M; r += 256) {
    double v = (double)x[(size_t)r * H_ + c];
    s += v; s2 += v * v;
  }
  __shared__ double sh[256], sh2[256];
  sh[threadIdx.x] = s; sh2[threadIdx.x] = s2;
  __syncthreads();
  for (int o = 128; o; o >>= 1) {
    if (threadIdx.x < o) { sh[threadIdx.x] += sh[threadIdx.x + o]; sh2[threadIdx.x] += sh2[threadIdx.x + o]; }
    __syncthreads();
  }
  if (threadIdx.x == 0) {
    double mean = sh[0] / M;
    double var = sh2[0] / M - mean * mean;
    mv[c] = (float)mean;
    mv[H_ + c] = (float)var;
  }
}

__global__ void bn_apply_kernel(const float* __restrict__ x, const float* __restrict__ mv,
                                const float* __restrict__ g, const float* __restrict__ bb,
                                int M, float* __restrict__ out) {
  int t = blockIdx.x * blockDim.x + threadIdx.x;
  if (t >= M * H_) return;
  int h = t & (H_ - 1);
  float mean = mv[h], var = mv[H_ + h];
  float v = (x[t] - mean) * (1.f / sqrtf(var + 1e-5f)) * g[h] + bb[h];
  out[t] = fmaxf(v, 0.f);
}

// one wave per row: y[r] = dot(x[r,:K], w) [+bias] [relu]
__global__ void rowdot_kernel(const float* __restrict__ x, const float* __restrict__ w,
                              int M, int K, const float* __restrict__ bias, int act,
                              float* __restrict__ y) {
  int wid = (blockIdx.x * blockDim.x + threadIdx.x) >> 6;
  int lane = threadIdx.x & 63;
  if (wid >= M) return;
  const float* xr = x + (size_t)wid * K;
  float s = 0.f;
  for (int k = lane; k < K; k += 64) s += xr[k] * w[k];
  for (int off = 32; off; off >>= 1) s += __shfl_down(s, off, 64);
  if (lane == 0) {
    float v = s + (bias ? bias[0] : 0.f);
    if (act == 1) v = fmaxf(v, 0.f);
    y[wid] = v;
  }
}

// -------- fused SAG pool + readout: rowdot + gcn + topk + gather + max/mean (block/graph) --------
__global__ __launch_bounds__(256) void sag_kernel(
    const float* __restrict__ hfeat, const float* __restrict__ adj_in, int n, int k,
    const float* __restrict__ pw, const float* __restrict__ pb,
    int* __restrict__ perm, float* __restrict__ xp, float* __restrict__ adjp,
    float* __restrict__ z, int accum) {
  __shared__ float ys[40], dinv[40], sc[40], tant[40];
  __shared__ int locs[40];
  int b = blockIdx.x;
  int wave = threadIdx.x >> 6, lane = threadIdx.x & 63;
  for (int i = wave; i < n; i += 4) {
    const float* xr = hfeat + (size_t)(b * n + i) * H_;
    float s = 0.f;
    for (int kk = lane; kk < H_; kk += 64) s += xr[kk] * pw[kk];
    for (int off = 32; off; off >>= 1) s += __shfl_down(s, off, 64);
    if (lane == 0) ys[i] = s;
  }
  __syncthreads();
  int i = threadIdx.x;
  if (i < n) {
    const float* ar = adj_in + ((size_t)b * n + i) * n;
    float sum = 1.f;
    for (int j = 0; j < n; ++j) sum += ar[j];
    dinv[i] = 1.f / sqrtf(sum);
  }
  __syncthreads();
  if (i < n) {
    const float* ar = adj_in + ((size_t)b * n + i) * n;
    float acc = 0.f;
    for (int j = 0; j < n; ++j) {
      float a = ar[j] + (i == j ? 1.f : 0.f);
      acc += a * dinv[j] * ys[j];
    }
    sc[i] = dinv[i] * acc + pb[0];
  }
  __syncthreads();
  if (wave == 0) {
    float cur = (lane < n) ? sc[lane] : -INFINITY;
    for (int t = 0; t < k; ++t) {
      float rv = cur;
      int rj = (lane < n) ? lane : (1 << 20);
      wave_argmax64(rv, rj);
      if (lane == 0) { tant[t] = tanhf(rv); locs[t] = rj; perm[b * k + t] = b * n + rj; }
      if (lane == rj) cur = -INFINITY;
    }
  }
  __syncthreads();
  // gather + readout: thread = feature column
  int hc = threadIdx.x;   // H_ == 256 == blockDim
  float mx = -INFINITY, sm = 0.f;
  for (int r = 0; r < k; ++r) {
    float v = hfeat[((size_t)(b * n + locs[r])) * H_ + hc] * tant[r];
    xp[((size_t)b * k + r) * H_ + hc] = v;
    mx = fmaxf(mx, v);
    sm += v;
  }
  float* zb = z + (size_t)b * 2 * H_;
  float mean = sm / (float)k;
  if (accum) { zb[hc] += mx; zb[H_ + hc] += mean; }
  else       { zb[hc] = mx;  zb[H_ + hc] = mean; }
  if (adjp) {
    for (int e = threadIdx.x; e < k * k; e += 256) {
      int t1 = e / k, t2 = e - t1 * k;
      adjp[(size_t)b * k * k + e] = adj_in[((size_t)b * n + locs[t1]) * n + locs[t2]];
    }
  }
}

// dst[i1[i2[r]] or i1[r]] = src[r]; fp32 + split-bf16 (all pre-zeroed)
__global__ void scatter_kernel(const float* __restrict__ src, const int* __restrict__ i1,
                               const int* __restrict__ i2, int rows,
                               float* __restrict__ dst,
                               short* __restrict__ dsth, short* __restrict__ dstl) {
  int t = blockIdx.x * blockDim.x + threadIdx.x;
  if (t >= rows * H_) return;
  int r = t / H_, h = t - r * H_;
  int tgt = i2 ? i1[i2[r]] : i1[r];
  float v = src[t];
  dst[(size_t)tgt * H_ + h] = v;
  short hi, lo;
  f2b2(v, hi, lo);
  dsth[(size_t)tgt * H_ + h] = hi;
  dstl[(size_t)tgt * H_ + h] = lo;
}

__global__ void gtpred_kernel(const float* __restrict__ deg, const float* __restrict__ xdeg,
                              const int* __restrict__ perm, int M,
                              float* __restrict__ gt, float* __restrict__ pred) {
  int t = blockIdx.x * blockDim.x + threadIdx.x;
  if (t >= M) return;
  int p = perm[t];
  gt[t] = deg[p];
  pred[t] = xdeg[p];
}

__global__ void softmax2_kernel(const float* __restrict__ logits, float* __restrict__ probs) {
  int b = blockIdx.x * blockDim.x + threadIdx.x;
  if (b >= B_) return;
  float a = logits[2 * b], c = logits[2 * b + 1];
  float m = fmaxf(a, c);
  float ea = expf(a - m), ec = expf(c - m);
  float inv = 1.f / (ea + ec);
  probs[2 * b] = ea * inv;
  probs[2 * b + 1] = ec * inv;
}

extern "C" void kernel_launch(void* const* d_in, const int* in_sizes, int n_in,
                              void* d_out, int out_size, void* d_ws, size_t ws_size,
                              hipStream_t stream) {
  auto in = [&](int i) { return (const float*)d_in[i]; };
  const float* x      = in(0);
  const float* adj    = in(1);
  const float* w_mlp1 = in(2);  const float* b_mlp1 = in(3);
  const float* w_mlp2 = in(4);  const float* b_mlp2 = in(5);
  const float* w_mlp3 = in(6);  const float* b_mlp3 = in(7);
  const float* w_mlp6 = in(8);  const float* b_mlp6 = in(9);
  const float* bn1_g = in(10);  const float* bn1_b = in(11);
  const float* bn2_g = in(12);  const float* bn2_b = in(13);
  const float* bn3_g = in(14);  const float* bn3_b = in(15);
  const float* p1_w = in(16);   const float* p1_b = in(17);
  const float* p2_w = in(18);   const float* p2_b = in(19);
  const float* p3_w = in(20);   const float* p3_b = in(21);
  const float* lin1_w = in(22); const float* lin1_b = in(23);
  const float* lin2_w = in(24); const float* lin2_b = in(25);
  const float* lin3_w = in(26); const float* lin3_b = in(27);
  const float* lin4_w = in(28); const float* lin4_b = in(29);
  const float* lin5_w = in(30); const float* lin5_b = in(31);
  const float* lin6_w = in(32); const float* lin6_b = in(33);

  float* out = (float*)d_out;
  float* out_probs = out;                      // 128*2
  float* out_dec1  = out_probs + 256;          // 3 x 4992*39 contiguous
  float* out_gt1   = out_dec1 + 3 * 4992 * 39;
  float* out_pred1 = out_gt1 + 4096;
  float* out_gt2   = out_pred1 + 4096;
  float* out_pred2 = out_gt2 + 3328;
  float* out_gt3   = out_pred2 + 3328;
  float* out_pred3 = out_gt3 + 2688;

  char* base = (char*)d_ws;
  size_t off = 0;
  auto allocf = [&](size_t n) -> float* {
    float* p = (float*)(base + off);
    off += ((n * sizeof(float) + 255) & ~(size_t)255);
    return p;
  };
  auto alloci = [&](size_t n) -> int* {
    int* p = (int*)(base + off);
    off += ((n * sizeof(int) + 255) & ~(size_t)255);
    return p;
  };
  auto allocs = [&](size_t n) -> short* {
    short* p = (short*)(base + off);
    off += ((n * sizeof(short) + 255) & ~(size_t)255);
    return p;
  };

  const size_t S = (size_t)4992 * 256;   // per-decoder slice (elements)
  const int SI = 4992 * KNN_;

  float* wcat1 = allocf(39 * 512);
  float* wcat2 = allocf(256 * 512);
  float* wcat3 = allocf(256 * 512);
  short* wcat2t_h = allocs(512 * 256); short* wcat2t_l = allocs(512 * 256);
  short* wcat3t_h = allocs(512 * 256); short* wcat3t_l = allocs(512 * 256);
  short* wcat6t_h = allocs(78 * 256);  short* wcat6t_l = allocs(78 * 256);
  short* lin4t_h  = allocs(256 * 256); short* lin4t_l  = allocs(256 * 256);
  short* lin5t_h  = allocs(128 * 256); short* lin5t_l  = allocs(128 * 256);
  float* deg   = allocf(4992);
  float* xdeg  = allocf(4992);
  int*   idxb  = alloci(3 * SI);
  float* AB    = allocf((size_t)4992 * 512);
  float* hbuf  = allocf(S);
  float* xp    = allocf((size_t)4096 * 256);
  size_t ms0 = off;                            // single memset region
  float* xoutb   = allocf(3 * S);              // 3 slices fp32
  short* xoutb_h = allocs(3 * S);
  short* xoutb_l = allocs(3 * S);
  size_t msz = off - ms0;
  float* t1b   = allocf(3 * S);
  short* t1b_h = allocs(3 * S);
  short* t1b_l = allocs(3 * S);
  float* adj1  = allocf(128 * 32 * 32);
  float* adj2  = allocf(128 * 26 * 26);
  float* stats = allocf(512);
  int* perm1 = alloci(4096); int* perm2 = alloci(3328); int* perm3 = alloci(2688);
  float* z  = allocf(128 * 512);
  float* z1 = allocf(128 * 256);
  float* z2 = allocf(128 * 128);
  float* logits = allocf(256);
  if (off > ws_size) return;

  // aliases: trunk pre-BN buffer + degree-head temporaries live in t1b (dead when decoders run)
  float* trunk_t1 = t1b;                 // 4992x256
  float* deg_t2   = t1b + S;             // 4992x128 fits
  short* dh_t1h   = t1b_h;
  short* dh_t1l   = t1b_l;
  // t2b aliases xoutb (xoutb dead after decoder stage 1 gemm)
  float* t2b = xoutb; short* t2b_h = xoutb_h; short* t2b_l = xoutb_l;

  auto knn = [&](const float* xin, int n, int graphs, int* idxp) {
    gram_knn_mfma_kernel<<<graphs, 512, 0, stream>>>(xin, n, 256, idxp);
  };

  // fp32 trunk edge conv (feeds top-k)
  auto edge_conv = [&](const float* xin, int n, int F, const float* wcat, const float* bias,
                       float* outbuf) {
    int M = B_ * n;
    gram_knn_mfma_kernel<<<B_, 512, 0, stream>>>(xin, n, F, idxb);
    dim3 gg(cdiv(512, BN), cdiv(M, BM));
    gemm_kernel<<<gg, 256, 0, stream>>>(xin, wcat, nullptr, AB, M, 512, F, 0);
    edge_agg_kernel<<<cdiv(M * 256, 256), 256, 0, stream>>>(AB, bias, idxb, n, 256, 0, outbuf, nullptr, nullptr);
  };

  // ---- one-shot prep + zero the scatter targets ----
  prep_kernel<<<dim3(512, 7), 256, 0, stream>>>(
      w_mlp1, w_mlp2, w_mlp3, w_mlp6, lin4_w, lin5_w, adj,
      wcat1, wcat2, wcat3,
      wcat2t_h, wcat2t_l, wcat3t_h, wcat3t_l, wcat6t_h, wcat6t_l,
      lin4t_h, lin4t_l, lin5t_h, lin5t_l, deg);
  hipMemsetAsync(xoutb, 0, msz, stream);

  // ---- level 1 ----
  edge_conv(x, N_, N_, wcat1, b_mlp1, trunk_t1);
  bn_stats_kernel<<<H_, 256, 0, stream>>>(trunk_t1, 4992, stats);
  bn_apply_kernel<<<cdiv(4992 * 256, 256), 256, 0, stream>>>(trunk_t1, stats, bn1_g, bn1_b, 4992, hbuf);
  sag_kernel<<<B_, 256, 0, stream>>>(hbuf, adj, N_, K1_, p1_w, p1_b, perm1, xp, adj1, z, 0);
  scatter_kernel<<<cdiv(4096 * 256, 256), 256, 0, stream>>>(xp, perm1, nullptr, 4096, xoutb, xoutb_h, xoutb_l);
  {  // degree head from x_out1 (split-bf16 MFMA)
    dim3 g4(2, 39);
    mfma_gemm_split_kernel<<<g4, 256, 0, stream>>>(xoutb_h, xoutb_l, lin4t_h, lin4t_l, lin4_b,
                                                   trunk_t1, dh_t1h, dh_t1l, 4992, 256, 256, 1);
    dim3 g5(1, 39);
    mfma_gemm_split_kernel<<<g5, 256, 0, stream>>>(dh_t1h, dh_t1l, lin5t_h, lin5t_l, lin5_b,
                                                   deg_t2, nullptr, nullptr, 4992, 128, 256, 1);
  }
  rowdot_kernel<<<cdiv(4992 * 64, 256), 256, 0, stream>>>(deg_t2, lin6_w, 4992, 128, lin6_b, 1, xdeg);
  gtpred_kernel<<<cdiv(4096, 256), 256, 0, stream>>>(deg, xdeg, perm1, 4096, out_gt1, out_pred1);

  // ---- level 2 ----
  edge_conv(xp, K1_, H_, wcat2, b_mlp2, trunk_t1);
  bn_stats_kernel<<<H_, 256, 0, stream>>>(trunk_t1, 4096, stats);
  bn_apply_kernel<<<cdiv(4096 * 256, 256), 256, 0, stream>>>(trunk_t1, stats, bn2_g, bn2_b, 4096, hbuf);
  sag_kernel<<<B_, 256, 0, stream>>>(hbuf, adj1, K1_, K2_, p2_w, p2_b, perm2, xp, adj2, z, 1);
  scatter_kernel<<<cdiv(3328 * 256, 256), 256, 0, stream>>>(xp, perm1, perm2, 3328, xoutb + S, xoutb_h + S, xoutb_l + S);
  gtpred_kernel<<<cdiv(3328, 256), 256, 0, stream>>>(deg, xdeg, perm2, 3328, out_gt2, out_pred2);

  // ---- level 3 ----
  edge_conv(xp, K2_, H_, wcat3, b_mlp3, trunk_t1);
  bn_stats_kernel<<<H_, 256, 0, stream>>>(trunk_t1, 3328, stats);
  bn_apply_kernel<<<cdiv(3328 * 256, 256), 256, 0, stream>>>(trunk_t1, stats, bn3_g, bn3_b, 3328, hbuf);
  sag_kernel<<<B_, 256, 0, stream>>>(hbuf, adj2, K2_, K3_, p3_w, p3_b, perm3, xp, nullptr, z, 1);
  scatter_kernel<<<cdiv(2688 * 256, 256), 256, 0, stream>>>(xp, perm2, perm3, 2688, xoutb + 2 * S, xoutb_h + 2 * S, xoutb_l + 2 * S);
  gtpred_kernel<<<cdiv(2688, 256), 256, 0, stream>>>(deg, xdeg, perm3, 2688, out_gt3, out_pred3);

  // ---- batched decoders (3 independent decoders, 384 graphs per knn) ----
  // stage 1: wcat3, tanh
  knn(xoutb, N_, 3 * B_, idxb);
  for (int d = 0; d < 3; ++d) {
    dim3 gg(4, 39);
    mfma_gemm_split_kernel<<<gg, 256, 0, stream>>>(xoutb_h + d * S, xoutb_l + d * S,
                                                   wcat3t_h, wcat3t_l, nullptr, AB, nullptr, nullptr,
                                                   4992, 512, 256, 0);
    edge_agg_kernel<<<cdiv(4992 * 256, 256), 256, 0, stream>>>(AB, b_mlp3, idxb + d * SI, N_, 256, 2,
                                                               t1b + d * S, t1b_h + d * S, t1b_l + d * S);
  }
  // stage 2: wcat2, tanh
  knn(t1b, N_, 3 * B_, idxb);
  for (int d = 0; d < 3; ++d) {
    dim3 gg(4, 39);
    mfma_gemm_split_kernel<<<gg, 256, 0, stream>>>(t1b_h + d * S, t1b_l + d * S,
                                                   wcat2t_h, wcat2t_l, nullptr, AB, nullptr, nullptr,
                                                   4992, 512, 256, 0);
    edge_agg_kernel<<<cdiv(4992 * 256, 256), 256, 0, stream>>>(AB, b_mlp2, idxb + d * SI, N_, 256, 2,
                                                               t2b + d * S, t2b_h + d * S, t2b_l + d * S);
  }
  // stage 3: wcat6, linear -> out_dec
  knn(t2b, N_, 3 * B_, idxb);
  for (int d = 0; d < 3; ++d) {
    dim3 gg(1, 39);
    mfma_gemm_split_kernel<<<gg, 256, 0, stream>>>(t2b_h + d * S, t2b_l + d * S,
                                                   wcat6t_h, wcat6t_l, nullptr, AB, nullptr, nullptr,
                                                   4992, 78, 256, 0);
    edge_agg_kernel<<<cdiv(4992 * 39, 256), 256, 0, stream>>>(AB, b_mlp6, idxb + d * SI, N_, 39, 0,
                                                              out_dec1 + (size_t)d * 4992 * 39, nullptr, nullptr);
  }

  // ---- classifier head (thin: M=128) ----
  rowgemm_kernel<<<128, 256, 0, stream>>>(z, lin1_w, lin1_b, z1, 256, 512, 1);
  rowgemm_kernel<<<128, 256, 0, stream>>>(z1, lin2_w, lin2_b, z2, 128, 256, 1);
  wavedot_gemm_kernel<<<cdiv(128 * 2 * 64, 256), 256, 0, stream>>>(z2, lin3_w, lin3_b, logits, 128, 2, 128, 0);
  softmax2_kernel<<<1, 128, 0, stream>>>(logits, out_probs);
}

// Round 13
// 977.531 us; speedup vs baseline: 1.3839x; 1.0036x over previous
//
#include <hip/hip_runtime.h>
#include <cmath>

#define B_   128
#define N_   39
#define KNN_ 10
#define H_   256
#define K1_  32
#define K2_  26
#define K3_  21

static inline int cdiv(int a, int b) { return (a + b - 1) / b; }

typedef __attribute__((ext_vector_type(8))) short short8;
typedef __attribute__((ext_vector_type(4))) short short4v;
typedef __attribute__((ext_vector_type(4))) float floatx4;

__device__ inline short f2b(float f) {   // fp32 -> bf16 RNE
  unsigned u = __float_as_uint(f);
  u += 0x7fff + ((u >> 16) & 1);
  return (short)(u >> 16);
}
__device__ inline float b2f(short h) {
  return __uint_as_float(((unsigned)(unsigned short)h) << 16);
}
__device__ inline void f2b3(float v, short& h, short& m, short& l) {  // v ~= h+m+l (24 bits)
  h = f2b(v);
  float r1 = v - b2f(h);
  m = f2b(r1);
  l = f2b(r1 - b2f(m));
}

// ---------- wave-wide argmax (64 lanes), ties -> lowest index ----------
__device__ inline void wave_argmax64(float& v, int& j) {
#pragma unroll
  for (int off = 32; off; off >>= 1) {
    float ov = __shfl_down(v, off, 64);
    int   oj = __shfl_down(j, off, 64);
    if (ov > v || (ov == v && oj < j)) { v = ov; j = oj; }
  }
  v = __shfl(v, 0, 64);
  j = __shfl(j, 0, 64);
}

// ------------- one-shot prep: all weights triple-split transposed + x split + degree -------------
__global__ void prep_kernel(
    const float* __restrict__ w1, const float* __restrict__ w2,
    const float* __restrict__ w3, const float* __restrict__ w6,
    const float* __restrict__ l4, const float* __restrict__ l5,
    const float* __restrict__ x, const float* __restrict__ adj,
    short* __restrict__ wt1h, short* __restrict__ wt1m, short* __restrict__ wt1l,
    short* __restrict__ wt2h, short* __restrict__ wt2m, short* __restrict__ wt2l,
    short* __restrict__ wt3h, short* __restrict__ wt3m, short* __restrict__ wt3l,
    short* __restrict__ wt6h, short* __restrict__ wt6m, short* __restrict__ wt6l,
    short* __restrict__ l4h, short* __restrict__ l4m,
    short* __restrict__ l5h, short* __restrict__ l5m,
    short* __restrict__ xsph, short* __restrict__ xspm, short* __restrict__ xspl,
    float* __restrict__ deg) {
  int task = blockIdx.y;
  int t = blockIdx.x * 256 + threadIdx.x;
  if (task == 0) {            // wcat1 tripleT: [512][64], K=39 padded
    if (t >= 512 * 64) return;
    int nn = t >> 6, k = t & 63;
    float v = 0.f;
    if (k < 39) v = (nn < 256) ? w1[k * 256 + nn] - w1[(39 + k) * 256 + nn]
                               : w1[(39 + k) * 256 + (nn - 256)];
    short h, m, l; f2b3(v, h, m, l);
    wt1h[t] = h; wt1m[t] = m; wt1l[t] = l;
  } else if (task == 1) {     // wcat2 tripleT: [512][256]
    if (t >= 512 * 256) return;
    int nn = t >> 8, k = t & 255;
    float v = (nn < 256) ? w2[k * 256 + nn] - w2[(256 + k) * 256 + nn]
                         : w2[(256 + k) * 256 + (nn - 256)];
    short h, m, l; f2b3(v, h, m, l);
    wt2h[t] = h; wt2m[t] = m; wt2l[t] = l;
  } else if (task == 2) {     // wcat3 tripleT
    if (t >= 512 * 256) return;
    int nn = t >> 8, k = t & 255;
    float v = (nn < 256) ? w3[k * 256 + nn] - w3[(256 + k) * 256 + nn]
                         : w3[(256 + k) * 256 + (nn - 256)];
    short h, m, l; f2b3(v, h, m, l);
    wt3h[t] = h; wt3m[t] = m; wt3l[t] = l;
  } else if (task == 3) {     // wcat6 tripleT: [78][256]
    if (t >= 78 * 256) return;
    int nn = t >> 8, k = t & 255;
    float v = (nn < 39) ? w6[k * 39 + nn] - w6[(256 + k) * 39 + nn]
                        : w6[(256 + k) * 39 + (nn - 39)];
    short h, m, l; f2b3(v, h, m, l);
    wt6h[t] = h; wt6m[t] = m; wt6l[t] = l;
  } else if (task == 4) {     // lin4 T (h,m): [256][256]
    if (t >= 256 * 256) return;
    int nn = t >> 8, k = t & 255;
    short h, m, l; f2b3(l4[k * 256 + nn], h, m, l);
    l4h[t] = h; l4m[t] = m;
  } else if (task == 5) {     // lin5 T (h,m): [128][256]
    if (t >= 128 * 256) return;
    int nn = t >> 8, k = t & 255;
    short h, m, l; f2b3(l5[k * 128 + nn], h, m, l);
    l5h[t] = h; l5m[t] = m;
  } else if (task == 6) {     // x split: [4992][64], F=39 padded
    if (t >= 4992 * 64) return;
    int r = t >> 6, k = t & 63;
    float v = (k < 39) ? x[r * 39 + k] : 0.f;
    short h, m, l; f2b3(v, h, m, l);
    xsph[t] = h; xspm[t] = m; xspl[t] = l;
  } else {                    // degree
    if (t >= B_ * N_) return;
    const float* row = adj + (size_t)t * N_;
    float s = 0.f;
    for (int j = 0; j < N_; ++j) s += row[j];
    deg[t] = s;
  }
}

// ---------------- MFMA gram + KNN from pre-split triple (block per graph, 512 thr) ----------------
__global__ __launch_bounds__(512) void gram_knn_kernel(
    const short* __restrict__ xh, const short* __restrict__ xm, const short* __restrict__ xl,
    int Ks, int n, int F32, int* __restrict__ idx) {
  __shared__ short sh_h[48 * 40], sh_m[48 * 40], sh_l[48 * 40];
  __shared__ float Gs[48][49];
  __shared__ float diag[48];
  int b = blockIdx.x;
  int tid = threadIdx.x;
  int wave = tid >> 6, lane = tid & 63;
  int lm = lane & 15, lk = (lane >> 4) * 8;
  int nt = (n + 15) >> 4;
  int tasks = nt * nt;
  floatx4 acc[2] = {};
  for (int k0 = 0; k0 < F32; k0 += 32) {
    for (int e = tid; e < 1152; e += 512) {   // 3 arrays x 48 rows x 8 short4
      int a = e / 384, rem = e - a * 384;
      int r = rem >> 3, c4 = (rem & 7) * 4;
      const short* src = (a == 0) ? xh : (a == 1) ? xm : xl;
      short* dst = (a == 0) ? sh_h : (a == 1) ? sh_m : sh_l;
      short4v v = {};
      if (r < n) v = *(const short4v*)&src[((size_t)(b * n + r)) * Ks + k0 + c4];
      *(short4v*)&dst[r * 40 + c4] = v;
    }
    __syncthreads();
#pragma unroll
    for (int ai = 0; ai < 2; ++ai) {
      int t = wave + ai * 8;
      if (t < tasks) {
        int ti = t / nt, tj = t - ti * nt;
        int ra = (ti * 16 + lm) * 40 + lk;
        int rb = (tj * 16 + lm) * 40 + lk;
        short8 ah = *(const short8*)&sh_h[ra];
        short8 am = *(const short8*)&sh_m[ra];
        short8 al = *(const short8*)&sh_l[ra];
        short8 bh = *(const short8*)&sh_h[rb];
        short8 bm = *(const short8*)&sh_m[rb];
        short8 bl = *(const short8*)&sh_l[rb];
        floatx4 a = acc[ai];
        a = __builtin_amdgcn_mfma_f32_16x16x32_bf16(ah, bh, a, 0, 0, 0);
        a = __builtin_amdgcn_mfma_f32_16x16x32_bf16(ah, bm, a, 0, 0, 0);
        a = __builtin_amdgcn_mfma_f32_16x16x32_bf16(am, bh, a, 0, 0, 0);
        a = __builtin_amdgcn_mfma_f32_16x16x32_bf16(ah, bl, a, 0, 0, 0);
        a = __builtin_amdgcn_mfma_f32_16x16x32_bf16(al, bh, a, 0, 0, 0);
        a = __builtin_amdgcn_mfma_f32_16x16x32_bf16(am, bm, a, 0, 0, 0);
        acc[ai] = a;
      }
    }
    __syncthreads();
  }
#pragma unroll
  for (int ai = 0; ai < 2; ++ai) {
    int t = wave + ai * 8;
    if (t < tasks) {
      int ti = t / nt, tj = t - ti * nt;
      int col = tj * 16 + lm;
      int rbase = ti * 16 + (lane >> 4) * 4;
#pragma unroll
      for (int r = 0; r < 4; ++r) Gs[rbase + r][col] = acc[ai][r];
    }
  }
  __syncthreads();
  if (tid < 48) diag[tid] = (tid < n) ? Gs[tid][tid] : INFINITY;
  __syncthreads();
  int row = lane * 8 + wave;
  if (row < n) {
    float gii = diag[row];
    unsigned long long mask = 0;
    int* outp = idx + (size_t)(b * n + row) * KNN_;
    for (int kk = 0; kk < KNN_; ++kk) {
      float best = INFINITY;
      int bj = 0;
      for (int j = 0; j < n; ++j) {
        float d = gii + diag[j] - 2.f * Gs[row][j];
        d = ((mask >> j) & 1ull) ? INFINITY : d;
        if (d < best) { best = d; bj = j; }
      }
      outp[kk] = bj;
      mask |= (1ull << bj);
    }
  }
}

// ------------- triple-split 6-term MFMA GEMM (trunk; fp32-faithful ~2^-24) -------------
// A pre-split h/m/l (M x Ks), W pre-split (N x Ks). M%128==0, N%128==0. C fp32.
__global__ __launch_bounds__(256) void mfma_gemm_triple_kernel(
    const short* __restrict__ Ah, const short* __restrict__ Am, const short* __restrict__ Al,
    int Ks,
    const short* __restrict__ Wh, const short* __restrict__ Wm, const short* __restrict__ Wl,
    float* __restrict__ C, int M, int N) {
  __shared__ short Ash[128 * 40], Asm[128 * 40], Asl[128 * 40];
  __shared__ short Bsh[128 * 40], Bsm[128 * 40], Bsl[128 * 40];
  int tid = threadIdx.x;
  int wave = tid >> 6, lane = tid & 63;
  int wm = wave & 1, wn = wave >> 1;
  int row0 = blockIdx.y * 128, col0 = blockIdx.x * 128;
  floatx4 acc[4][4] = {};
  int lm = lane & 15, lk = (lane >> 4) * 8;
  for (int k0 = 0; k0 < Ks; k0 += 32) {
    for (int e = tid; e < 1536; e += 256) {   // A: 3 arrays x 128 rows x 4 short8
      int a = e / 512, rem = e - a * 512;
      int r = rem >> 2, kc = (rem & 3) * 8;
      const short* src = (a == 0) ? Ah : (a == 1) ? Am : Al;
      short* dst = (a == 0) ? Ash : (a == 1) ? Asm : Asl;
      *(short8*)&dst[r * 40 + kc] = *(const short8*)&src[((size_t)(row0 + r)) * Ks + k0 + kc];
    }
    for (int e = tid; e < 1536; e += 256) {   // B
      int a = e / 512, rem = e - a * 512;
      int r = rem >> 2, kc = (rem & 3) * 8;
      const short* src = (a == 0) ? Wh : (a == 1) ? Wm : Wl;
      short* dst = (a == 0) ? Bsh : (a == 1) ? Bsm : Bsl;
      *(short8*)&dst[r * 40 + kc] = *(const short8*)&src[((size_t)(col0 + r)) * Ks + k0 + kc];
    }
    __syncthreads();
    short8 afh[4], afm[4], afl[4];
#pragma unroll
    for (int mi = 0; mi < 4; ++mi) {
      int ro = (wm * 64 + mi * 16 + lm) * 40 + lk;
      afh[mi] = *(const short8*)&Ash[ro];
      afm[mi] = *(const short8*)&Asm[ro];
      afl[mi] = *(const short8*)&Asl[ro];
    }
#pragma unroll
    for (int ni = 0; ni < 4; ++ni) {
      int ro = (wn * 64 + ni * 16 + lm) * 40 + lk;
      short8 bfh = *(const short8*)&Bsh[ro];
      short8 bfm = *(const short8*)&Bsm[ro];
      short8 bfl = *(const short8*)&Bsl[ro];
#pragma unroll
      for (int mi = 0; mi < 4; ++mi) {
        floatx4 a = acc[mi][ni];
        a = __builtin_amdgcn_mfma_f32_16x16x32_bf16(afh[mi], bfh, a, 0, 0, 0);
        a = __builtin_amdgcn_mfma_f32_16x16x32_bf16(afh[mi], bfm, a, 0, 0, 0);
        a = __builtin_amdgcn_mfma_f32_16x16x32_bf16(afm[mi], bfh, a, 0, 0, 0);
        a = __builtin_amdgcn_mfma_f32_16x16x32_bf16(afh[mi], bfl, a, 0, 0, 0);
        a = __builtin_amdgcn_mfma_f32_16x16x32_bf16(afl[mi], bfh, a, 0, 0, 0);
        a = __builtin_amdgcn_mfma_f32_16x16x32_bf16(afm[mi], bfm, a, 0, 0, 0);
        acc[mi][ni] = a;
      }
    }
    __syncthreads();
  }
  int lr = (lane >> 4) * 4;
#pragma unroll
  for (int mi = 0; mi < 4; ++mi)
#pragma unroll
    for (int ni = 0; ni < 4; ++ni) {
      int colg = col0 + wn * 64 + ni * 16 + lm;
#pragma unroll
      for (int r = 0; r < 4; ++r) {
        int rowg = row0 + wm * 64 + mi * 16 + lr + r;
        C[(size_t)rowg * N + colg] = acc[mi][ni][r];
      }
    }
}

// ------------- 2-term split MFMA GEMM (decoder/degree head, ~2^-16) -------------
__global__ __launch_bounds__(256) void mfma_gemm_split_kernel(
    const short* __restrict__ Ah, const short* __restrict__ Al,
    const short* __restrict__ Wth, const short* __restrict__ Wtl,
    const float* __restrict__ bias,
    float* __restrict__ C, short* __restrict__ Ch, short* __restrict__ Cl,
    int M, int N, int K, int act) {
  __shared__ short Ash[128 * 40];
  __shared__ short Asl[128 * 40];
  __shared__ short Bsh[128 * 40];
  __shared__ short Bsl[128 * 40];
  int tid = threadIdx.x;
  int wave = tid >> 6, lane = tid & 63;
  int wm = wave & 1, wn = wave >> 1;
  int row0 = blockIdx.y * 128, col0 = blockIdx.x * 128;
  floatx4 acc[4][4] = {};
  int lm = lane & 15, lk = (lane >> 4) * 8;
  for (int k0 = 0; k0 < K; k0 += 32) {
    for (int c = tid; c < 512; c += 256) {
      int r = c >> 2, kc = (c & 3) * 8;
      int grow = row0 + r;
      short8 vh = {}, vl = {};
      if (grow < M) {
        vh = *(const short8*)&Ah[(size_t)grow * K + k0 + kc];
        vl = *(const short8*)&Al[(size_t)grow * K + k0 + kc];
      }
      *(short8*)&Ash[r * 40 + kc] = vh;
      *(short8*)&Asl[r * 40 + kc] = vl;
    }
    for (int c = tid; c < 512; c += 256) {
      int r = c >> 2, kc = (c & 3) * 8;
      int gn = col0 + r;
      short8 vh = {}, vl = {};
      if (gn < N) {
        vh = *(const short8*)&Wth[(size_t)gn * K + k0 + kc];
        vl = *(const short8*)&Wtl[(size_t)gn * K + k0 + kc];
      }
      *(short8*)&Bsh[r * 40 + kc] = vh;
      *(short8*)&Bsl[r * 40 + kc] = vl;
    }
    __syncthreads();
    short8 afh[4], afl[4], bfh[4], bfl[4];
#pragma unroll
    for (int mi = 0; mi < 4; ++mi) {
      int ro = (wm * 64 + mi * 16 + lm) * 40 + lk;
      afh[mi] = *(const short8*)&Ash[ro];
      afl[mi] = *(const short8*)&Asl[ro];
    }
#pragma unroll
    for (int ni = 0; ni < 4; ++ni) {
      int ro = (wn * 64 + ni * 16 + lm) * 40 + lk;
      bfh[ni] = *(const short8*)&Bsh[ro];
      bfl[ni] = *(const short8*)&Bsl[ro];
    }
#pragma unroll
    for (int mi = 0; mi < 4; ++mi)
#pragma unroll
      for (int ni = 0; ni < 4; ++ni) {
        acc[mi][ni] = __builtin_amdgcn_mfma_f32_16x16x32_bf16(afh[mi], bfh[ni], acc[mi][ni], 0, 0, 0);
        acc[mi][ni] = __builtin_amdgcn_mfma_f32_16x16x32_bf16(afh[mi], bfl[ni], acc[mi][ni], 0, 0, 0);
        acc[mi][ni] = __builtin_amdgcn_mfma_f32_16x16x32_bf16(afl[mi], bfh[ni], acc[mi][ni], 0, 0, 0);
      }
    __syncthreads();
  }
  int lr = (lane >> 4) * 4;
#pragma unroll
  for (int mi = 0; mi < 4; ++mi)
#pragma unroll
    for (int ni = 0; ni < 4; ++ni) {
      int colg = col0 + wn * 64 + ni * 16 + lm;
      if (colg >= N) continue;
      float bv = bias ? bias[colg] : 0.f;
#pragma unroll
      for (int r = 0; r < 4; ++r) {
        int rowg = row0 + wm * 64 + mi * 16 + lr + r;
        if (rowg >= M) continue;
        float v = acc[mi][ni][r] + bv;
        if (act == 1) v = fmaxf(v, 0.f);
        C[(size_t)rowg * N + colg] = v;
        if (Ch) {
          short hi = f2b(v);
          short lo = f2b(v - b2f(hi));
          Ch[(size_t)rowg * N + colg] = hi;
          Cl[(size_t)rowg * N + colg] = lo;
        }
      }
    }
}

// Thin GEMM (small M): one block per row.
__global__ __launch_bounds__(256) void rowgemm_kernel(
    const float* __restrict__ A, const float* __restrict__ W, const float* __restrict__ bias,
    float* __restrict__ C, int N, int K, int act) {
  __shared__ float a[512];
  int row = blockIdx.x;
  for (int k = threadIdx.x; k < K; k += 256) a[k] = A[(size_t)row * K + k];
  __syncthreads();
  for (int c = threadIdx.x; c < N; c += 256) {
    float s = 0.f;
    for (int k = 0; k < K; k += 4) {
      float4 av = *(const float4*)&a[k];
      s += av.x * W[(size_t)k * N + c];
      s += av.y * W[(size_t)(k + 1) * N + c];
      s += av.z * W[(size_t)(k + 2) * N + c];
      s += av.w * W[(size_t)(k + 3) * N + c];
    }
    float v = s + (bias ? bias[c] : 0.f);
    if (act == 1) v = fmaxf(v, 0.f);
    C[(size_t)row * N + c] = v;
  }
}

// one wave per output element (for very small M*N)
__global__ void wavedot_gemm_kernel(const float* __restrict__ A, const float* __restrict__ W,
                                    const float* __restrict__ bias, float* __restrict__ C,
                                    int M, int N, int K, int act) {
  int wid = (blockIdx.x * blockDim.x + threadIdx.x) >> 6;
  int lane = threadIdx.x & 63;
  if (wid >= M * N) return;
  int row = wid / N, col = wid - row * N;
  const float* ar = A + (size_t)row * K;
  float s = 0.f;
  for (int k = lane; k < K; k += 64) s += ar[k] * W[(size_t)k * N + col];
  for (int off = 32; off; off >>= 1) s += __shfl_down(s, off, 64);
  if (lane == 0) {
    float v = s + (bias ? bias[col] : 0.f);
    if (act == 1) v = fmaxf(v, 0.f);
    C[(size_t)row * N + col] = v;
  }
}

// AB row r: [0..Hc) = xi@(Wt-Wb), [Hc..2Hc) = xi@Wb.  out = max_k relu(Ai + b + Bm[nbr]) [tanh]
__global__ void edge_agg_kernel(const float* __restrict__ AB, const float* __restrict__ bias,
                                const int* __restrict__ idx, int n, int Hc, int act, int rows,
                                float* __restrict__ out,
                                short* __restrict__ outh, short* __restrict__ outm,
                                short* __restrict__ outl) {
  int t = blockIdx.x * blockDim.x + threadIdx.x;
  if (t >= rows * Hc) return;
  int r = t / Hc, h = t - r * Hc;
  int b = r / n;
  int s2 = 2 * Hc;
  float av = AB[(size_t)r * s2 + h] + bias[h];
  const int* ir = idx + (size_t)r * KNN_;
  int base = b * n;
  float m = -INFINITY;
  for (int k = 0; k < KNN_; ++k) {
    float v = av + AB[(size_t)(base + ir[k]) * s2 + Hc + h];
    v = fmaxf(v, 0.f);
    m = fmaxf(m, v);
  }
  if (act == 2) m = tanhf(m);
  if (out) out[t] = m;
  if (outh) {
    short hh, mm, ll;
    f2b3(m, hh, mm, ll);
    outh[t] = hh; outm[t] = mm; outl[t] = ll;
  }
}

// BN stats -> per-column scale/shift: norm(v) = relu(v*sc + sh)
__global__ void bn_stats_kernel(const float* __restrict__ xx, int M,
                                const float* __restrict__ g, const float* __restrict__ bb,
                                float* __restrict__ scsh) {
  int c = blockIdx.x;
  double s = 0.0, s2 = 0.0;
  for (int r = threadIdx.x; r < M; r += 256) {
    double v = (double)xx[(size_t)r * H_ + c];
    s += v; s2 += v * v;
  }
  __shared__ double sh[256], sh2[256];
  sh[threadIdx.x] = s; sh2[threadIdx.x] = s2;
  __syncthreads();
  for (int o = 128; o; o >>= 1) {
    if (threadIdx.x < o) { sh[threadIdx.x] += sh[threadIdx.x + o]; sh2[threadIdx.x] += sh2[threadIdx.x + o]; }
    __syncthreads();
  }
  if (threadIdx.x == 0) {
    double mean = sh[0] / M;
    double var = sh2[0] / M - mean * mean;
    float rstd = 1.f / sqrtf((float)var + 1e-5f);
    float sc = rstd * g[c];
    scsh[c] = sc;
    scsh[H_ + c] = bb[c] - (float)mean * sc;
  }
}

// one wave per row: y[r] = dot(x[r,:K], w) [+bias] [relu]
__global__ void rowdot_kernel(const float* __restrict__ x, const float* __restrict__ w,
                              int M, int K, const float* __restrict__ bias, int act,
                              float* __restrict__ y) {
  int wid = (blockIdx.x * blockDim.x + threadIdx.x) >> 6;
  int lane = threadIdx.x & 63;
  if (wid >= M) return;
  const float* xr = x + (size_t)wid * K;
  float s = 0.f;
  for (int k = lane; k < K; k += 64) s += xr[k] * w[k];
  for (int off = 32; off; off >>= 1) s += __shfl_down(s, off, 64);
  if (lane == 0) {
    float v = s + (bias ? bias[0] : 0.f);
    if (act == 1) v = fmaxf(v, 0.f);
    y[wid] = v;
  }
}

// -------- mega SAG: BN(on the fly) + rowdot + gcn + topk + gather(xp triple) +
//          scatter(xoutb triple via remap) + readout + optional gt/pred --------
__global__ __launch_bounds__(256) void sag_kernel(
    const float* __restrict__ t1, const float* __restrict__ scsh,
    const float* __restrict__ adj_in, int n, int k,
    const float* __restrict__ pw, const float* __restrict__ pb,
    int* __restrict__ perm, const int* __restrict__ remap,
    short* __restrict__ xph, short* __restrict__ xpm, short* __restrict__ xpl,
    short* __restrict__ soh, short* __restrict__ som, short* __restrict__ sol,
    float* __restrict__ adjp, float* __restrict__ z, int accum,
    const float* __restrict__ deg, const float* __restrict__ xdeg,
    float* __restrict__ gt, float* __restrict__ pred) {
  __shared__ float ys[40], dinv[40], scs[40], tant[40];
  __shared__ int locs[40];
  int b = blockIdx.x;
  int wave = threadIdx.x >> 6, lane = threadIdx.x & 63;
  for (int i = wave; i < n; i += 4) {
    const float* xr = t1 + (size_t)(b * n + i) * H_;
    float s = 0.f;
    for (int kk = lane; kk < H_; kk += 64) {
      float v = fmaxf(xr[kk] * scsh[kk] + scsh[H_ + kk], 0.f);
      s += v * pw[kk];
    }
    for (int off = 32; off; off >>= 1) s += __shfl_down(s, off, 64);
    if (lane == 0) ys[i] = s;
  }
  __syncthreads();
  int i = threadIdx.x;
  if (i < n) {
    const float* ar = adj_in + ((size_t)b * n + i) * n;
    float sum = 1.f;
    for (int j = 0; j < n; ++j) sum += ar[j];
    dinv[i] = 1.f / sqrtf(sum);
  }
  __syncthreads();
  if (i < n) {
    const float* ar = adj_in + ((size_t)b * n + i) * n;
    float acc = 0.f;
    for (int j = 0; j < n; ++j) {
      float a = ar[j] + (i == j ? 1.f : 0.f);
      acc += a * dinv[j] * ys[j];
    }
    scs[i] = dinv[i] * acc + pb[0];
  }
  __syncthreads();
  if (wave == 0) {
    float cur = (lane < n) ? scs[lane] : -INFINITY;
    for (int t = 0; t < k; ++t) {
      float rv = cur;
      int rj = (lane < n) ? lane : (1 << 20);
      wave_argmax64(rv, rj);
      if (lane == 0) { tant[t] = tanhf(rv); locs[t] = rj; perm[b * k + t] = b * n + rj; }
      if (lane == rj) cur = -INFINITY;
    }
  }
  __syncthreads();
  int hc = threadIdx.x;   // feature column (H_ == 256 == blockDim)
  float scv = scsh[hc], shv = scsh[H_ + hc];
  float mx = -INFINITY, sm = 0.f;
  for (int r = 0; r < k; ++r) {
    int own = b * n + locs[r];
    float v = fmaxf(t1[(size_t)own * H_ + hc] * scv + shv, 0.f) * tant[r];
    short hh, mm, ll;
    f2b3(v, hh, mm, ll);
    size_t xo = ((size_t)(b * k + r)) * H_ + hc;
    xph[xo] = hh; xpm[xo] = mm; xpl[xo] = ll;
    int tgt = remap ? remap[own] : own;
    size_t so = (size_t)tgt * H_ + hc;
    soh[so] = hh; som[so] = mm; sol[so] = ll;
    mx = fmaxf(mx, v);
    sm += v;
  }
  float* zb = z + (size_t)b * 2 * H_;
  float mean = sm / (float)k;
  if (accum) { zb[hc] += mx; zb[H_ + hc] += mean; }
  else       { zb[hc] = mx;  zb[H_ + hc] = mean; }
  if (adjp) {
    for (int e = threadIdx.x; e < k * k; e += 256) {
      int t1i = e / k, t2i = e - t1i * k;
      adjp[(size_t)b * k * k + e] = adj_in[((size_t)b * n + locs[t1i]) * n + locs[t2i]];
    }
  }
  if (gt && threadIdx.x < k) {
    int p = b * n + locs[threadIdx.x];
    gt[b * k + threadIdx.x] = deg[p];
    pred[b * k + threadIdx.x] = xdeg[p];
  }
}

__global__ void gtpred_kernel(const float* __restrict__ deg, const float* __restrict__ xdeg,
                              const int* __restrict__ perm, int M,
                              float* __restrict__ gt, float* __restrict__ pred) {
  int t = blockIdx.x * blockDim.x + threadIdx.x;
  if (t >= M) return;
  int p = perm[t];
  gt[t] = deg[p];
  pred[t] = xdeg[p];
}

__global__ void softmax2_kernel(const float* __restrict__ logits, float* __restrict__ probs) {
  int b = blockIdx.x * blockDim.x + threadIdx.x;
  if (b >= B_) return;
  float a = logits[2 * b], c = logits[2 * b + 1];
  float m = fmaxf(a, c);
  float ea = expf(a - m), ec = expf(c - m);
  float inv = 1.f / (ea + ec);
  probs[2 * b] = ea * inv;
  probs[2 * b + 1] = ec * inv;
}

extern "C" void kernel_launch(void* const* d_in, const int* in_sizes, int n_in,
                              void* d_out, int out_size, void* d_ws, size_t ws_size,
                              hipStream_t stream) {
  auto in = [&](int i) { return (const float*)d_in[i]; };
  const float* x      = in(0);
  const float* adj    = in(1);
  const float* w_mlp1 = in(2);  const float* b_mlp1 = in(3);
  const float* w_mlp2 = in(4);  const float* b_mlp2 = in(5);
  const float* w_mlp3 = in(6);  const float* b_mlp3 = in(7);
  const float* w_mlp6 = in(8);  const float* b_mlp6 = in(9);
  const float* bn1_g = in(10);  const float* bn1_b = in(11);
  const float* bn2_g = in(12);  const float* bn2_b = in(13);
  const float* bn3_g = in(14);  const float* bn3_b = in(15);
  const float* p1_w = in(16);   const float* p1_b = in(17);
  const float* p2_w = in(18);   const float* p2_b = in(19);
  const float* p3_w = in(20);   const float* p3_b = in(21);
  const float* lin1_w = in(22); const float* lin1_b = in(23);
  const float* lin2_w = in(24); const float* lin2_b = in(25);
  const float* lin3_w = in(26); const float* lin3_b = in(27);
  const float* lin4_w = in(28); const float* lin4_b = in(29);
  const float* lin5_w = in(30); const float* lin5_b = in(31);
  const float* lin6_w = in(32); const float* lin6_b = in(33);

  float* out = (float*)d_out;
  float* out_probs = out;
  float* out_dec1  = out_probs + 256;            // 3 x 4992*39 contiguous
  float* out_gt1   = out_dec1 + 3 * 4992 * 39;
  float* out_pred1 = out_gt1 + 4096;
  float* out_gt2   = out_pred1 + 4096;
  float* out_pred2 = out_gt2 + 3328;
  float* out_gt3   = out_pred2 + 3328;
  float* out_pred3 = out_gt3 + 2688;

  char* base = (char*)d_ws;
  size_t off = 0;
  auto allocf = [&](size_t n) -> float* {
    float* p = (float*)(base + off);
    off += ((n * sizeof(float) + 255) & ~(size_t)255);
    return p;
  };
  auto alloci = [&](size_t n) -> int* {
    int* p = (int*)(base + off);
    off += ((n * sizeof(int) + 255) & ~(size_t)255);
    return p;
  };
  auto allocs = [&](size_t n) -> short* {
    short* p = (short*)(base + off);
    off += ((n * sizeof(short) + 255) & ~(size_t)255);
    return p;
  };

  const size_t S = (size_t)4992 * 256;
  const int SI = 4992 * KNN_;

  short* wt1h = allocs(512 * 64); short* wt1m = allocs(512 * 64); short* wt1l = allocs(512 * 64);
  short* wt2h = allocs(512 * 256); short* wt2m = allocs(512 * 256); short* wt2l = allocs(512 * 256);
  short* wt3h = allocs(512 * 256); short* wt3m = allocs(512 * 256); short* wt3l = allocs(512 * 256);
  short* wt6h = allocs(78 * 256);  short* wt6m = allocs(78 * 256);  short* wt6l = allocs(78 * 256);
  short* l4h = allocs(256 * 256);  short* l4m = allocs(256 * 256);
  short* l5h = allocs(128 * 256);  short* l5m = allocs(128 * 256);
  short* xsph = allocs(4992 * 64); short* xspm = allocs(4992 * 64); short* xspl = allocs(4992 * 64);
  float* deg  = allocf(4992);
  float* xdeg = allocf(4992);
  int* idxb = alloci(3 * SI);
  float* AB = allocf((size_t)4992 * 512);
  float* trunk_t1 = allocf(S);
  float* scsh = allocf(512);
  short* xph = allocs((size_t)4096 * 256); short* xpm = allocs((size_t)4096 * 256); short* xpl = allocs((size_t)4096 * 256);
  size_t ms0 = off;
  short* xoutb_h = allocs(3 * S);
  short* xoutb_m = allocs(3 * S);
  short* xoutb_l = allocs(3 * S);
  size_t msz = off - ms0;
  short* t1b_h = allocs(3 * S);
  short* t1b_m = allocs(3 * S);
  short* t1b_l = allocs(3 * S);
  float* adj1 = allocf(128 * 32 * 32);
  float* adj2 = allocf(128 * 26 * 26);
  int* perm1 = alloci(4096); int* perm2 = alloci(3328); int* perm3 = alloci(2688);
  float* z  = allocf(128 * 512);
  float* z1 = allocf(128 * 256);
  float* z2 = allocf(128 * 128);
  float* logits = allocf(256);
  if (off > ws_size) return;

  // t2b aliases xoutb (dead after decoder stage 1)
  short* t2b_h = xoutb_h; short* t2b_m = xoutb_m; short* t2b_l = xoutb_l;

  // ---- prep + zero scatter targets ----
  prep_kernel<<<dim3(1248, 8), 256, 0, stream>>>(
      w_mlp1, w_mlp2, w_mlp3, w_mlp6, lin4_w, lin5_w, x, adj,
      wt1h, wt1m, wt1l, wt2h, wt2m, wt2l, wt3h, wt3m, wt3l, wt6h, wt6m, wt6l,
      l4h, l4m, l5h, l5m, xsph, xspm, xspl, deg);
  hipMemsetAsync(xoutb_h, 0, msz, stream);

  // ---- level 1 ----
  gram_knn_kernel<<<B_, 512, 0, stream>>>(xsph, xspm, xspl, 64, N_, 64, idxb);
  {
    dim3 gg(4, 39);
    mfma_gemm_triple_kernel<<<gg, 256, 0, stream>>>(xsph, xspm, xspl, 64,
                                                    wt1h, wt1m, wt1l, AB, 4992, 512);
  }
  edge_agg_kernel<<<cdiv(4992 * 256, 256), 256, 0, stream>>>(AB, b_mlp1, idxb, N_, 256, 0, 4992,
                                                             trunk_t1, nullptr, nullptr, nullptr);
  bn_stats_kernel<<<H_, 256, 0, stream>>>(trunk_t1, 4992, bn1_g, bn1_b, scsh);
  sag_kernel<<<B_, 256, 0, stream>>>(trunk_t1, scsh, adj, N_, K1_, p1_w, p1_b,
                                     perm1, nullptr, xph, xpm, xpl,
                                     xoutb_h, xoutb_m, xoutb_l, adj1, z, 0,
                                     nullptr, nullptr, nullptr, nullptr);
  {  // degree head from x_out1
    dim3 g4(2, 39);
    mfma_gemm_split_kernel<<<g4, 256, 0, stream>>>(xoutb_h, xoutb_m, l4h, l4m, lin4_b,
                                                   trunk_t1, t1b_h, t1b_m, 4992, 256, 256, 1);
    dim3 g5(1, 39);
    mfma_gemm_split_kernel<<<g5, 256, 0, stream>>>(t1b_h, t1b_m, l5h, l5m, lin5_b,
                                                   AB, nullptr, nullptr, 4992, 128, 256, 1);
  }
  rowdot_kernel<<<cdiv(4992 * 64, 256), 256, 0, stream>>>(AB, lin6_w, 4992, 128, lin6_b, 1, xdeg);
  gtpred_kernel<<<cdiv(4096, 256), 256, 0, stream>>>(deg, xdeg, perm1, 4096, out_gt1, out_pred1);

  // ---- level 2 ----
  gram_knn_kernel<<<B_, 512, 0, stream>>>(xph, xpm, xpl, 256, K1_, 256, idxb);
  {
    dim3 gg(4, 32);
    mfma_gemm_triple_kernel<<<gg, 256, 0, stream>>>(xph, xpm, xpl, 256,
                                                    wt2h, wt2m, wt2l, AB, 4096, 512);
  }
  edge_agg_kernel<<<cdiv(4096 * 256, 256), 256, 0, stream>>>(AB, b_mlp2, idxb, K1_, 256, 0, 4096,
                                                             trunk_t1, nullptr, nullptr, nullptr);
  bn_stats_kernel<<<H_, 256, 0, stream>>>(trunk_t1, 4096, bn2_g, bn2_b, scsh);
  sag_kernel<<<B_, 256, 0, stream>>>(trunk_t1, scsh, adj1, K1_, K2_, p2_w, p2_b,
                                     perm2, perm1, xph, xpm, xpl,
                                     xoutb_h + S, xoutb_m + S, xoutb_l + S, adj2, z, 1,
                                     deg, xdeg, out_gt2, out_pred2);

  // ---- level 3 ----
  gram_knn_kernel<<<B_, 512, 0, stream>>>(xph, xpm, xpl, 256, K2_, 256, idxb);
  {
    dim3 gg(4, 26);
    mfma_gemm_triple_kernel<<<gg, 256, 0, stream>>>(xph, xpm, xpl, 256,
                                                    wt3h, wt3m, wt3l, AB, 3328, 512);
  }
  edge_agg_kernel<<<cdiv(3328 * 256, 256), 256, 0, stream>>>(AB, b_mlp3, idxb, K2_, 256, 0, 3328,
                                                             trunk_t1, nullptr, nullptr, nullptr);
  bn_stats_kernel<<<H_, 256, 0, stream>>>(trunk_t1, 3328, bn3_g, bn3_b, scsh);
  sag_kernel<<<B_, 256, 0, stream>>>(trunk_t1, scsh, adj2, K2_, K3_, p3_w, p3_b,
                                     perm3, perm2, xph, xpm, xpl,
                                     xoutb_h + 2 * S, xoutb_m + 2 * S, xoutb_l + 2 * S, nullptr, z, 1,
                                     deg, xdeg, out_gt3, out_pred3);

  // ---- classifier head (z complete) ----
  rowgemm_kernel<<<128, 256, 0, stream>>>(z, lin1_w, lin1_b, z1, 256, 512, 1);
  rowgemm_kernel<<<128, 256, 0, stream>>>(z1, lin2_w, lin2_b, z2, 128, 256, 1);
  wavedot_gemm_kernel<<<cdiv(128 * 2 * 64, 256), 256, 0, stream>>>(z2, lin3_w, lin3_b, logits, 128, 2, 128, 0);
  softmax2_kernel<<<1, 128, 0, stream>>>(logits, out_probs);

  // ---- batched decoders (3 independent, share weights; 384-graph knn) ----
  // stage 1: wcat3, tanh
  gram_knn_kernel<<<3 * B_, 512, 0, stream>>>(xoutb_h, xoutb_m, xoutb_l, 256, N_, 256, idxb);
  for (int d = 0; d < 3; ++d) {
    dim3 gg(4, 39);
    mfma_gemm_split_kernel<<<gg, 256, 0, stream>>>(xoutb_h + d * S, xoutb_m + d * S,
                                                   wt3h, wt3m, nullptr, AB, nullptr, nullptr,
                                                   4992, 512, 256, 0);
    edge_agg_kernel<<<cdiv(4992 * 256, 256), 256, 0, stream>>>(AB, b_mlp3, idxb + d * SI, N_, 256, 2, 4992,
                                                               nullptr, t1b_h + d * S, t1b_m + d * S, t1b_l + d * S);
  }
  // stage 2: wcat2, tanh
  gram_knn_kernel<<<3 * B_, 512, 0, stream>>>(t1b_h, t1b_m, t1b_l, 256, N_, 256, idxb);
  for (int d = 0; d < 3; ++d) {
    dim3 gg(4, 39);
    mfma_gemm_split_kernel<<<gg, 256, 0, stream>>>(t1b_h + d * S, t1b_m + d * S,
                                                   wt2h, wt2m, nullptr, AB, nullptr, nullptr,
                                                   4992, 512, 256, 0);
    edge_agg_kernel<<<cdiv(4992 * 256, 256), 256, 0, stream>>>(AB, b_mlp2, idxb + d * SI, N_, 256, 2, 4992,
                                                               nullptr, t2b_h + d * S, t2b_m + d * S, t2b_l + d * S);
  }
  // stage 3: wcat6, linear -> out_dec
  gram_knn_kernel<<<3 * B_, 512, 0, stream>>>(t2b_h, t2b_m, t2b_l, 256, N_, 256, idxb);
  for (int d = 0; d < 3; ++d) {
    dim3 gg(1, 39);
    mfma_gemm_split_kernel<<<gg, 256, 0, stream>>>(t2b_h + d * S, t2b_m + d * S,
                                                   wt6h, wt6m, nullptr, AB, nullptr, nullptr,
                                                   4992, 78, 256, 0);
    edge_agg_kernel<<<cdiv(4992 * 39, 256), 256, 0, stream>>>(AB, b_mlp6, idxb + d * SI, N_, 39, 0, 4992,
                                                              out_dec1 + (size_t)d * 4992 * 39, nullptr, nullptr, nullptr);
  }
}

// Round 14
// 823.714 us; speedup vs baseline: 1.6424x; 1.1867x over previous
//
#include <hip/hip_runtime.h>
#include <cmath>

#define B_   128
#define N_   39
#define KNN_ 10
#define H_   256
#define K1_  32
#define K2_  26
#define K3_  21

static inline int cdiv(int a, int b) { return (a + b - 1) / b; }

typedef __attribute__((ext_vector_type(8))) short short8;
typedef __attribute__((ext_vector_type(4))) short short4v;
typedef __attribute__((ext_vector_type(4))) float floatx4;

__device__ inline short f2b(float f) {   // fp32 -> bf16 RNE
  unsigned u = __float_as_uint(f);
  u += 0x7fff + ((u >> 16) & 1);
  return (short)(u >> 16);
}
__device__ inline float b2f(short h) {
  return __uint_as_float(((unsigned)(unsigned short)h) << 16);
}
__device__ inline void f2b3(float v, short& h, short& m, short& l) {  // v ~= h+m+l (24 bits)
  h = f2b(v);
  float r1 = v - b2f(h);
  m = f2b(r1);
  l = f2b(r1 - b2f(m));
}

// ---------- wave-wide argmax (64 lanes), ties -> lowest index ----------
__device__ inline void wave_argmax64(float& v, int& j) {
#pragma unroll
  for (int off = 32; off; off >>= 1) {
    float ov = __shfl_down(v, off, 64);
    int   oj = __shfl_down(j, off, 64);
    if (ov > v || (ov == v && oj < j)) { v = ov; j = oj; }
  }
  v = __shfl(v, 0, 64);
  j = __shfl(j, 0, 64);
}

// ------------- one-shot prep: weights triple-split transposed + x split + degree -------------
__global__ void prep_kernel(
    const float* __restrict__ w1, const float* __restrict__ w2,
    const float* __restrict__ w3, const float* __restrict__ w6,
    const float* __restrict__ l4, const float* __restrict__ l5,
    const float* __restrict__ x, const float* __restrict__ adj,
    short* __restrict__ wt1h, short* __restrict__ wt1m, short* __restrict__ wt1l,
    short* __restrict__ wt2h, short* __restrict__ wt2m, short* __restrict__ wt2l,
    short* __restrict__ wt3h, short* __restrict__ wt3m, short* __restrict__ wt3l,
    short* __restrict__ wt6h, short* __restrict__ wt6m,
    short* __restrict__ l4h, short* __restrict__ l4m,
    short* __restrict__ l5h, short* __restrict__ l5m,
    short* __restrict__ xsph, short* __restrict__ xspm, short* __restrict__ xspl,
    float* __restrict__ deg) {
  int task = blockIdx.y;
  int t = blockIdx.x * 256 + threadIdx.x;
  if (task == 0) {            // wcat1 tripleT: [512][64], K=39 padded
    if (t >= 512 * 64) return;
    int nn = t >> 6, k = t & 63;
    float v = 0.f;
    if (k < 39) v = (nn < 256) ? w1[k * 256 + nn] - w1[(39 + k) * 256 + nn]
                               : w1[(39 + k) * 256 + (nn - 256)];
    short h, m, l; f2b3(v, h, m, l);
    wt1h[t] = h; wt1m[t] = m; wt1l[t] = l;
  } else if (task == 1) {     // wcat2 tripleT: [512][256]
    if (t >= 512 * 256) return;
    int nn = t >> 8, k = t & 255;
    float v = (nn < 256) ? w2[k * 256 + nn] - w2[(256 + k) * 256 + nn]
                         : w2[(256 + k) * 256 + (nn - 256)];
    short h, m, l; f2b3(v, h, m, l);
    wt2h[t] = h; wt2m[t] = m; wt2l[t] = l;
  } else if (task == 2) {     // wcat3 tripleT
    if (t >= 512 * 256) return;
    int nn = t >> 8, k = t & 255;
    float v = (nn < 256) ? w3[k * 256 + nn] - w3[(256 + k) * 256 + nn]
                         : w3[(256 + k) * 256 + (nn - 256)];
    short h, m, l; f2b3(v, h, m, l);
    wt3h[t] = h; wt3m[t] = m; wt3l[t] = l;
  } else if (task == 3) {     // wcat6 T (h,m): [78][256]
    if (t >= 78 * 256) return;
    int nn = t >> 8, k = t & 255;
    float v = (nn < 39) ? w6[k * 39 + nn] - w6[(256 + k) * 39 + nn]
                        : w6[(256 + k) * 39 + (nn - 39)];
    short h, m, l; f2b3(v, h, m, l);
    wt6h[t] = h; wt6m[t] = m;
  } else if (task == 4) {     // lin4 T (h,m): [256][256]
    if (t >= 256 * 256) return;
    int nn = t >> 8, k = t & 255;
    short h, m, l; f2b3(l4[k * 256 + nn], h, m, l);
    l4h[t] = h; l4m[t] = m;
  } else if (task == 5) {     // lin5 T (h,m): [128][256]
    if (t >= 128 * 256) return;
    int nn = t >> 8, k = t & 255;
    short h, m, l; f2b3(l5[k * 128 + nn], h, m, l);
    l5h[t] = h; l5m[t] = m;
  } else if (task == 6) {     // x split: [4992][64], F=39 padded
    if (t >= 4992 * 64) return;
    int r = t >> 6, k = t & 63;
    float v = (k < 39) ? x[r * 39 + k] : 0.f;
    short h, m, l; f2b3(v, h, m, l);
    xsph[t] = h; xspm[t] = m; xspl[t] = l;
  } else {                    // degree
    if (t >= B_ * N_) return;
    const float* row = adj + (size_t)t * N_;
    float s = 0.f;
    for (int j = 0; j < N_; ++j) s += row[j];
    deg[t] = s;
  }
}

// ------------- MFMA gram + KNN (block per graph, 512 thr; 2- or 3-term split) -------------
__global__ __launch_bounds__(512) void gram_knn_kernel(
    const short* __restrict__ xh, const short* __restrict__ xm, const short* __restrict__ xl,
    int nterms, int Ks, int n, int F32, int* __restrict__ idx) {
  __shared__ short sh_h[48 * 40], sh_m[48 * 40], sh_l[48 * 40];
  __shared__ float Gs[48][49];
  __shared__ float diag[48];
  int b = blockIdx.x;
  int tid = threadIdx.x;
  int wave = tid >> 6, lane = tid & 63;
  int lm = lane & 15, lk = (lane >> 4) * 8;
  int nt = (n + 15) >> 4;
  int tasks = nt * nt;
  floatx4 acc[2] = {};
  int stage_elems = 384 * nterms;
  for (int k0 = 0; k0 < F32; k0 += 32) {
    for (int e = tid; e < stage_elems; e += 512) {
      int a = e / 384, rem = e - a * 384;
      int r = rem >> 3, c4 = (rem & 7) * 4;
      const short* src = (a == 0) ? xh : (a == 1) ? xm : xl;
      short* dst = (a == 0) ? sh_h : (a == 1) ? sh_m : sh_l;
      short4v v = {};
      if (r < n) v = *(const short4v*)&src[((size_t)(b * n + r)) * Ks + k0 + c4];
      *(short4v*)&dst[r * 40 + c4] = v;
    }
    __syncthreads();
#pragma unroll
    for (int ai = 0; ai < 2; ++ai) {
      int t = wave + ai * 8;
      if (t < tasks) {
        int ti = t / nt, tj = t - ti * nt;
        int ra = (ti * 16 + lm) * 40 + lk;
        int rb = (tj * 16 + lm) * 40 + lk;
        short8 ah = *(const short8*)&sh_h[ra];
        short8 am = *(const short8*)&sh_m[ra];
        short8 bh = *(const short8*)&sh_h[rb];
        short8 bm = *(const short8*)&sh_m[rb];
        floatx4 a = acc[ai];
        a = __builtin_amdgcn_mfma_f32_16x16x32_bf16(ah, bh, a, 0, 0, 0);
        a = __builtin_amdgcn_mfma_f32_16x16x32_bf16(ah, bm, a, 0, 0, 0);
        a = __builtin_amdgcn_mfma_f32_16x16x32_bf16(am, bh, a, 0, 0, 0);
        if (nterms == 3) {
          short8 al = *(const short8*)&sh_l[ra];
          short8 bl = *(const short8*)&sh_l[rb];
          a = __builtin_amdgcn_mfma_f32_16x16x32_bf16(ah, bl, a, 0, 0, 0);
          a = __builtin_amdgcn_mfma_f32_16x16x32_bf16(al, bh, a, 0, 0, 0);
          a = __builtin_amdgcn_mfma_f32_16x16x32_bf16(am, bm, a, 0, 0, 0);
        }
        acc[ai] = a;
      }
    }
    __syncthreads();
  }
#pragma unroll
  for (int ai = 0; ai < 2; ++ai) {
    int t = wave + ai * 8;
    if (t < tasks) {
      int ti = t / nt, tj = t - ti * nt;
      int col = tj * 16 + lm;
      int rbase = ti * 16 + (lane >> 4) * 4;
#pragma unroll
      for (int r = 0; r < 4; ++r) Gs[rbase + r][col] = acc[ai][r];
    }
  }
  __syncthreads();
  if (tid < 48) diag[tid] = (tid < n) ? Gs[tid][tid] : INFINITY;
  __syncthreads();
  int row = lane * 8 + wave;
  if (row < n) {
    float gii = diag[row];
    unsigned long long mask = 0;
    int* outp = idx + (size_t)(b * n + row) * KNN_;
    for (int kk = 0; kk < KNN_; ++kk) {
      float best = INFINITY;
      int bj = 0;
      for (int j = 0; j < n; ++j) {
        float d = gii + diag[j] - 2.f * Gs[row][j];
        d = ((mask >> j) & 1ull) ? INFINITY : d;
        if (d < best) { best = d; bj = j; }
      }
      outp[kk] = bj;
      mask |= (1ull << bj);
    }
  }
}

// ------------- triple-split 6-term MFMA GEMM (trunk; fp32-faithful ~2^-24) -------------
__global__ __launch_bounds__(256) void mfma_gemm_triple_kernel(
    const short* __restrict__ Ah, const short* __restrict__ Am, const short* __restrict__ Al,
    int Ks,
    const short* __restrict__ Wh, const short* __restrict__ Wm, const short* __restrict__ Wl,
    float* __restrict__ C, int M, int N) {
  __shared__ short Ash[128 * 40], Asm[128 * 40], Asl[128 * 40];
  __shared__ short Bsh[128 * 40], Bsm[128 * 40], Bsl[128 * 40];
  int tid = threadIdx.x;
  int wave = tid >> 6, lane = tid & 63;
  int wm = wave & 1, wn = wave >> 1;
  int row0 = blockIdx.y * 128, col0 = blockIdx.x * 128;
  floatx4 acc[4][4] = {};
  int lm = lane & 15, lk = (lane >> 4) * 8;
  for (int k0 = 0; k0 < Ks; k0 += 32) {
    for (int e = tid; e < 1536; e += 256) {
      int a = e / 512, rem = e - a * 512;
      int r = rem >> 2, kc = (rem & 3) * 8;
      const short* src = (a == 0) ? Ah : (a == 1) ? Am : Al;
      short* dst = (a == 0) ? Ash : (a == 1) ? Asm : Asl;
      *(short8*)&dst[r * 40 + kc] = *(const short8*)&src[((size_t)(row0 + r)) * Ks + k0 + kc];
    }
    for (int e = tid; e < 1536; e += 256) {
      int a = e / 512, rem = e - a * 512;
      int r = rem >> 2, kc = (rem & 3) * 8;
      const short* src = (a == 0) ? Wh : (a == 1) ? Wm : Wl;
      short* dst = (a == 0) ? Bsh : (a == 1) ? Bsm : Bsl;
      *(short8*)&dst[r * 40 + kc] = *(const short8*)&src[((size_t)(col0 + r)) * Ks + k0 + kc];
    }
    __syncthreads();
    short8 afh[4], afm[4], afl[4];
#pragma unroll
    for (int mi = 0; mi < 4; ++mi) {
      int ro = (wm * 64 + mi * 16 + lm) * 40 + lk;
      afh[mi] = *(const short8*)&Ash[ro];
      afm[mi] = *(const short8*)&Asm[ro];
      afl[mi] = *(const short8*)&Asl[ro];
    }
#pragma unroll
    for (int ni = 0; ni < 4; ++ni) {
      int ro = (wn * 64 + ni * 16 + lm) * 40 + lk;
      short8 bfh = *(const short8*)&Bsh[ro];
      short8 bfm = *(const short8*)&Bsm[ro];
      short8 bfl = *(const short8*)&Bsl[ro];
#pragma unroll
      for (int mi = 0; mi < 4; ++mi) {
        floatx4 a = acc[mi][ni];
        a = __builtin_amdgcn_mfma_f32_16x16x32_bf16(afh[mi], bfh, a, 0, 0, 0);
        a = __builtin_amdgcn_mfma_f32_16x16x32_bf16(afh[mi], bfm, a, 0, 0, 0);
        a = __builtin_amdgcn_mfma_f32_16x16x32_bf16(afm[mi], bfh, a, 0, 0, 0);
        a = __builtin_amdgcn_mfma_f32_16x16x32_bf16(afh[mi], bfl, a, 0, 0, 0);
        a = __builtin_amdgcn_mfma_f32_16x16x32_bf16(afl[mi], bfh, a, 0, 0, 0);
        a = __builtin_amdgcn_mfma_f32_16x16x32_bf16(afm[mi], bfm, a, 0, 0, 0);
        acc[mi][ni] = a;
      }
    }
    __syncthreads();
  }
  int lr = (lane >> 4) * 4;
#pragma unroll
  for (int mi = 0; mi < 4; ++mi)
#pragma unroll
    for (int ni = 0; ni < 4; ++ni) {
      int colg = col0 + wn * 64 + ni * 16 + lm;
#pragma unroll
      for (int r = 0; r < 4; ++r) {
        int rowg = row0 + wm * 64 + mi * 16 + lr + r;
        C[(size_t)rowg * N + colg] = acc[mi][ni][r];
      }
    }
}

// ------------- 2-term split MFMA GEMM (decoder/degree head, ~2^-16); z-batched -------------
__global__ __launch_bounds__(256) void mfma_gemm_split_kernel(
    const short* __restrict__ Ah0, const short* __restrict__ Al0,
    const short* __restrict__ Wth, const short* __restrict__ Wtl,
    const float* __restrict__ bias,
    float* __restrict__ C0, short* __restrict__ Ch0, short* __restrict__ Cl0,
    int M, int N, int K, int act, size_t Astride, size_t Cstride) {
  const short* Ah = Ah0 + blockIdx.z * Astride;
  const short* Al = Al0 + blockIdx.z * Astride;
  float* C = C0 + blockIdx.z * Cstride;
  short* Ch = Ch0 ? Ch0 + blockIdx.z * Cstride : nullptr;
  short* Cl = Cl0 ? Cl0 + blockIdx.z * Cstride : nullptr;
  __shared__ short Ash[128 * 40];
  __shared__ short Asl[128 * 40];
  __shared__ short Bsh[128 * 40];
  __shared__ short Bsl[128 * 40];
  int tid = threadIdx.x;
  int wave = tid >> 6, lane = tid & 63;
  int wm = wave & 1, wn = wave >> 1;
  int row0 = blockIdx.y * 128, col0 = blockIdx.x * 128;
  floatx4 acc[4][4] = {};
  int lm = lane & 15, lk = (lane >> 4) * 8;
  for (int k0 = 0; k0 < K; k0 += 32) {
    for (int c = tid; c < 512; c += 256) {
      int r = c >> 2, kc = (c & 3) * 8;
      int grow = row0 + r;
      short8 vh = {}, vl = {};
      if (grow < M) {
        vh = *(const short8*)&Ah[(size_t)grow * K + k0 + kc];
        vl = *(const short8*)&Al[(size_t)grow * K + k0 + kc];
      }
      *(short8*)&Ash[r * 40 + kc] = vh;
      *(short8*)&Asl[r * 40 + kc] = vl;
    }
    for (int c = tid; c < 512; c += 256) {
      int r = c >> 2, kc = (c & 3) * 8;
      int gn = col0 + r;
      short8 vh = {}, vl = {};
      if (gn < N) {
        vh = *(const short8*)&Wth[(size_t)gn * K + k0 + kc];
        vl = *(const short8*)&Wtl[(size_t)gn * K + k0 + kc];
      }
      *(short8*)&Bsh[r * 40 + kc] = vh;
      *(short8*)&Bsl[r * 40 + kc] = vl;
    }
    __syncthreads();
    short8 afh[4], afl[4], bfh[4], bfl[4];
#pragma unroll
    for (int mi = 0; mi < 4; ++mi) {
      int ro = (wm * 64 + mi * 16 + lm) * 40 + lk;
      afh[mi] = *(const short8*)&Ash[ro];
      afl[mi] = *(const short8*)&Asl[ro];
    }
#pragma unroll
    for (int ni = 0; ni < 4; ++ni) {
      int ro = (wn * 64 + ni * 16 + lm) * 40 + lk;
      bfh[ni] = *(const short8*)&Bsh[ro];
      bfl[ni] = *(const short8*)&Bsl[ro];
    }
#pragma unroll
    for (int mi = 0; mi < 4; ++mi)
#pragma unroll
      for (int ni = 0; ni < 4; ++ni) {
        acc[mi][ni] = __builtin_amdgcn_mfma_f32_16x16x32_bf16(afh[mi], bfh[ni], acc[mi][ni], 0, 0, 0);
        acc[mi][ni] = __builtin_amdgcn_mfma_f32_16x16x32_bf16(afh[mi], bfl[ni], acc[mi][ni], 0, 0, 0);
        acc[mi][ni] = __builtin_amdgcn_mfma_f32_16x16x32_bf16(afl[mi], bfh[ni], acc[mi][ni], 0, 0, 0);
      }
    __syncthreads();
  }
  int lr = (lane >> 4) * 4;
#pragma unroll
  for (int mi = 0; mi < 4; ++mi)
#pragma unroll
    for (int ni = 0; ni < 4; ++ni) {
      int colg = col0 + wn * 64 + ni * 16 + lm;
      if (colg >= N) continue;
      float bv = bias ? bias[colg] : 0.f;
#pragma unroll
      for (int r = 0; r < 4; ++r) {
        int rowg = row0 + wm * 64 + mi * 16 + lr + r;
        if (rowg >= M) continue;
        float v = acc[mi][ni][r] + bv;
        if (act == 1) v = fmaxf(v, 0.f);
        C[(size_t)rowg * N + colg] = v;
        if (Ch) {
          short hi = f2b(v);
          short lo = f2b(v - b2f(hi));
          Ch[(size_t)rowg * N + colg] = hi;
          Cl[(size_t)rowg * N + colg] = lo;
        }
      }
    }
}

// Thin GEMM (small M): one block per row.
__global__ __launch_bounds__(256) void rowgemm_kernel(
    const float* __restrict__ A, const float* __restrict__ W, const float* __restrict__ bias,
    float* __restrict__ C, int N, int K, int act) {
  __shared__ float a[512];
  int row = blockIdx.x;
  for (int k = threadIdx.x; k < K; k += 256) a[k] = A[(size_t)row * K + k];
  __syncthreads();
  for (int c = threadIdx.x; c < N; c += 256) {
    float s = 0.f;
    for (int k = 0; k < K; k += 4) {
      float4 av = *(const float4*)&a[k];
      s += av.x * W[(size_t)k * N + c];
      s += av.y * W[(size_t)(k + 1) * N + c];
      s += av.z * W[(size_t)(k + 2) * N + c];
      s += av.w * W[(size_t)(k + 3) * N + c];
    }
    float v = s + (bias ? bias[c] : 0.f);
    if (act == 1) v = fmaxf(v, 0.f);
    C[(size_t)row * N + c] = v;
  }
}

// one wave per output element (for very small M*N)
__global__ void wavedot_gemm_kernel(const float* __restrict__ A, const float* __restrict__ W,
                                    const float* __restrict__ bias, float* __restrict__ C,
                                    int M, int N, int K, int act) {
  int wid = (blockIdx.x * blockDim.x + threadIdx.x) >> 6;
  int lane = threadIdx.x & 63;
  if (wid >= M * N) return;
  int row = wid / N, col = wid - row * N;
  const float* ar = A + (size_t)row * K;
  float s = 0.f;
  for (int k = lane; k < K; k += 64) s += ar[k] * W[(size_t)k * N + col];
  for (int off = 32; off; off >>= 1) s += __shfl_down(s, off, 64);
  if (lane == 0) {
    float v = s + (bias ? bias[col] : 0.f);
    if (act == 1) v = fmaxf(v, 0.f);
    C[(size_t)row * N + col] = v;
  }
}

// edge agg over global rows (batched decoders: d = r / per); AB is (rows x 2Hc)
__global__ void edge_agg_kernel(const float* __restrict__ AB, const float* __restrict__ bias,
                                const int* __restrict__ idx, int n, int Hc, int act,
                                int rows, int per,
                                float* __restrict__ out,
                                short* __restrict__ outh, short* __restrict__ outm,
                                short* __restrict__ outl) {
  int t = blockIdx.x * blockDim.x + threadIdx.x;
  if (t >= rows * Hc) return;
  int r = t / Hc, h = t - r * Hc;
  int d = r / per, rloc = r - d * per;
  int b = rloc / n;
  int s2 = 2 * Hc;
  float av = AB[(size_t)r * s2 + h] + bias[h];
  const int* ir = idx + ((size_t)d * per + rloc) * KNN_;
  int base = d * per + b * n;
  float m = -INFINITY;
  for (int k = 0; k < KNN_; ++k) {
    float v = av + AB[(size_t)(base + ir[k]) * s2 + Hc + h];
    v = fmaxf(v, 0.f);
    m = fmaxf(m, v);
  }
  if (act == 2) m = tanhf(m);
  if (out) out[t] = m;
  if (outh) {
    short hh, mm, ll;
    f2b3(m, hh, mm, ll);
    outh[t] = hh; outm[t] = mm;
    if (outl) outl[t] = ll;
  }
}

// BN stats -> per-column scale/shift: norm(v) = relu(v*sc + sh)
__global__ void bn_stats_kernel(const float* __restrict__ xx, int M,
                                const float* __restrict__ g, const float* __restrict__ bb,
                                float* __restrict__ scsh) {
  int c = blockIdx.x;
  double s = 0.0, s2 = 0.0;
  for (int r = threadIdx.x; r < M; r += 256) {
    double v = (double)xx[(size_t)r * H_ + c];
    s += v; s2 += v * v;
  }
  __shared__ double sh[256], sh2[256];
  sh[threadIdx.x] = s; sh2[threadIdx.x] = s2;
  __syncthreads();
  for (int o = 128; o; o >>= 1) {
    if (threadIdx.x < o) { sh[threadIdx.x] += sh[threadIdx.x + o]; sh2[threadIdx.x] += sh2[threadIdx.x + o]; }
    __syncthreads();
  }
  if (threadIdx.x == 0) {
    double mean = sh[0] / M;
    double var = sh2[0] / M - mean * mean;
    float rstd = 1.f / sqrtf((float)var + 1e-5f);
    float sc = rstd * g[c];
    scsh[c] = sc;
    scsh[H_ + c] = bb[c] - (float)mean * sc;
  }
}

// one wave per row: y[r] = dot(x[r,:K], w) [+bias] [relu]
__global__ void rowdot_kernel(const float* __restrict__ x, const float* __restrict__ w,
                              int M, int K, const float* __restrict__ bias, int act,
                              float* __restrict__ y) {
  int wid = (blockIdx.x * blockDim.x + threadIdx.x) >> 6;
  int lane = threadIdx.x & 63;
  if (wid >= M) return;
  const float* xr = x + (size_t)wid * K;
  float s = 0.f;
  for (int k = lane; k < K; k += 64) s += xr[k] * w[k];
  for (int off = 32; off; off >>= 1) s += __shfl_down(s, off, 64);
  if (lane == 0) {
    float v = s + (bias ? bias[0] : 0.f);
    if (act == 1) v = fmaxf(v, 0.f);
    y[wid] = v;
  }
}

// -------- sag select: BN-fused rowdot + gcn + topk; writes tant/locs/perm/adjp/gt/pred --------
__global__ __launch_bounds__(256) void sag_select_kernel(
    const float* __restrict__ t1, const float* __restrict__ scsh,
    const float* __restrict__ adj_in, int n, int k,
    const float* __restrict__ pw, const float* __restrict__ pb,
    int* __restrict__ perm, float* __restrict__ tantg, int* __restrict__ locsg,
    float* __restrict__ adjp,
    const float* __restrict__ deg, const float* __restrict__ xdeg,
    float* __restrict__ gt, float* __restrict__ pred) {
  __shared__ float ys[40], dinv[40], scs[40];
  __shared__ int locs[40];
  int b = blockIdx.x;
  int wave = threadIdx.x >> 6, lane = threadIdx.x & 63;
  for (int i = wave; i < n; i += 4) {
    const float* xr = t1 + (size_t)(b * n + i) * H_;
    float s = 0.f;
    for (int kk = lane; kk < H_; kk += 64) {
      float v = fmaxf(xr[kk] * scsh[kk] + scsh[H_ + kk], 0.f);
      s += v * pw[kk];
    }
    for (int off = 32; off; off >>= 1) s += __shfl_down(s, off, 64);
    if (lane == 0) ys[i] = s;
  }
  __syncthreads();
  int i = threadIdx.x;
  if (i < n) {
    const float* ar = adj_in + ((size_t)b * n + i) * n;
    float sum = 1.f;
    for (int j = 0; j < n; ++j) sum += ar[j];
    dinv[i] = 1.f / sqrtf(sum);
  }
  __syncthreads();
  if (i < n) {
    const float* ar = adj_in + ((size_t)b * n + i) * n;
    float acc = 0.f;
    for (int j = 0; j < n; ++j) {
      float a = ar[j] + (i == j ? 1.f : 0.f);
      acc += a * dinv[j] * ys[j];
    }
    scs[i] = dinv[i] * acc + pb[0];
  }
  __syncthreads();
  if (wave == 0) {
    float cur = (lane < n) ? scs[lane] : -INFINITY;
    for (int t = 0; t < k; ++t) {
      float rv = cur;
      int rj = (lane < n) ? lane : (1 << 20);
      wave_argmax64(rv, rj);
      if (lane == 0) {
        tantg[b * k + t] = tanhf(rv);
        locsg[b * k + t] = rj;
        locs[t] = rj;
        perm[b * k + t] = b * n + rj;
      }
      if (lane == rj) cur = -INFINITY;
    }
  }
  __syncthreads();
  if (adjp) {
    for (int e = threadIdx.x; e < k * k; e += 256) {
      int t1i = e / k, t2i = e - t1i * k;
      adjp[(size_t)b * k * k + e] = adj_in[((size_t)b * n + locs[t1i]) * n + locs[t2i]];
    }
  }
  if (gt && threadIdx.x < k) {
    int p = b * n + locs[threadIdx.x];
    gt[b * k + threadIdx.x] = deg[p];
    pred[b * k + threadIdx.x] = xdeg[p];
  }
}

// -------- pool scatter: per-element gather+BN+tanh-scale -> xp triple + xout (h,m) --------
__global__ void pool_scatter_kernel(
    const float* __restrict__ t1, const float* __restrict__ scsh,
    const float* __restrict__ tantg, const int* __restrict__ locsg,
    const int* __restrict__ remap, int n, int k,
    short* __restrict__ xph, short* __restrict__ xpm, short* __restrict__ xpl,
    short* __restrict__ soh, short* __restrict__ som) {
  int t = blockIdx.x * blockDim.x + threadIdx.x;
  if (t >= B_ * k * H_) return;
  int r = t >> 8, hc = t & 255;
  int b = r / k, rr = r - b * k;
  int own = b * n + locsg[b * k + rr];
  float v = fmaxf(t1[(size_t)own * H_ + hc] * scsh[hc] + scsh[H_ + hc], 0.f) * tantg[b * k + rr];
  short hh, mm, ll;
  f2b3(v, hh, mm, ll);
  xph[t] = hh; xpm[t] = mm; xpl[t] = ll;
  int tgt = remap ? remap[own] : own;
  size_t so = (size_t)tgt * H_ + hc;
  soh[so] = hh; som[so] = mm;
}

// -------- readout: z[b] = [max_r xp, mean_r xp] from triple --------
__global__ void readout_kernel(const short* __restrict__ xph, const short* __restrict__ xpm,
                               const short* __restrict__ xpl, int k, int accum,
                               float* __restrict__ z) {
  int t = blockIdx.x * blockDim.x + threadIdx.x;
  if (t >= B_ * H_) return;
  int b = t >> 8, hc = t & 255;
  float mx = -INFINITY, sm = 0.f;
  for (int r = 0; r < k; ++r) {
    size_t o = ((size_t)(b * k + r)) * H_ + hc;
    float v = b2f(xph[o]) + b2f(xpm[o]) + b2f(xpl[o]);
    mx = fmaxf(mx, v);
    sm += v;
  }
  float* zb = z + (size_t)b * 2 * H_;
  float mean = sm / (float)k;
  if (accum) { zb[hc] += mx; zb[H_ + hc] += mean; }
  else       { zb[hc] = mx;  zb[H_ + hc] = mean; }
}

__global__ void gtpred_kernel(const float* __restrict__ deg, const float* __restrict__ xdeg,
                              const int* __restrict__ perm, int M,
                              float* __restrict__ gt, float* __restrict__ pred) {
  int t = blockIdx.x * blockDim.x + threadIdx.x;
  if (t >= M) return;
  int p = perm[t];
  gt[t] = deg[p];
  pred[t] = xdeg[p];
}

__global__ void softmax2_kernel(const float* __restrict__ logits, float* __restrict__ probs) {
  int b = blockIdx.x * blockDim.x + threadIdx.x;
  if (b >= B_) return;
  float a = logits[2 * b], c = logits[2 * b + 1];
  float m = fmaxf(a, c);
  float ea = expf(a - m), ec = expf(c - m);
  float inv = 1.f / (ea + ec);
  probs[2 * b] = ea * inv;
  probs[2 * b + 1] = ec * inv;
}

extern "C" void kernel_launch(void* const* d_in, const int* in_sizes, int n_in,
                              void* d_out, int out_size, void* d_ws, size_t ws_size,
                              hipStream_t stream) {
  auto in = [&](int i) { return (const float*)d_in[i]; };
  const float* x      = in(0);
  const float* adj    = in(1);
  const float* w_mlp1 = in(2);  const float* b_mlp1 = in(3);
  const float* w_mlp2 = in(4);  const float* b_mlp2 = in(5);
  const float* w_mlp3 = in(6);  const float* b_mlp3 = in(7);
  const float* w_mlp6 = in(8);  const float* b_mlp6 = in(9);
  const float* bn1_g = in(10);  const float* bn1_b = in(11);
  const float* bn2_g = in(12);  const float* bn2_b = in(13);
  const float* bn3_g = in(14);  const float* bn3_b = in(15);
  const float* p1_w = in(16);   const float* p1_b = in(17);
  const float* p2_w = in(18);   const float* p2_b = in(19);
  const float* p3_w = in(20);   const float* p3_b = in(21);
  const float* lin1_w = in(22); const float* lin1_b = in(23);
  const float* lin2_w = in(24); const float* lin2_b = in(25);
  const float* lin3_w = in(26); const float* lin3_b = in(27);
  const float* lin4_w = in(28); const float* lin4_b = in(29);
  const float* lin5_w = in(30); const float* lin5_b = in(31);
  const float* lin6_w = in(32); const float* lin6_b = in(33);

  float* out = (float*)d_out;
  float* out_probs = out;
  float* out_dec1  = out_probs + 256;            // 3 x 4992*39 contiguous
  float* out_gt1   = out_dec1 + 3 * 4992 * 39;
  float* out_pred1 = out_gt1 + 4096;
  float* out_gt2   = out_pred1 + 4096;
  float* out_pred2 = out_gt2 + 3328;
  float* out_gt3   = out_pred2 + 3328;
  float* out_pred3 = out_gt3 + 2688;

  char* base = (char*)d_ws;
  size_t off = 0;
  auto allocf = [&](size_t n) -> float* {
    float* p = (float*)(base + off);
    off += ((n * sizeof(float) + 255) & ~(size_t)255);
    return p;
  };
  auto alloci = [&](size_t n) -> int* {
    int* p = (int*)(base + off);
    off += ((n * sizeof(int) + 255) & ~(size_t)255);
    return p;
  };
  auto allocs = [&](size_t n) -> short* {
    short* p = (short*)(base + off);
    off += ((n * sizeof(short) + 255) & ~(size_t)255);
    return p;
  };

  const size_t S = (size_t)4992 * 256;
  const size_t AB_S = (size_t)4992 * 512;
  const int SI = 4992 * KNN_;

  short* wt1h = allocs(512 * 64); short* wt1m = allocs(512 * 64); short* wt1l = allocs(512 * 64);
  short* wt2h = allocs(512 * 256); short* wt2m = allocs(512 * 256); short* wt2l = allocs(512 * 256);
  short* wt3h = allocs(512 * 256); short* wt3m = allocs(512 * 256); short* wt3l = allocs(512 * 256);
  short* wt6h = allocs(78 * 256);  short* wt6m = allocs(78 * 256);
  short* l4h = allocs(256 * 256);  short* l4m = allocs(256 * 256);
  short* l5h = allocs(128 * 256);  short* l5m = allocs(128 * 256);
  short* xsph = allocs(4992 * 64); short* xspm = allocs(4992 * 64); short* xspl = allocs(4992 * 64);
  float* deg  = allocf(4992);
  float* xdeg = allocf(4992);
  int* idxb = alloci(3 * SI);
  float* AB3 = allocf(3 * AB_S);
  float* trunk_t1 = allocf(S);
  float* scsh = allocf(512);
  float* tantg = allocf(4096);
  int* locsg = alloci(4096);
  short* xph = allocs((size_t)4096 * 256); short* xpm = allocs((size_t)4096 * 256); short* xpl = allocs((size_t)4096 * 256);
  size_t ms0 = off;
  short* xoutb_h = allocs(3 * S);
  short* xoutb_m = allocs(3 * S);
  size_t msz = off - ms0;
  short* t1b_h = allocs(3 * S);
  short* t1b_m = allocs(3 * S);
  float* adj1 = allocf(128 * 32 * 32);
  float* adj2 = allocf(128 * 26 * 26);
  int* perm1 = alloci(4096); int* perm2 = alloci(3328); int* perm3 = alloci(2688);
  float* z  = allocf(128 * 512);
  float* z1 = allocf(128 * 256);
  float* z2 = allocf(128 * 128);
  float* logits = allocf(256);
  if (off > ws_size) return;

  // t2b aliases xoutb (dead after decoder stage 1)
  short* t2b_h = xoutb_h; short* t2b_m = xoutb_m;

  // ---- prep + zero scatter targets ----
  prep_kernel<<<dim3(1248, 8), 256, 0, stream>>>(
      w_mlp1, w_mlp2, w_mlp3, w_mlp6, lin4_w, lin5_w, x, adj,
      wt1h, wt1m, wt1l, wt2h, wt2m, wt2l, wt3h, wt3m, wt3l, wt6h, wt6m,
      l4h, l4m, l5h, l5m, xsph, xspm, xspl, deg);
  hipMemsetAsync(xoutb_h, 0, msz, stream);

  // ---- level 1 ----
  gram_knn_kernel<<<B_, 512, 0, stream>>>(xsph, xspm, xspl, 3, 64, N_, 64, idxb);
  {
    dim3 gg(4, 39);
    mfma_gemm_triple_kernel<<<gg, 256, 0, stream>>>(xsph, xspm, xspl, 64,
                                                    wt1h, wt1m, wt1l, AB3, 4992, 512);
  }
  edge_agg_kernel<<<cdiv(4992 * 256, 256), 256, 0, stream>>>(AB3, b_mlp1, idxb, N_, 256, 0, 4992, 4992,
                                                             trunk_t1, nullptr, nullptr, nullptr);
  bn_stats_kernel<<<H_, 256, 0, stream>>>(trunk_t1, 4992, bn1_g, bn1_b, scsh);
  sag_select_kernel<<<B_, 256, 0, stream>>>(trunk_t1, scsh, adj, N_, K1_, p1_w, p1_b,
                                            perm1, tantg, locsg, adj1,
                                            nullptr, nullptr, nullptr, nullptr);
  pool_scatter_kernel<<<cdiv(B_ * K1_ * H_, 256), 256, 0, stream>>>(
      trunk_t1, scsh, tantg, locsg, nullptr, N_, K1_, xph, xpm, xpl, xoutb_h, xoutb_m);
  readout_kernel<<<cdiv(B_ * H_, 256), 256, 0, stream>>>(xph, xpm, xpl, K1_, 0, z);
  {  // degree head from x_out1
    dim3 g4(2, 39, 1);
    mfma_gemm_split_kernel<<<g4, 256, 0, stream>>>(xoutb_h, xoutb_m, l4h, l4m, lin4_b,
                                                   trunk_t1, t1b_h, t1b_m, 4992, 256, 256, 1, 0, 0);
    dim3 g5(1, 39, 1);
    mfma_gemm_split_kernel<<<g5, 256, 0, stream>>>(t1b_h, t1b_m, l5h, l5m, lin5_b,
                                                   AB3, nullptr, nullptr, 4992, 128, 256, 1, 0, 0);
  }
  rowdot_kernel<<<cdiv(4992 * 64, 256), 256, 0, stream>>>(AB3, lin6_w, 4992, 128, lin6_b, 1, xdeg);
  gtpred_kernel<<<cdiv(4096, 256), 256, 0, stream>>>(deg, xdeg, perm1, 4096, out_gt1, out_pred1);

  // ---- level 2 ----
  gram_knn_kernel<<<B_, 512, 0, stream>>>(xph, xpm, xpl, 3, 256, K1_, 256, idxb);
  {
    dim3 gg(4, 32);
    mfma_gemm_triple_kernel<<<gg, 256, 0, stream>>>(xph, xpm, xpl, 256,
                                                    wt2h, wt2m, wt2l, AB3, 4096, 512);
  }
  edge_agg_kernel<<<cdiv(4096 * 256, 256), 256, 0, stream>>>(AB3, b_mlp2, idxb, K1_, 256, 0, 4096, 4096,
                                                             trunk_t1, nullptr, nullptr, nullptr);
  bn_stats_kernel<<<H_, 256, 0, stream>>>(trunk_t1, 4096, bn2_g, bn2_b, scsh);
  sag_select_kernel<<<B_, 256, 0, stream>>>(trunk_t1, scsh, adj1, K1_, K2_, p2_w, p2_b,
                                            perm2, tantg, locsg, adj2,
                                            deg, xdeg, out_gt2, out_pred2);
  pool_scatter_kernel<<<cdiv(B_ * K2_ * H_, 256), 256, 0, stream>>>(
      trunk_t1, scsh, tantg, locsg, perm1, K1_, K2_, xph, xpm, xpl, xoutb_h + S, xoutb_m + S);
  readout_kernel<<<cdiv(B_ * H_, 256), 256, 0, stream>>>(xph, xpm, xpl, K2_, 1, z);

  // ---- level 3 ----
  gram_knn_kernel<<<B_, 512, 0, stream>>>(xph, xpm, xpl, 3, 256, K2_, 256, idxb);
  {
    dim3 gg(4, 26);
    mfma_gemm_triple_kernel<<<gg, 256, 0, stream>>>(xph, xpm, xpl, 256,
                                                    wt3h, wt3m, wt3l, AB3, 3328, 512);
  }
  edge_agg_kernel<<<cdiv(3328 * 256, 256), 256, 0, stream>>>(AB3, b_mlp3, idxb, K2_, 256, 0, 3328, 3328,
                                                             trunk_t1, nullptr, nullptr, nullptr);
  bn_stats_kernel<<<H_, 256, 0, stream>>>(trunk_t1, 3328, bn3_g, bn3_b, scsh);
  sag_select_kernel<<<B_, 256, 0, stream>>>(trunk_t1, scsh, adj2, K2_, K3_, p3_w, p3_b,
                                            perm3, tantg, locsg, nullptr,
                                            deg, xdeg, out_gt3, out_pred3);
  pool_scatter_kernel<<<cdiv(B_ * K3_ * H_, 256), 256, 0, stream>>>(
      trunk_t1, scsh, tantg, locsg, perm2, K2_, K3_, xph, xpm, xpl, xoutb_h + 2 * S, xoutb_m + 2 * S);
  readout_kernel<<<cdiv(B_ * H_, 256), 256, 0, stream>>>(xph, xpm, xpl, K3_, 1, z);

  // ---- classifier head ----
  rowgemm_kernel<<<128, 256, 0, stream>>>(z, lin1_w, lin1_b, z1, 256, 512, 1);
  rowgemm_kernel<<<128, 256, 0, stream>>>(z1, lin2_w, lin2_b, z2, 128, 256, 1);
  wavedot_gemm_kernel<<<cdiv(128 * 2 * 64, 256), 256, 0, stream>>>(z2, lin3_w, lin3_b, logits, 128, 2, 128, 0);
  softmax2_kernel<<<1, 128, 0, stream>>>(logits, out_probs);

  // ---- batched decoders (3 independent, share weights; z-batched gemm, 384-graph knn) ----
  // stage 1: wcat3, tanh
  gram_knn_kernel<<<3 * B_, 512, 0, stream>>>(xoutb_h, xoutb_m, nullptr, 2, 256, N_, 256, idxb);
  {
    dim3 gg(4, 39, 3);
    mfma_gemm_split_kernel<<<gg, 256, 0, stream>>>(xoutb_h, xoutb_m, wt3h, wt3m, nullptr,
                                                   AB3, nullptr, nullptr, 4992, 512, 256, 0, S, AB_S);
  }
  edge_agg_kernel<<<cdiv(3 * 4992 * 256, 256), 256, 0, stream>>>(
      AB3, b_mlp3, idxb, N_, 256, 2, 3 * 4992, 4992, nullptr, t1b_h, t1b_m, nullptr);
  // stage 2: wcat2, tanh
  gram_knn_kernel<<<3 * B_, 512, 0, stream>>>(t1b_h, t1b_m, nullptr, 2, 256, N_, 256, idxb);
  {
    dim3 gg(4, 39, 3);
    mfma_gemm_split_kernel<<<gg, 256, 0, stream>>>(t1b_h, t1b_m, wt2h, wt2m, nullptr,
                                                   AB3, nullptr, nullptr, 4992, 512, 256, 0, S, AB_S);
  }
  edge_agg_kernel<<<cdiv(3 * 4992 * 256, 256), 256, 0, stream>>>(
      AB3, b_mlp2, idxb, N_, 256, 2, 3 * 4992, 4992, nullptr, t2b_h, t2b_m, nullptr);
  // stage 3: wcat6, linear -> out_dec
  gram_knn_kernel<<<3 * B_, 512, 0, stream>>>(t2b_h, t2b_m, nullptr, 2, 256, N_, 256, idxb);
  {
    dim3 gg(1, 39, 3);
    mfma_gemm_split_kernel<<<gg, 256, 0, stream>>>(t2b_h, t2b_m, wt6h, wt6m, nullptr,
                                                   AB3, nullptr, nullptr, 4992, 78, 256, 0, S, (size_t)4992 * 78);
  }
  edge_agg_kernel<<<cdiv(3 * 4992 * 39, 256), 256, 0, stream>>>(
      AB3, b_mlp6, idxb, N_, 39, 0, 3 * 4992, 4992, out_dec1, nullptr, nullptr, nullptr);
}

// Round 15
// 660.774 us; speedup vs baseline: 2.0473x; 1.2466x over previous
//
#include <hip/hip_runtime.h>
#include <cmath>

#define B_   128
#define N_   39
#define KNN_ 10
#define H_   256
#define K1_  32
#define K2_  26
#define K3_  21

static inline int cdiv(int a, int b) { return (a + b - 1) / b; }

typedef __attribute__((ext_vector_type(8))) short short8;
typedef __attribute__((ext_vector_type(4))) short short4v;
typedef __attribute__((ext_vector_type(4))) float floatx4;

__device__ inline short f2b(float f) {   // fp32 -> bf16 RNE
  unsigned u = __float_as_uint(f);
  u += 0x7fff + ((u >> 16) & 1);
  return (short)(u >> 16);
}
__device__ inline float b2f(short h) {
  return __uint_as_float(((unsigned)(unsigned short)h) << 16);
}
__device__ inline void f2b3(float v, short& h, short& m, short& l) {  // v ~= h+m+l (24 bits)
  h = f2b(v);
  float r1 = v - b2f(h);
  m = f2b(r1);
  l = f2b(r1 - b2f(m));
}

// ------------- one-shot prep: weights triple-split transposed + x split + degree -------------
__global__ void prep_kernel(
    const float* __restrict__ w1, const float* __restrict__ w2,
    const float* __restrict__ w3, const float* __restrict__ w6,
    const float* __restrict__ l4, const float* __restrict__ l5,
    const float* __restrict__ x, const float* __restrict__ adj,
    short* __restrict__ wt1h, short* __restrict__ wt1m, short* __restrict__ wt1l,
    short* __restrict__ wt2h, short* __restrict__ wt2m, short* __restrict__ wt2l,
    short* __restrict__ wt3h, short* __restrict__ wt3m, short* __restrict__ wt3l,
    short* __restrict__ wt6h, short* __restrict__ wt6m,
    short* __restrict__ l4h, short* __restrict__ l4m,
    short* __restrict__ l5h, short* __restrict__ l5m,
    short* __restrict__ xsph, short* __restrict__ xspm, short* __restrict__ xspl,
    float* __restrict__ deg) {
  int task = blockIdx.y;
  int t = blockIdx.x * 256 + threadIdx.x;
  if (task == 0) {            // wcat1 tripleT: [512][64], K=39 padded
    if (t >= 512 * 64) return;
    int nn = t >> 6, k = t & 63;
    float v = 0.f;
    if (k < 39) v = (nn < 256) ? w1[k * 256 + nn] - w1[(39 + k) * 256 + nn]
                               : w1[(39 + k) * 256 + (nn - 256)];
    short h, m, l; f2b3(v, h, m, l);
    wt1h[t] = h; wt1m[t] = m; wt1l[t] = l;
  } else if (task == 1) {     // wcat2 tripleT: [512][256]
    if (t >= 512 * 256) return;
    int nn = t >> 8, k = t & 255;
    float v = (nn < 256) ? w2[k * 256 + nn] - w2[(256 + k) * 256 + nn]
                         : w2[(256 + k) * 256 + (nn - 256)];
    short h, m, l; f2b3(v, h, m, l);
    wt2h[t] = h; wt2m[t] = m; wt2l[t] = l;
  } else if (task == 2) {     // wcat3 tripleT
    if (t >= 512 * 256) return;
    int nn = t >> 8, k = t & 255;
    float v = (nn < 256) ? w3[k * 256 + nn] - w3[(256 + k) * 256 + nn]
                         : w3[(256 + k) * 256 + (nn - 256)];
    short h, m, l; f2b3(v, h, m, l);
    wt3h[t] = h; wt3m[t] = m; wt3l[t] = l;
  } else if (task == 3) {     // wcat6 T (h,m): [78][256]
    if (t >= 78 * 256) return;
    int nn = t >> 8, k = t & 255;
    float v = (nn < 39) ? w6[k * 39 + nn] - w6[(256 + k) * 39 + nn]
                        : w6[(256 + k) * 39 + (nn - 39)];
    short h, m, l; f2b3(v, h, m, l);
    wt6h[t] = h; wt6m[t] = m;
  } else if (task == 4) {     // lin4 T (h,m): [256][256]
    if (t >= 256 * 256) return;
    int nn = t >> 8, k = t & 255;
    short h, m, l; f2b3(l4[k * 256 + nn], h, m, l);
    l4h[t] = h; l4m[t] = m;
  } else if (task == 5) {     // lin5 T (h,m): [128][256]
    if (t >= 128 * 256) return;
    int nn = t >> 8, k = t & 255;
    short h, m, l; f2b3(l5[k * 128 + nn], h, m, l);
    l5h[t] = h; l5m[t] = m;
  } else if (task == 6) {     // x split: [4992][64], F=39 padded
    if (t >= 4992 * 64) return;
    int r = t >> 6, k = t & 63;
    float v = (k < 39) ? x[r * 39 + k] : 0.f;
    short h, m, l; f2b3(v, h, m, l);
    xsph[t] = h; xspm[t] = m; xspl[t] = l;
  } else {                    // degree
    if (t >= B_ * N_) return;
    const float* row = adj + (size_t)t * N_;
    float s = 0.f;
    for (int j = 0; j < N_; ++j) s += row[j];
    deg[t] = s;
  }
}

// ------------- MFMA gram + rank-parallel KNN (block per graph, 512 thr) -------------
__global__ __launch_bounds__(512) void gram_knn_kernel(
    const short* __restrict__ xh, const short* __restrict__ xm, const short* __restrict__ xl,
    int nterms, int Ks, int n, int F32, int* __restrict__ idx) {
  __shared__ short sh_h[48 * 40], sh_m[48 * 40], sh_l[48 * 40];
  __shared__ float Gs[48][49];
  __shared__ float diag[48];
  int b = blockIdx.x;
  int tid = threadIdx.x;
  int wave = tid >> 6, lane = tid & 63;
  int lm = lane & 15, lk = (lane >> 4) * 8;
  int nt = (n + 15) >> 4;
  int tasks = nt * nt;
  floatx4 acc[2] = {};
  int stage_elems = 384 * nterms;
  for (int k0 = 0; k0 < F32; k0 += 32) {
    for (int e = tid; e < stage_elems; e += 512) {
      int a = e / 384, rem = e - a * 384;
      int r = rem >> 3, c4 = (rem & 7) * 4;
      const short* src = (a == 0) ? xh : (a == 1) ? xm : xl;
      short* dst = (a == 0) ? sh_h : (a == 1) ? sh_m : sh_l;
      short4v v = {};
      if (r < n) v = *(const short4v*)&src[((size_t)(b * n + r)) * Ks + k0 + c4];
      *(short4v*)&dst[r * 40 + c4] = v;
    }
    __syncthreads();
#pragma unroll
    for (int ai = 0; ai < 2; ++ai) {
      int t = wave + ai * 8;
      if (t < tasks) {
        int ti = t / nt, tj = t - ti * nt;
        int ra = (ti * 16 + lm) * 40 + lk;
        int rb = (tj * 16 + lm) * 40 + lk;
        short8 ah = *(const short8*)&sh_h[ra];
        short8 am = *(const short8*)&sh_m[ra];
        short8 bh = *(const short8*)&sh_h[rb];
        short8 bm = *(const short8*)&sh_m[rb];
        floatx4 a = acc[ai];
        a = __builtin_amdgcn_mfma_f32_16x16x32_bf16(ah, bh, a, 0, 0, 0);
        a = __builtin_amdgcn_mfma_f32_16x16x32_bf16(ah, bm, a, 0, 0, 0);
        a = __builtin_amdgcn_mfma_f32_16x16x32_bf16(am, bh, a, 0, 0, 0);
        if (nterms == 3) {
          short8 al = *(const short8*)&sh_l[ra];
          short8 bl = *(const short8*)&sh_l[rb];
          a = __builtin_amdgcn_mfma_f32_16x16x32_bf16(ah, bl, a, 0, 0, 0);
          a = __builtin_amdgcn_mfma_f32_16x16x32_bf16(al, bh, a, 0, 0, 0);
          a = __builtin_amdgcn_mfma_f32_16x16x32_bf16(am, bm, a, 0, 0, 0);
        }
        acc[ai] = a;
      }
    }
    __syncthreads();
  }
#pragma unroll
  for (int ai = 0; ai < 2; ++ai) {
    int t = wave + ai * 8;
    if (t < tasks) {
      int ti = t / nt, tj = t - ti * nt;
      int col = tj * 16 + lm;
      int rbase = ti * 16 + (lane >> 4) * 4;
#pragma unroll
      for (int r = 0; r < 4; ++r) Gs[rbase + r][col] = acc[ai][r];
    }
  }
  __syncthreads();
  if (tid < 48) diag[tid] = (tid < n) ? Gs[tid][tid] : INFINITY;
  __syncthreads();
  // rank-parallel selection: row per wave, lane j holds d_j; rank via wave-uniform scan
  for (int row = wave; row < n; row += 8) {
    float gii = diag[row];
    float dj = (lane < n) ? (gii + diag[lane] - 2.f * Gs[row][lane]) : INFINITY;
    int rank = 0;
    for (int j = 0; j < n; ++j) {
      float djp = gii + diag[j] - 2.f * Gs[row][j];   // LDS broadcast
      rank += (djp < dj || (djp == dj && j < lane)) ? 1 : 0;
    }
    if (lane < n && rank < KNN_)
      idx[(size_t)(b * n + row) * KNN_ + rank] = lane;
  }
}

// ------------- triple-split 6-term MFMA GEMM (trunk; fp32-faithful ~2^-24) -------------
__global__ __launch_bounds__(256) void mfma_gemm_triple_kernel(
    const short* __restrict__ Ah, const short* __restrict__ Am, const short* __restrict__ Al,
    int Ks,
    const short* __restrict__ Wh, const short* __restrict__ Wm, const short* __restrict__ Wl,
    float* __restrict__ C, int M, int N) {
  __shared__ short Ash[128 * 40], Asm[128 * 40], Asl[128 * 40];
  __shared__ short Bsh[128 * 40], Bsm[128 * 40], Bsl[128 * 40];
  int tid = threadIdx.x;
  int wave = tid >> 6, lane = tid & 63;
  int wm = wave & 1, wn = wave >> 1;
  int row0 = blockIdx.y * 128, col0 = blockIdx.x * 128;
  floatx4 acc[4][4] = {};
  int lm = lane & 15, lk = (lane >> 4) * 8;
  for (int k0 = 0; k0 < Ks; k0 += 32) {
    for (int e = tid; e < 1536; e += 256) {
      int a = e / 512, rem = e - a * 512;
      int r = rem >> 2, kc = (rem & 3) * 8;
      const short* src = (a == 0) ? Ah : (a == 1) ? Am : Al;
      short* dst = (a == 0) ? Ash : (a == 1) ? Asm : Asl;
      *(short8*)&dst[r * 40 + kc] = *(const short8*)&src[((size_t)(row0 + r)) * Ks + k0 + kc];
    }
    for (int e = tid; e < 1536; e += 256) {
      int a = e / 512, rem = e - a * 512;
      int r = rem >> 2, kc = (rem & 3) * 8;
      const short* src = (a == 0) ? Wh : (a == 1) ? Wm : Wl;
      short* dst = (a == 0) ? Bsh : (a == 1) ? Bsm : Bsl;
      *(short8*)&dst[r * 40 + kc] = *(const short8*)&src[((size_t)(col0 + r)) * Ks + k0 + kc];
    }
    __syncthreads();
    short8 afh[4], afm[4], afl[4];
#pragma unroll
    for (int mi = 0; mi < 4; ++mi) {
      int ro = (wm * 64 + mi * 16 + lm) * 40 + lk;
      afh[mi] = *(const short8*)&Ash[ro];
      afm[mi] = *(const short8*)&Asm[ro];
      afl[mi] = *(const short8*)&Asl[ro];
    }
#pragma unroll
    for (int ni = 0; ni < 4; ++ni) {
      int ro = (wn * 64 + ni * 16 + lm) * 40 + lk;
      short8 bfh = *(const short8*)&Bsh[ro];
      short8 bfm = *(const short8*)&Bsm[ro];
      short8 bfl = *(const short8*)&Bsl[ro];
#pragma unroll
      for (int mi = 0; mi < 4; ++mi) {
        floatx4 a = acc[mi][ni];
        a = __builtin_amdgcn_mfma_f32_16x16x32_bf16(afh[mi], bfh, a, 0, 0, 0);
        a = __builtin_amdgcn_mfma_f32_16x16x32_bf16(afh[mi], bfm, a, 0, 0, 0);
        a = __builtin_amdgcn_mfma_f32_16x16x32_bf16(afm[mi], bfh, a, 0, 0, 0);
        a = __builtin_amdgcn_mfma_f32_16x16x32_bf16(afh[mi], bfl, a, 0, 0, 0);
        a = __builtin_amdgcn_mfma_f32_16x16x32_bf16(afl[mi], bfh, a, 0, 0, 0);
        a = __builtin_amdgcn_mfma_f32_16x16x32_bf16(afm[mi], bfm, a, 0, 0, 0);
        acc[mi][ni] = a;
      }
    }
    __syncthreads();
  }
  int lr = (lane >> 4) * 4;
#pragma unroll
  for (int mi = 0; mi < 4; ++mi)
#pragma unroll
    for (int ni = 0; ni < 4; ++ni) {
      int colg = col0 + wn * 64 + ni * 16 + lm;
#pragma unroll
      for (int r = 0; r < 4; ++r) {
        int rowg = row0 + wm * 64 + mi * 16 + lr + r;
        C[(size_t)rowg * N + colg] = acc[mi][ni][r];
      }
    }
}

// ------------- 2-term split MFMA GEMM (decoder/degree head, ~2^-16); z-batched -------------
__global__ __launch_bounds__(256) void mfma_gemm_split_kernel(
    const short* __restrict__ Ah0, const short* __restrict__ Al0,
    const short* __restrict__ Wth, const short* __restrict__ Wtl,
    const float* __restrict__ bias,
    float* __restrict__ C0, short* __restrict__ Ch0, short* __restrict__ Cl0,
    int M, int N, int K, int act, size_t Astride, size_t Cstride) {
  const short* Ah = Ah0 + blockIdx.z * Astride;
  const short* Al = Al0 + blockIdx.z * Astride;
  float* C = C0 + blockIdx.z * Cstride;
  short* Ch = Ch0 ? Ch0 + blockIdx.z * Cstride : nullptr;
  short* Cl = Cl0 ? Cl0 + blockIdx.z * Cstride : nullptr;
  __shared__ short Ash[128 * 40];
  __shared__ short Asl[128 * 40];
  __shared__ short Bsh[128 * 40];
  __shared__ short Bsl[128 * 40];
  int tid = threadIdx.x;
  int wave = tid >> 6, lane = tid & 63;
  int wm = wave & 1, wn = wave >> 1;
  int row0 = blockIdx.y * 128, col0 = blockIdx.x * 128;
  floatx4 acc[4][4] = {};
  int lm = lane & 15, lk = (lane >> 4) * 8;
  for (int k0 = 0; k0 < K; k0 += 32) {
    for (int c = tid; c < 512; c += 256) {
      int r = c >> 2, kc = (c & 3) * 8;
      int grow = row0 + r;
      short8 vh = {}, vl = {};
      if (grow < M) {
        vh = *(const short8*)&Ah[(size_t)grow * K + k0 + kc];
        vl = *(const short8*)&Al[(size_t)grow * K + k0 + kc];
      }
      *(short8*)&Ash[r * 40 + kc] = vh;
      *(short8*)&Asl[r * 40 + kc] = vl;
    }
    for (int c = tid; c < 512; c += 256) {
      int r = c >> 2, kc = (c & 3) * 8;
      int gn = col0 + r;
      short8 vh = {}, vl = {};
      if (gn < N) {
        vh = *(const short8*)&Wth[(size_t)gn * K + k0 + kc];
        vl = *(const short8*)&Wtl[(size_t)gn * K + k0 + kc];
      }
      *(short8*)&Bsh[r * 40 + kc] = vh;
      *(short8*)&Bsl[r * 40 + kc] = vl;
    }
    __syncthreads();
    short8 afh[4], afl[4], bfh[4], bfl[4];
#pragma unroll
    for (int mi = 0; mi < 4; ++mi) {
      int ro = (wm * 64 + mi * 16 + lm) * 40 + lk;
      afh[mi] = *(const short8*)&Ash[ro];
      afl[mi] = *(const short8*)&Asl[ro];
    }
#pragma unroll
    for (int ni = 0; ni < 4; ++ni) {
      int ro = (wn * 64 + ni * 16 + lm) * 40 + lk;
      bfh[ni] = *(const short8*)&Bsh[ro];
      bfl[ni] = *(const short8*)&Bsl[ro];
    }
#pragma unroll
    for (int mi = 0; mi < 4; ++mi)
#pragma unroll
      for (int ni = 0; ni < 4; ++ni) {
        acc[mi][ni] = __builtin_amdgcn_mfma_f32_16x16x32_bf16(afh[mi], bfh[ni], acc[mi][ni], 0, 0, 0);
        acc[mi][ni] = __builtin_amdgcn_mfma_f32_16x16x32_bf16(afh[mi], bfl[ni], acc[mi][ni], 0, 0, 0);
        acc[mi][ni] = __builtin_amdgcn_mfma_f32_16x16x32_bf16(afl[mi], bfh[ni], acc[mi][ni], 0, 0, 0);
      }
    __syncthreads();
  }
  int lr = (lane >> 4) * 4;
#pragma unroll
  for (int mi = 0; mi < 4; ++mi)
#pragma unroll
    for (int ni = 0; ni < 4; ++ni) {
      int colg = col0 + wn * 64 + ni * 16 + lm;
      if (colg >= N) continue;
      float bv = bias ? bias[colg] : 0.f;
#pragma unroll
      for (int r = 0; r < 4; ++r) {
        int rowg = row0 + wm * 64 + mi * 16 + lr + r;
        if (rowg >= M) continue;
        float v = acc[mi][ni][r] + bv;
        if (act == 1) v = fmaxf(v, 0.f);
        C[(size_t)rowg * N + colg] = v;
        if (Ch) {
          short hi = f2b(v);
          short lo = f2b(v - b2f(hi));
          Ch[(size_t)rowg * N + colg] = hi;
          Cl[(size_t)rowg * N + colg] = lo;
        }
      }
    }
}

// Thin GEMM (small M): one block per row.
__global__ __launch_bounds__(256) void rowgemm_kernel(
    const float* __restrict__ A, const float* __restrict__ W, const float* __restrict__ bias,
    float* __restrict__ C, int N, int K, int act) {
  __shared__ float a[512];
  int row = blockIdx.x;
  for (int k = threadIdx.x; k < K; k += 256) a[k] = A[(size_t)row * K + k];
  __syncthreads();
  for (int c = threadIdx.x; c < N; c += 256) {
    float s = 0.f;
    for (int k = 0; k < K; k += 4) {
      float4 av = *(const float4*)&a[k];
      s += av.x * W[(size_t)k * N + c];
      s += av.y * W[(size_t)(k + 1) * N + c];
      s += av.z * W[(size_t)(k + 2) * N + c];
      s += av.w * W[(size_t)(k + 3) * N + c];
    }
    float v = s + (bias ? bias[c] : 0.f);
    if (act == 1) v = fmaxf(v, 0.f);
    C[(size_t)row * N + c] = v;
  }
}

// one wave per output element (for very small M*N)
__global__ void wavedot_gemm_kernel(const float* __restrict__ A, const float* __restrict__ W,
                                    const float* __restrict__ bias, float* __restrict__ C,
                                    int M, int N, int K, int act) {
  int wid = (blockIdx.x * blockDim.x + threadIdx.x) >> 6;
  int lane = threadIdx.x & 63;
  if (wid >= M * N) return;
  int row = wid / N, col = wid - row * N;
  const float* ar = A + (size_t)row * K;
  float s = 0.f;
  for (int k = lane; k < K; k += 64) s += ar[k] * W[(size_t)k * N + col];
  for (int off = 32; off; off >>= 1) s += __shfl_down(s, off, 64);
  if (lane == 0) {
    float v = s + (bias ? bias[col] : 0.f);
    if (act == 1) v = fmaxf(v, 0.f);
    C[(size_t)row * N + col] = v;
  }
}

// edge agg over global rows (batched decoders: d = r / per); AB is (rows x 2Hc)
__global__ void edge_agg_kernel(const float* __restrict__ AB, const float* __restrict__ bias,
                                const int* __restrict__ idx, int n, int Hc, int act,
                                int rows, int per,
                                float* __restrict__ out,
                                short* __restrict__ outh, short* __restrict__ outm,
                                short* __restrict__ outl) {
  int t = blockIdx.x * blockDim.x + threadIdx.x;
  if (t >= rows * Hc) return;
  int r = t / Hc, h = t - r * Hc;
  int d = r / per, rloc = r - d * per;
  int b = rloc / n;
  int s2 = 2 * Hc;
  float av = AB[(size_t)r * s2 + h] + bias[h];
  const int* ir = idx + ((size_t)d * per + rloc) * KNN_;
  int base = d * per + b * n;
  float m = -INFINITY;
  for (int k = 0; k < KNN_; ++k) {
    float v = av + AB[(size_t)(base + ir[k]) * s2 + Hc + h];
    v = fmaxf(v, 0.f);
    m = fmaxf(m, v);
  }
  if (act == 2) m = tanhf(m);
  if (out) out[t] = m;
  if (outh) {
    short hh, mm, ll;
    f2b3(m, hh, mm, ll);
    outh[t] = hh; outm[t] = mm;
    if (outl) outl[t] = ll;
  }
}

// BN stats -> per-column scale/shift: norm(v) = relu(v*sc + sh)
__global__ void bn_stats_kernel(const float* __restrict__ xx, int M,
                                const float* __restrict__ g, const float* __restrict__ bb,
                                float* __restrict__ scsh) {
  int c = blockIdx.x;
  double s = 0.0, s2 = 0.0;
  for (int r = threadIdx.x; r < M; r += 256) {
    double v = (double)xx[(size_t)r * H_ + c];
    s += v; s2 += v * v;
  }
  __shared__ double sh[256], sh2[256];
  sh[threadIdx.x] = s; sh2[threadIdx.x] = s2;
  __syncthreads();
  for (int o = 128; o; o >>= 1) {
    if (threadIdx.x < o) { sh[threadIdx.x] += sh[threadIdx.x + o]; sh2[threadIdx.x] += sh2[threadIdx.x + o]; }
    __syncthreads();
  }
  if (threadIdx.x == 0) {
    double mean = sh[0] / M;
    double var = sh2[0] / M - mean * mean;
    float rstd = 1.f / sqrtf((float)var + 1e-5f);
    float sc = rstd * g[c];
    scsh[c] = sc;
    scsh[H_ + c] = bb[c] - (float)mean * sc;
  }
}

// BN-fused rowdot (wave per row): ys[r] = sum_k relu(t1*sc+sh) * pw
__global__ void bnrowdot_kernel(const float* __restrict__ t1, const float* __restrict__ scsh,
                                const float* __restrict__ pw, int M, float* __restrict__ ys) {
  int wid = (blockIdx.x * blockDim.x + threadIdx.x) >> 6;
  int lane = threadIdx.x & 63;
  if (wid >= M) return;
  const float* xr = t1 + (size_t)wid * H_;
  float s = 0.f;
  for (int k = lane; k < H_; k += 64) {
    float v = fmaxf(xr[k] * scsh[k] + scsh[H_ + k], 0.f);
    s += v * pw[k];
  }
  for (int off = 32; off; off >>= 1) s += __shfl_down(s, off, 64);
  if (lane == 0) ys[wid] = s;
}

// one wave per row: y[r] = dot(x[r,:K], w) [+bias] [relu]
__global__ void rowdot_kernel(const float* __restrict__ x, const float* __restrict__ w,
                              int M, int K, const float* __restrict__ bias, int act,
                              float* __restrict__ y) {
  int wid = (blockIdx.x * blockDim.x + threadIdx.x) >> 6;
  int lane = threadIdx.x & 63;
  if (wid >= M) return;
  const float* xr = x + (size_t)wid * K;
  float s = 0.f;
  for (int k = lane; k < K; k += 64) s += xr[k] * w[k];
  for (int off = 32; off; off >>= 1) s += __shfl_down(s, off, 64);
  if (lane == 0) {
    float v = s + (bias ? bias[0] : 0.f);
    if (act == 1) v = fmaxf(v, 0.f);
    y[wid] = v;
  }
}

// -------- sag select: gcn + rank-parallel topk; writes tant/locs/perm/adjp/gt/pred --------
__global__ __launch_bounds__(256) void sag_select_kernel(
    const float* __restrict__ ysg,
    const float* __restrict__ adj_in, int n, int k,
    const float* __restrict__ pb,
    int* __restrict__ perm, float* __restrict__ tantg, int* __restrict__ locsg,
    float* __restrict__ adjp,
    const float* __restrict__ deg, const float* __restrict__ xdeg,
    float* __restrict__ gt, float* __restrict__ pred) {
  __shared__ float ys[40], dinv[40], scs[40];
  __shared__ int locs[40];
  int b = blockIdx.x;
  int i = threadIdx.x;
  if (i < n) {
    ys[i] = ysg[b * n + i];
    const float* ar = adj_in + ((size_t)b * n + i) * n;
    float sum = 1.f;
    for (int j = 0; j < n; ++j) sum += ar[j];
    dinv[i] = 1.f / sqrtf(sum);
  }
  __syncthreads();
  if (i < n) {
    const float* ar = adj_in + ((size_t)b * n + i) * n;
    float acc = 0.f;
    for (int j = 0; j < n; ++j) {
      float a = ar[j] + (i == j ? 1.f : 0.f);
      acc += a * dinv[j] * ys[j];
    }
    scs[i] = dinv[i] * acc + pb[0];
  }
  __syncthreads();
  if (i < n) {   // rank-based stable descending top-k (ties -> lowest index)
    float si = scs[i];
    int rank = 0;
    for (int j = 0; j < n; ++j) {
      float sj = scs[j];
      rank += (sj > si || (sj == si && j < i)) ? 1 : 0;
    }
    if (rank < k) {
      tantg[b * k + rank] = tanhf(si);
      locsg[b * k + rank] = i;
      locs[rank] = i;
      perm[b * k + rank] = b * n + i;
    }
  }
  __syncthreads();
  if (adjp) {
    for (int e = threadIdx.x; e < k * k; e += 256) {
      int t1i = e / k, t2i = e - t1i * k;
      adjp[(size_t)b * k * k + e] = adj_in[((size_t)b * n + locs[t1i]) * n + locs[t2i]];
    }
  }
  if (gt && threadIdx.x < k) {
    int p = b * n + locs[threadIdx.x];
    gt[b * k + threadIdx.x] = deg[p];
    pred[b * k + threadIdx.x] = xdeg[p];
  }
}

// -------- pool scatter: per-element gather+BN+tanh-scale -> xp triple + xout (h,m) --------
__global__ void pool_scatter_kernel(
    const float* __restrict__ t1, const float* __restrict__ scsh,
    const float* __restrict__ tantg, const int* __restrict__ locsg,
    const int* __restrict__ remap, int n, int k,
    short* __restrict__ xph, short* __restrict__ xpm, short* __restrict__ xpl,
    short* __restrict__ soh, short* __restrict__ som) {
  int t = blockIdx.x * blockDim.x + threadIdx.x;
  if (t >= B_ * k * H_) return;
  int r = t >> 8, hc = t & 255;
  int b = r / k, rr = r - b * k;
  int own = b * n + locsg[b * k + rr];
  float v = fmaxf(t1[(size_t)own * H_ + hc] * scsh[hc] + scsh[H_ + hc], 0.f) * tantg[b * k + rr];
  short hh, mm, ll;
  f2b3(v, hh, mm, ll);
  xph[t] = hh; xpm[t] = mm; xpl[t] = ll;
  int tgt = remap ? remap[own] : own;
  size_t so = (size_t)tgt * H_ + hc;
  soh[so] = hh; som[so] = mm;
}

// -------- readout: z[b] = [max_r xp, mean_r xp] from triple --------
__global__ void readout_kernel(const short* __restrict__ xph, const short* __restrict__ xpm,
                               const short* __restrict__ xpl, int k, int accum,
                               float* __restrict__ z) {
  int t = blockIdx.x * blockDim.x + threadIdx.x;
  if (t >= B_ * H_) return;
  int b = t >> 8, hc = t & 255;
  float mx = -INFINITY, sm = 0.f;
  for (int r = 0; r < k; ++r) {
    size_t o = ((size_t)(b * k + r)) * H_ + hc;
    float v = b2f(xph[o]) + b2f(xpm[o]) + b2f(xpl[o]);
    mx = fmaxf(mx, v);
    sm += v;
  }
  float* zb = z + (size_t)b * 2 * H_;
  float mean = sm / (float)k;
  if (accum) { zb[hc] += mx; zb[H_ + hc] += mean; }
  else       { zb[hc] = mx;  zb[H_ + hc] = mean; }
}

__global__ void gtpred_kernel(const float* __restrict__ deg, const float* __restrict__ xdeg,
                              const int* __restrict__ perm, int M,
                              float* __restrict__ gt, float* __restrict__ pred) {
  int t = blockIdx.x * blockDim.x + threadIdx.x;
  if (t >= M) return;
  int p = perm[t];
  gt[t] = deg[p];
  pred[t] = xdeg[p];
}

__global__ void softmax2_kernel(const float* __restrict__ logits, float* __restrict__ probs) {
  int b = blockIdx.x * blockDim.x + threadIdx.x;
  if (b >= B_) return;
  float a = logits[2 * b], c = logits[2 * b + 1];
  float m = fmaxf(a, c);
  float ea = expf(a - m), ec = expf(c - m);
  float inv = 1.f / (ea + ec);
  probs[2 * b] = ea * inv;
  probs[2 * b + 1] = ec * inv;
}

extern "C" void kernel_launch(void* const* d_in, const int* in_sizes, int n_in,
                              void* d_out, int out_size, void* d_ws, size_t ws_size,
                              hipStream_t stream) {
  auto in = [&](int i) { return (const float*)d_in[i]; };
  const float* x      = in(0);
  const float* adj    = in(1);
  const float* w_mlp1 = in(2);  const float* b_mlp1 = in(3);
  const float* w_mlp2 = in(4);  const float* b_mlp2 = in(5);
  const float* w_mlp3 = in(6);  const float* b_mlp3 = in(7);
  const float* w_mlp6 = in(8);  const float* b_mlp6 = in(9);
  const float* bn1_g = in(10);  const float* bn1_b = in(11);
  const float* bn2_g = in(12);  const float* bn2_b = in(13);
  const float* bn3_g = in(14);  const float* bn3_b = in(15);
  const float* p1_w = in(16);   const float* p1_b = in(17);
  const float* p2_w = in(18);   const float* p2_b = in(19);
  const float* p3_w = in(20);   const float* p3_b = in(21);
  const float* lin1_w = in(22); const float* lin1_b = in(23);
  const float* lin2_w = in(24); const float* lin2_b = in(25);
  const float* lin3_w = in(26); const float* lin3_b = in(27);
  const float* lin4_w = in(28); const float* lin4_b = in(29);
  const float* lin5_w = in(30); const float* lin5_b = in(31);
  const float* lin6_w = in(32); const float* lin6_b = in(33);

  float* out = (float*)d_out;
  float* out_probs = out;
  float* out_dec1  = out_probs + 256;            // 3 x 4992*39 contiguous
  float* out_gt1   = out_dec1 + 3 * 4992 * 39;
  float* out_pred1 = out_gt1 + 4096;
  float* out_gt2   = out_pred1 + 4096;
  float* out_pred2 = out_gt2 + 3328;
  float* out_gt3   = out_pred2 + 3328;
  float* out_pred3 = out_gt3 + 2688;

  char* base = (char*)d_ws;
  size_t off = 0;
  auto allocf = [&](size_t n) -> float* {
    float* p = (float*)(base + off);
    off += ((n * sizeof(float) + 255) & ~(size_t)255);
    return p;
  };
  auto alloci = [&](size_t n) -> int* {
    int* p = (int*)(base + off);
    off += ((n * sizeof(int) + 255) & ~(size_t)255);
    return p;
  };
  auto allocs = [&](size_t n) -> short* {
    short* p = (short*)(base + off);
    off += ((n * sizeof(short) + 255) & ~(size_t)255);
    return p;
  };

  const size_t S = (size_t)4992 * 256;
  const size_t AB_S = (size_t)4992 * 512;
  const int SI = 4992 * KNN_;

  short* wt1h = allocs(512 * 64); short* wt1m = allocs(512 * 64); short* wt1l = allocs(512 * 64);
  short* wt2h = allocs(512 * 256); short* wt2m = allocs(512 * 256); short* wt2l = allocs(512 * 256);
  short* wt3h = allocs(512 * 256); short* wt3m = allocs(512 * 256); short* wt3l = allocs(512 * 256);
  short* wt6h = allocs(78 * 256);  short* wt6m = allocs(78 * 256);
  short* l4h = allocs(256 * 256);  short* l4m = allocs(256 * 256);
  short* l5h = allocs(128 * 256);  short* l5m = allocs(128 * 256);
  short* xsph = allocs(4992 * 64); short* xspm = allocs(4992 * 64); short* xspl = allocs(4992 * 64);
  float* deg  = allocf(4992);
  float* xdeg = allocf(4992);
  float* ysg  = allocf(4992);
  int* idxb = alloci(3 * SI);
  float* AB3 = allocf(3 * AB_S);
  float* trunk_t1 = allocf(S);
  float* scsh = allocf(512);
  float* tantg = allocf(4096);
  int* locsg = alloci(4096);
  short* xph = allocs((size_t)4096 * 256); short* xpm = allocs((size_t)4096 * 256); short* xpl = allocs((size_t)4096 * 256);
  size_t ms0 = off;
  short* xoutb_h = allocs(3 * S);
  short* xoutb_m = allocs(3 * S);
  size_t msz = off - ms0;
  short* t1b_h = allocs(3 * S);
  short* t1b_m = allocs(3 * S);
  float* adj1 = allocf(128 * 32 * 32);
  float* adj2 = allocf(128 * 26 * 26);
  int* perm1 = alloci(4096); int* perm2 = alloci(3328); int* perm3 = alloci(2688);
  float* z  = allocf(128 * 512);
  float* z1 = allocf(128 * 256);
  float* z2 = allocf(128 * 128);
  float* logits = allocf(256);
  if (off > ws_size) return;

  // t2b aliases xoutb (dead after decoder stage 1)
  short* t2b_h = xoutb_h; short* t2b_m = xoutb_m;

  // ---- prep + zero scatter targets ----
  prep_kernel<<<dim3(1248, 8), 256, 0, stream>>>(
      w_mlp1, w_mlp2, w_mlp3, w_mlp6, lin4_w, lin5_w, x, adj,
      wt1h, wt1m, wt1l, wt2h, wt2m, wt2l, wt3h, wt3m, wt3l, wt6h, wt6m,
      l4h, l4m, l5h, l5m, xsph, xspm, xspl, deg);
  hipMemsetAsync(xoutb_h, 0, msz, stream);

  // ---- level 1 ----
  gram_knn_kernel<<<B_, 512, 0, stream>>>(xsph, xspm, xspl, 3, 64, N_, 64, idxb);
  {
    dim3 gg(4, 39);
    mfma_gemm_triple_kernel<<<gg, 256, 0, stream>>>(xsph, xspm, xspl, 64,
                                                    wt1h, wt1m, wt1l, AB3, 4992, 512);
  }
  edge_agg_kernel<<<cdiv(4992 * 256, 256), 256, 0, stream>>>(AB3, b_mlp1, idxb, N_, 256, 0, 4992, 4992,
                                                             trunk_t1, nullptr, nullptr, nullptr);
  bn_stats_kernel<<<H_, 256, 0, stream>>>(trunk_t1, 4992, bn1_g, bn1_b, scsh);
  bnrowdot_kernel<<<cdiv(4992 * 64, 256), 256, 0, stream>>>(trunk_t1, scsh, p1_w, 4992, ysg);
  sag_select_kernel<<<B_, 256, 0, stream>>>(ysg, adj, N_, K1_, p1_b,
                                            perm1, tantg, locsg, adj1,
                                            nullptr, nullptr, nullptr, nullptr);
  pool_scatter_kernel<<<cdiv(B_ * K1_ * H_, 256), 256, 0, stream>>>(
      trunk_t1, scsh, tantg, locsg, nullptr, N_, K1_, xph, xpm, xpl, xoutb_h, xoutb_m);
  readout_kernel<<<cdiv(B_ * H_, 256), 256, 0, stream>>>(xph, xpm, xpl, K1_, 0, z);
  {  // degree head from x_out1
    dim3 g4(2, 39, 1);
    mfma_gemm_split_kernel<<<g4, 256, 0, stream>>>(xoutb_h, xoutb_m, l4h, l4m, lin4_b,
                                                   trunk_t1, t1b_h, t1b_m, 4992, 256, 256, 1, 0, 0);
    dim3 g5(1, 39, 1);
    mfma_gemm_split_kernel<<<g5, 256, 0, stream>>>(t1b_h, t1b_m, l5h, l5m, lin5_b,
                                                   AB3, nullptr, nullptr, 4992, 128, 256, 1, 0, 0);
  }
  rowdot_kernel<<<cdiv(4992 * 64, 256), 256, 0, stream>>>(AB3, lin6_w, 4992, 128, lin6_b, 1, xdeg);
  gtpred_kernel<<<cdiv(4096, 256), 256, 0, stream>>>(deg, xdeg, perm1, 4096, out_gt1, out_pred1);

  // ---- level 2 ----
  gram_knn_kernel<<<B_, 512, 0, stream>>>(xph, xpm, xpl, 3, 256, K1_, 256, idxb);
  {
    dim3 gg(4, 32);
    mfma_gemm_triple_kernel<<<gg, 256, 0, stream>>>(xph, xpm, xpl, 256,
                                                    wt2h, wt2m, wt2l, AB3, 4096, 512);
  }
  edge_agg_kernel<<<cdiv(4096 * 256, 256), 256, 0, stream>>>(AB3, b_mlp2, idxb, K1_, 256, 0, 4096, 4096,
                                                             trunk_t1, nullptr, nullptr, nullptr);
  bn_stats_kernel<<<H_, 256, 0, stream>>>(trunk_t1, 4096, bn2_g, bn2_b, scsh);
  bnrowdot_kernel<<<cdiv(4096 * 64, 256), 256, 0, stream>>>(trunk_t1, scsh, p2_w, 4096, ysg);
  sag_select_kernel<<<B_, 256, 0, stream>>>(ysg, adj1, K1_, K2_, p2_b,
                                            perm2, tantg, locsg, adj2,
                                            deg, xdeg, out_gt2, out_pred2);
  pool_scatter_kernel<<<cdiv(B_ * K2_ * H_, 256), 256, 0, stream>>>(
      trunk_t1, scsh, tantg, locsg, perm1, K1_, K2_, xph, xpm, xpl, xoutb_h + S, xoutb_m + S);
  readout_kernel<<<cdiv(B_ * H_, 256), 256, 0, stream>>>(xph, xpm, xpl, K2_, 1, z);

  // ---- level 3 ----
  gram_knn_kernel<<<B_, 512, 0, stream>>>(xph, xpm, xpl, 3, 256, K2_, 256, idxb);
  {
    dim3 gg(4, 26);
    mfma_gemm_triple_kernel<<<gg, 256, 0, stream>>>(xph, xpm, xpl, 256,
                                                    wt3h, wt3m, wt3l, AB3, 3328, 512);
  }
  edge_agg_kernel<<<cdiv(3328 * 256, 256), 256, 0, stream>>>(AB3, b_mlp3, idxb, K2_, 256, 0, 3328, 3328,
                                                             trunk_t1, nullptr, nullptr, nullptr);
  bn_stats_kernel<<<H_, 256, 0, stream>>>(trunk_t1, 3328, bn3_g, bn3_b, scsh);
  bnrowdot_kernel<<<cdiv(3328 * 64, 256), 256, 0, stream>>>(trunk_t1, scsh, p3_w, 3328, ysg);
  sag_select_kernel<<<B_, 256, 0, stream>>>(ysg, adj2, K2_, K3_, p3_b,
                                            perm3, tantg, locsg, nullptr,
                                            deg, xdeg, out_gt3, out_pred3);
  pool_scatter_kernel<<<cdiv(B_ * K3_ * H_, 256), 256, 0, stream>>>(
      trunk_t1, scsh, tantg, locsg, perm2, K2_, K3_, xph, xpm, xpl, xoutb_h + 2 * S, xoutb_m + 2 * S);
  readout_kernel<<<cdiv(B_ * H_, 256), 256, 0, stream>>>(xph, xpm, xpl, K3_, 1, z);

  // ---- classifier head ----
  rowgemm_kernel<<<128, 256, 0, stream>>>(z, lin1_w, lin1_b, z1, 256, 512, 1);
  rowgemm_kernel<<<128, 256, 0, stream>>>(z1, lin2_w, lin2_b, z2, 128, 256, 1);
  wavedot_gemm_kernel<<<cdiv(128 * 2 * 64, 256), 256, 0, stream>>>(z2, lin3_w, lin3_b, logits, 128, 2, 128, 0);
  softmax2_kernel<<<1, 128, 0, stream>>>(logits, out_probs);

  // ---- batched decoders (3 independent, share weights; z-batched gemm, 384-graph knn) ----
  // stage 1: wcat3, tanh
  gram_knn_kernel<<<3 * B_, 512, 0, stream>>>(xoutb_h, xoutb_m, nullptr, 2, 256, N_, 256, idxb);
  {
    dim3 gg(4, 39, 3);
    mfma_gemm_split_kernel<<<gg, 256, 0, stream>>>(xoutb_h, xoutb_m, wt3h, wt3m, nullptr,
                                                   AB3, nullptr, nullptr, 4992, 512, 256, 0, S, AB_S);
  }
  edge_agg_kernel<<<cdiv(3 * 4992 * 256, 256), 256, 0, stream>>>(
      AB3, b_mlp3, idxb, N_, 256, 2, 3 * 4992, 4992, nullptr, t1b_h, t1b_m, nullptr);
  // stage 2: wcat2, tanh
  gram_knn_kernel<<<3 * B_, 512, 0, stream>>>(t1b_h, t1b_m, nullptr, 2, 256, N_, 256, idxb);
  {
    dim3 gg(4, 39, 3);
    mfma_gemm_split_kernel<<<gg, 256, 0, stream>>>(t1b_h, t1b_m, wt2h, wt2m, nullptr,
                                                   AB3, nullptr, nullptr, 4992, 512, 256, 0, S, AB_S);
  }
  edge_agg_kernel<<<cdiv(3 * 4992 * 256, 256), 256, 0, stream>>>(
      AB3, b_mlp2, idxb, N_, 256, 2, 3 * 4992, 4992, nullptr, t2b_h, t2b_m, nullptr);
  // stage 3: wcat6, linear -> out_dec
  gram_knn_kernel<<<3 * B_, 512, 0, stream>>>(t2b_h, t2b_m, nullptr, 2, 256, N_, 256, idxb);
  {
    dim3 gg(1, 39, 3);
    mfma_gemm_split_kernel<<<gg, 256, 0, stream>>>(t2b_h, t2b_m, wt6h, wt6m, nullptr,
                                                   AB3, nullptr, nullptr, 4992, 78, 256, 0, S, (size_t)4992 * 78);
  }
  edge_agg_kernel<<<cdiv(3 * 4992 * 39, 256), 256, 0, stream>>>(
      AB3, b_mlp6, idxb, N_, 39, 0, 3 * 4992, 4992, out_dec1, nullptr, nullptr, nullptr);
}

// Round 16
// 563.301 us; speedup vs baseline: 2.4016x; 1.1730x over previous
//
#include <hip/hip_runtime.h>
#include <cmath>

#define B_   128
#define N_   39
#define KNN_ 10
#define H_   256
#define K1_  32
#define K2_  26
#define K3_  21

static inline int cdiv(int a, int b) { return (a + b - 1) / b; }

typedef __attribute__((ext_vector_type(8))) short short8;
typedef __attribute__((ext_vector_type(4))) short short4v;
typedef __attribute__((ext_vector_type(4))) float floatx4;

__device__ inline short f2b(float f) {   // fp32 -> bf16 RNE
  unsigned u = __float_as_uint(f);
  u += 0x7fff + ((u >> 16) & 1);
  return (short)(u >> 16);
}
__device__ inline float b2f(short h) {
  return __uint_as_float(((unsigned)(unsigned short)h) << 16);
}
__device__ inline void f2b3(float v, short& h, short& m, short& l) {  // v ~= h+m+l (24 bits)
  h = f2b(v);
  float r1 = v - b2f(h);
  m = f2b(r1);
  l = f2b(r1 - b2f(m));
}

// ------------- one-shot prep: weights triple-split transposed + x split + degree -------------
__global__ void prep_kernel(
    const float* __restrict__ w1, const float* __restrict__ w2,
    const float* __restrict__ w3, const float* __restrict__ w6,
    const float* __restrict__ l4, const float* __restrict__ l5,
    const float* __restrict__ x, const float* __restrict__ adj,
    short* __restrict__ wt1h, short* __restrict__ wt1m, short* __restrict__ wt1l,
    short* __restrict__ wt2h, short* __restrict__ wt2m, short* __restrict__ wt2l,
    short* __restrict__ wt3h, short* __restrict__ wt3m, short* __restrict__ wt3l,
    short* __restrict__ wt6h, short* __restrict__ wt6m,
    short* __restrict__ l4h, short* __restrict__ l4m,
    short* __restrict__ l5h, short* __restrict__ l5m,
    short* __restrict__ xsph, short* __restrict__ xspm, short* __restrict__ xspl,
    float* __restrict__ deg) {
  int task = blockIdx.y;
  int t = blockIdx.x * 256 + threadIdx.x;
  if (task == 0) {            // wcat1 tripleT: [512][64], K=39 padded
    if (t >= 512 * 64) return;
    int nn = t >> 6, k = t & 63;
    float v = 0.f;
    if (k < 39) v = (nn < 256) ? w1[k * 256 + nn] - w1[(39 + k) * 256 + nn]
                               : w1[(39 + k) * 256 + (nn - 256)];
    short h, m, l; f2b3(v, h, m, l);
    wt1h[t] = h; wt1m[t] = m; wt1l[t] = l;
  } else if (task == 1) {     // wcat2 tripleT: [512][256]
    if (t >= 512 * 256) return;
    int nn = t >> 8, k = t & 255;
    float v = (nn < 256) ? w2[k * 256 + nn] - w2[(256 + k) * 256 + nn]
                         : w2[(256 + k) * 256 + (nn - 256)];
    short h, m, l; f2b3(v, h, m, l);
    wt2h[t] = h; wt2m[t] = m; wt2l[t] = l;
  } else if (task == 2) {     // wcat3 tripleT
    if (t >= 512 * 256) return;
    int nn = t >> 8, k = t & 255;
    float v = (nn < 256) ? w3[k * 256 + nn] - w3[(256 + k) * 256 + nn]
                         : w3[(256 + k) * 256 + (nn - 256)];
    short h, m, l; f2b3(v, h, m, l);
    wt3h[t] = h; wt3m[t] = m; wt3l[t] = l;
  } else if (task == 3) {     // wcat6 T (h,m): [78][256]
    if (t >= 78 * 256) return;
    int nn = t >> 8, k = t & 255;
    float v = (nn < 39) ? w6[k * 39 + nn] - w6[(256 + k) * 39 + nn]
                        : w6[(256 + k) * 39 + (nn - 39)];
    short h, m, l; f2b3(v, h, m, l);
    wt6h[t] = h; wt6m[t] = m;
  } else if (task == 4) {     // lin4 T (h,m): [256][256]
    if (t >= 256 * 256) return;
    int nn = t >> 8, k = t & 255;
    short h, m, l; f2b3(l4[k * 256 + nn], h, m, l);
    l4h[t] = h; l4m[t] = m;
  } else if (task == 5) {     // lin5 T (h,m): [128][256]
    if (t >= 128 * 256) return;
    int nn = t >> 8, k = t & 255;
    short h, m, l; f2b3(l5[k * 128 + nn], h, m, l);
    l5h[t] = h; l5m[t] = m;
  } else if (task == 6) {     // x split: [4992][64], F=39 padded
    if (t >= 4992 * 64) return;
    int r = t >> 6, k = t & 63;
    float v = (k < 39) ? x[r * 39 + k] : 0.f;
    short h, m, l; f2b3(v, h, m, l);
    xsph[t] = h; xspm[t] = m; xspl[t] = l;
  } else {                    // degree
    if (t >= B_ * N_) return;
    const float* row = adj + (size_t)t * N_;
    float s = 0.f;
    for (int j = 0; j < N_; ++j) s += row[j];
    deg[t] = s;
  }
}

// ======== fused KNN + GEMM (one dispatch; block role by blockIdx.x) ========
// knn: blocks [0, knnB): MFMA gram + rank-parallel KNN (per graph).
// gemm: blocks [knnB, ...): C = A·W^T, M%128==0; store guard on N. Both 512 thr.
// nterms selects 2-term (~2^-16) or 3-term (~2^-24) split; MFMA order fixed.
__global__ __launch_bounds__(512) void knn_gemm_kernel(
    const short* __restrict__ kxh, const short* __restrict__ kxm, const short* __restrict__ kxl,
    int knt, int kKs, int kn, int kF32, int* __restrict__ idx, int knnB,
    const short* __restrict__ Ah, const short* __restrict__ Am, const short* __restrict__ Al,
    int gnt, int gK,
    const short* __restrict__ Wh, const short* __restrict__ Wm, const short* __restrict__ Wl,
    float* __restrict__ C0, int gM, int gN, int gyB,
    size_t Astride, size_t Cstride) {
  extern __shared__ char smem[];
  int tid = threadIdx.x;
  int wave = tid >> 6, lane = tid & 63;
  int lm = lane & 15, lk = (lane >> 4) * 8;
  if ((int)blockIdx.x < knnB) {
    // ---------------- KNN path ----------------
    short* sh_h = (short*)smem;
    short* sh_m = sh_h + 48 * 40;
    short* sh_l = sh_m + 48 * 40;
    float* Gs   = (float*)(sh_l + 48 * 40);    // [48][49]
    float* diag = Gs + 48 * 49;
    int b = blockIdx.x;
    int nt = (kn + 15) >> 4;
    int tasks = nt * nt;
    floatx4 acc[2] = {};
    int stage_elems = 384 * knt;
    for (int k0 = 0; k0 < kF32; k0 += 32) {
      for (int e = tid; e < stage_elems; e += 512) {
        int a = e / 384, rem = e - a * 384;
        int r = rem >> 3, c4 = (rem & 7) * 4;
        const short* src = (a == 0) ? kxh : (a == 1) ? kxm : kxl;
        short* dst = (a == 0) ? sh_h : (a == 1) ? sh_m : sh_l;
        *(short4v*)&dst[r * 40 + c4] =
            *(const short4v*)&src[((size_t)(b * kn + r)) * kKs + k0 + c4];
      }
      __syncthreads();
#pragma unroll
      for (int ai = 0; ai < 2; ++ai) {
        int t = wave + ai * 8;
        if (t < tasks) {
          int ti = t / nt, tj = t - ti * nt;
          int ra = (ti * 16 + lm) * 40 + lk;
          int rb = (tj * 16 + lm) * 40 + lk;
          short8 ah = *(const short8*)&sh_h[ra];
          short8 am = *(const short8*)&sh_m[ra];
          short8 bh = *(const short8*)&sh_h[rb];
          short8 bm = *(const short8*)&sh_m[rb];
          floatx4 a = acc[ai];
          a = __builtin_amdgcn_mfma_f32_16x16x32_bf16(ah, bh, a, 0, 0, 0);
          a = __builtin_amdgcn_mfma_f32_16x16x32_bf16(ah, bm, a, 0, 0, 0);
          a = __builtin_amdgcn_mfma_f32_16x16x32_bf16(am, bh, a, 0, 0, 0);
          if (knt == 3) {
            short8 al = *(const short8*)&sh_l[ra];
            short8 bl = *(const short8*)&sh_l[rb];
            a = __builtin_amdgcn_mfma_f32_16x16x32_bf16(ah, bl, a, 0, 0, 0);
            a = __builtin_amdgcn_mfma_f32_16x16x32_bf16(al, bh, a, 0, 0, 0);
            a = __builtin_amdgcn_mfma_f32_16x16x32_bf16(am, bm, a, 0, 0, 0);
          }
          acc[ai] = a;
        }
      }
      __syncthreads();
    }
#pragma unroll
    for (int ai = 0; ai < 2; ++ai) {
      int t = wave + ai * 8;
      if (t < tasks) {
        int ti = t / nt, tj = t - ti * nt;
        int col = tj * 16 + lm;
        int rbase = ti * 16 + (lane >> 4) * 4;
#pragma unroll
        for (int r = 0; r < 4; ++r) Gs[(rbase + r) * 49 + col] = acc[ai][r];
      }
    }
    __syncthreads();
    if (tid < 48) diag[tid] = (tid < kn) ? Gs[tid * 49 + tid] : INFINITY;
    __syncthreads();
    for (int row = wave; row < kn; row += 8) {
      float gii = diag[row];
      float dj = (lane < kn) ? (gii + diag[lane] - 2.f * Gs[row * 49 + lane]) : INFINITY;
      int rank = 0;
      for (int j = 0; j < kn; ++j) {
        float djp = gii + diag[j] - 2.f * Gs[row * 49 + j];
        rank += (djp < dj || (djp == dj && j < lane)) ? 1 : 0;
      }
      if (lane < kn && rank < KNN_)
        idx[(size_t)(b * kn + row) * KNN_ + rank] = lane;
    }
  } else {
    // ---------------- GEMM path (8 waves: 2 row-groups x 4 col-groups) ----------------
    short* Ash = (short*)smem;
    short* Asm = Ash + 128 * 40;
    short* Asl = Asm + 128 * 40;
    short* Bsh = Asl + ((gnt == 3) ? 128 * 40 : -128 * 40);   // 2-term: B starts after Asm
    // simpler: recompute
    Bsh = (short*)smem + gnt * 128 * 40;
    short* Bsm = Bsh + 128 * 40;
    short* Bsl = Bsm + 128 * 40;
    int gb = blockIdx.x - knnB;
    int gxB = (gN + 127) >> 7;
    int gx = gb % gxB;
    int rest = gb / gxB;
    int gy = rest % gyB;
    int gz = rest / gyB;
    const short* A_h = Ah + (size_t)gz * Astride;
    const short* A_m = Am ? Am + (size_t)gz * Astride : nullptr;
    const short* A_l = Al ? Al + (size_t)gz * Astride : nullptr;
    float* C = C0 + (size_t)gz * Cstride;
    int row0 = gy * 128, col0 = gx * 128;
    int wm = wave & 1, wn = wave >> 1;
    floatx4 acc[4][2] = {};
    for (int k0 = 0; k0 < gK; k0 += 32) {
      for (int e = tid; e < gnt * 512; e += 512) {
        int a = e >> 9, rem = e & 511;
        int r = rem >> 2, kc = (rem & 3) * 8;
        const short* src = (a == 0) ? A_h : (a == 1) ? A_m : A_l;
        short* dst = (a == 0) ? Ash : (a == 1) ? Asm : Asl;
        *(short8*)&dst[r * 40 + kc] = *(const short8*)&src[((size_t)(row0 + r)) * gK + k0 + kc];
      }
      for (int e = tid; e < gnt * 512; e += 512) {
        int a = e >> 9, rem = e & 511;
        int r = rem >> 2, kc = (rem & 3) * 8;
        const short* src = (a == 0) ? Wh : (a == 1) ? Wm : Wl;
        short* dst = (a == 0) ? Bsh : (a == 1) ? Bsm : Bsl;
        *(short8*)&dst[r * 40 + kc] = *(const short8*)&src[((size_t)(col0 + r)) * gK + k0 + kc];
      }
      __syncthreads();
      short8 afh[4], afm[4], afl[4];
#pragma unroll
      for (int mi = 0; mi < 4; ++mi) {
        int ro = (wm * 64 + mi * 16 + lm) * 40 + lk;
        afh[mi] = *(const short8*)&Ash[ro];
        if (gnt == 3) {
          afm[mi] = *(const short8*)&Asm[ro];
          afl[mi] = *(const short8*)&Asl[ro];
        } else {
          afm[mi] = *(const short8*)&Asm[ro];   // 2-term: m is "low"
        }
      }
#pragma unroll
      for (int ni = 0; ni < 2; ++ni) {
        int ro = (wn * 32 + ni * 16 + lm) * 40 + lk;
        short8 bfh = *(const short8*)&Bsh[ro];
        short8 bfm = *(const short8*)&Bsm[ro];
#pragma unroll
        for (int mi = 0; mi < 4; ++mi) {
          floatx4 a = acc[mi][ni];
          a = __builtin_amdgcn_mfma_f32_16x16x32_bf16(afh[mi], bfh, a, 0, 0, 0);
          a = __builtin_amdgcn_mfma_f32_16x16x32_bf16(afh[mi], bfm, a, 0, 0, 0);
          a = __builtin_amdgcn_mfma_f32_16x16x32_bf16(afm[mi], bfh, a, 0, 0, 0);
          if (gnt == 3) {
            short8 bfl = *(const short8*)&Bsl[ro];
            a = __builtin_amdgcn_mfma_f32_16x16x32_bf16(afh[mi], bfl, a, 0, 0, 0);
            a = __builtin_amdgcn_mfma_f32_16x16x32_bf16(afl[mi], bfh, a, 0, 0, 0);
            a = __builtin_amdgcn_mfma_f32_16x16x32_bf16(afm[mi], bfm, a, 0, 0, 0);
          }
          acc[mi][ni] = a;
        }
      }
      __syncthreads();
    }
    int lr = (lane >> 4) * 4;
#pragma unroll
    for (int mi = 0; mi < 4; ++mi)
#pragma unroll
      for (int ni = 0; ni < 2; ++ni) {
        int colg = col0 + wn * 32 + ni * 16 + lm;
        if (colg >= gN) continue;
#pragma unroll
        for (int r = 0; r < 4; ++r) {
          int rowg = row0 + wm * 64 + mi * 16 + lr + r;
          C[(size_t)rowg * gN + colg] = acc[mi][ni][r];
        }
      }
  }
}

// ------------- 2-term split MFMA GEMM w/ bias+relu+split-out (degree head) -------------
__global__ __launch_bounds__(256) void mfma_gemm_split_kernel(
    const short* __restrict__ Ah, const short* __restrict__ Al,
    const short* __restrict__ Wth, const short* __restrict__ Wtl,
    const float* __restrict__ bias,
    float* __restrict__ C, short* __restrict__ Ch, short* __restrict__ Cl,
    int M, int N, int K, int act) {
  __shared__ short Ash[128 * 40];
  __shared__ short Asl[128 * 40];
  __shared__ short Bsh[128 * 40];
  __shared__ short Bsl[128 * 40];
  int tid = threadIdx.x;
  int wave = tid >> 6, lane = tid & 63;
  int wm = wave & 1, wn = wave >> 1;
  int row0 = blockIdx.y * 128, col0 = blockIdx.x * 128;
  floatx4 acc[4][4] = {};
  int lm = lane & 15, lk = (lane >> 4) * 8;
  for (int k0 = 0; k0 < K; k0 += 32) {
    for (int c = tid; c < 512; c += 256) {
      int r = c >> 2, kc = (c & 3) * 8;
      int grow = row0 + r;
      short8 vh = {}, vl = {};
      if (grow < M) {
        vh = *(const short8*)&Ah[(size_t)grow * K + k0 + kc];
        vl = *(const short8*)&Al[(size_t)grow * K + k0 + kc];
      }
      *(short8*)&Ash[r * 40 + kc] = vh;
      *(short8*)&Asl[r * 40 + kc] = vl;
    }
    for (int c = tid; c < 512; c += 256) {
      int r = c >> 2, kc = (c & 3) * 8;
      int gn = col0 + r;
      short8 vh = {}, vl = {};
      if (gn < N) {
        vh = *(const short8*)&Wth[(size_t)gn * K + k0 + kc];
        vl = *(const short8*)&Wtl[(size_t)gn * K + k0 + kc];
      }
      *(short8*)&Bsh[r * 40 + kc] = vh;
      *(short8*)&Bsl[r * 40 + kc] = vl;
    }
    __syncthreads();
    short8 afh[4], afl[4], bfh[4], bfl[4];
#pragma unroll
    for (int mi = 0; mi < 4; ++mi) {
      int ro = (wm * 64 + mi * 16 + lm) * 40 + lk;
      afh[mi] = *(const short8*)&Ash[ro];
      afl[mi] = *(const short8*)&Asl[ro];
    }
#pragma unroll
    for (int ni = 0; ni < 4; ++ni) {
      int ro = (wn * 64 + ni * 16 + lm) * 40 + lk;
      bfh[ni] = *(const short8*)&Bsh[ro];
      bfl[ni] = *(const short8*)&Bsl[ro];
    }
#pragma unroll
    for (int mi = 0; mi < 4; ++mi)
#pragma unroll
      for (int ni = 0; ni < 4; ++ni) {
        acc[mi][ni] = __builtin_amdgcn_mfma_f32_16x16x32_bf16(afh[mi], bfh[ni], acc[mi][ni], 0, 0, 0);
        acc[mi][ni] = __builtin_amdgcn_mfma_f32_16x16x32_bf16(afh[mi], bfl[ni], acc[mi][ni], 0, 0, 0);
        acc[mi][ni] = __builtin_amdgcn_mfma_f32_16x16x32_bf16(afl[mi], bfh[ni], acc[mi][ni], 0, 0, 0);
      }
    __syncthreads();
  }
  int lr = (lane >> 4) * 4;
#pragma unroll
  for (int mi = 0; mi < 4; ++mi)
#pragma unroll
    for (int ni = 0; ni < 4; ++ni) {
      int colg = col0 + wn * 64 + ni * 16 + lm;
      if (colg >= N) continue;
      float bv = bias ? bias[colg] : 0.f;
#pragma unroll
      for (int r = 0; r < 4; ++r) {
        int rowg = row0 + wm * 64 + mi * 16 + lr + r;
        if (rowg >= M) continue;
        float v = acc[mi][ni][r] + bv;
        if (act == 1) v = fmaxf(v, 0.f);
        C[(size_t)rowg * N + colg] = v;
        if (Ch) {
          short hi = f2b(v);
          short lo = f2b(v - b2f(hi));
          Ch[(size_t)rowg * N + colg] = hi;
          Cl[(size_t)rowg * N + colg] = lo;
        }
      }
    }
}

// Thin GEMM (small M): one block per row.
__global__ __launch_bounds__(256) void rowgemm_kernel(
    const float* __restrict__ A, const float* __restrict__ W, const float* __restrict__ bias,
    float* __restrict__ C, int N, int K, int act) {
  __shared__ float a[512];
  int row = blockIdx.x;
  for (int k = threadIdx.x; k < K; k += 256) a[k] = A[(size_t)row * K + k];
  __syncthreads();
  for (int c = threadIdx.x; c < N; c += 256) {
    float s = 0.f;
    for (int k = 0; k < K; k += 4) {
      float4 av = *(const float4*)&a[k];
      s += av.x * W[(size_t)k * N + c];
      s += av.y * W[(size_t)(k + 1) * N + c];
      s += av.z * W[(size_t)(k + 2) * N + c];
      s += av.w * W[(size_t)(k + 3) * N + c];
    }
    float v = s + (bias ? bias[c] : 0.f);
    if (act == 1) v = fmaxf(v, 0.f);
    C[(size_t)row * N + c] = v;
  }
}

// one wave per output element (for very small M*N)
__global__ void wavedot_gemm_kernel(const float* __restrict__ A, const float* __restrict__ W,
                                    const float* __restrict__ bias, float* __restrict__ C,
                                    int M, int N, int K, int act) {
  int wid = (blockIdx.x * blockDim.x + threadIdx.x) >> 6;
  int lane = threadIdx.x & 63;
  if (wid >= M * N) return;
  int row = wid / N, col = wid - row * N;
  const float* ar = A + (size_t)row * K;
  float s = 0.f;
  for (int k = lane; k < K; k += 64) s += ar[k] * W[(size_t)k * N + col];
  for (int off = 32; off; off >>= 1) s += __shfl_down(s, off, 64);
  if (lane == 0) {
    float v = s + (bias ? bias[col] : 0.f);
    if (act == 1) v = fmaxf(v, 0.f);
    C[(size_t)row * N + col] = v;
  }
}

// edge agg over global rows (batched decoders: d = r / per); AB is (rows x 2Hc)
__global__ void edge_agg_kernel(const float* __restrict__ AB, const float* __restrict__ bias,
                                const int* __restrict__ idx, int n, int Hc, int act,
                                int rows, int per,
                                float* __restrict__ out,
                                short* __restrict__ outh, short* __restrict__ outm,
                                short* __restrict__ outl) {
  int t = blockIdx.x * blockDim.x + threadIdx.x;
  if (t >= rows * Hc) return;
  int r = t / Hc, h = t - r * Hc;
  int d = r / per, rloc = r - d * per;
  int b = rloc / n;
  int s2 = 2 * Hc;
  float av = AB[(size_t)r * s2 + h] + bias[h];
  const int* ir = idx + ((size_t)d * per + rloc) * KNN_;
  int base = d * per + b * n;
  float m = -INFINITY;
  for (int k = 0; k < KNN_; ++k) {
    float v = av + AB[(size_t)(base + ir[k]) * s2 + Hc + h];
    v = fmaxf(v, 0.f);
    m = fmaxf(m, v);
  }
  if (act == 2) m = tanhf(m);
  if (out) out[t] = m;
  if (outh) {
    short hh, mm, ll;
    f2b3(m, hh, mm, ll);
    outh[t] = hh; outm[t] = mm;
    if (outl) outl[t] = ll;
  }
}

// BN stats -> per-column scale/shift: norm(v) = relu(v*sc + sh)
__global__ void bn_stats_kernel(const float* __restrict__ xx, int M,
                                const float* __restrict__ g, const float* __restrict__ bb,
                                float* __restrict__ scsh) {
  int c = blockIdx.x;
  double s = 0.0, s2 = 0.0;
  for (int r = threadIdx.x; r < M; r += 256) {
    double v = (double)xx[(size_t)r * H_ + c];
    s += v; s2 += v * v;
  }
  __shared__ double sh[256], sh2[256];
  sh[threadIdx.x] = s; sh2[threadIdx.x] = s2;
  __syncthreads();
  for (int o = 128; o; o >>= 1) {
    if (threadIdx.x < o) { sh[threadIdx.x] += sh[threadIdx.x + o]; sh2[threadIdx.x] += sh2[threadIdx.x + o]; }
    __syncthreads();
  }
  if (threadIdx.x == 0) {
    double mean = sh[0] / M;
    double var = sh2[0] / M - mean * mean;
    float rstd = 1.f / sqrtf((float)var + 1e-5f);
    float sc = rstd * g[c];
    scsh[c] = sc;
    scsh[H_ + c] = bb[c] - (float)mean * sc;
  }
}

// BN-fused rowdot (wave per row): ys[r] = sum_k relu(t1*sc+sh) * pw
__global__ void bnrowdot_kernel(const float* __restrict__ t1, const float* __restrict__ scsh,
                                const float* __restrict__ pw, int M, float* __restrict__ ys) {
  int wid = (blockIdx.x * blockDim.x + threadIdx.x) >> 6;
  int lane = threadIdx.x & 63;
  if (wid >= M) return;
  const float* xr = t1 + (size_t)wid * H_;
  float s = 0.f;
  for (int k = lane; k < H_; k += 64) {
    float v = fmaxf(xr[k] * scsh[k] + scsh[H_ + k], 0.f);
    s += v * pw[k];
  }
  for (int off = 32; off; off >>= 1) s += __shfl_down(s, off, 64);
  if (lane == 0) ys[wid] = s;
}

// one wave per row: y[r] = dot(x[r,:K], w) [+bias] [relu]
__global__ void rowdot_kernel(const float* __restrict__ x, const float* __restrict__ w,
                              int M, int K, const float* __restrict__ bias, int act,
                              float* __restrict__ y) {
  int wid = (blockIdx.x * blockDim.x + threadIdx.x) >> 6;
  int lane = threadIdx.x & 63;
  if (wid >= M) return;
  const float* xr = x + (size_t)wid * K;
  float s = 0.f;
  for (int k = lane; k < K; k += 64) s += xr[k] * w[k];
  for (int off = 32; off; off >>= 1) s += __shfl_down(s, off, 64);
  if (lane == 0) {
    float v = s + (bias ? bias[0] : 0.f);
    if (act == 1) v = fmaxf(v, 0.f);
    y[wid] = v;
  }
}

// -------- sag select: gcn + rank-parallel topk --------
__global__ __launch_bounds__(256) void sag_select_kernel(
    const float* __restrict__ ysg,
    const float* __restrict__ adj_in, int n, int k,
    const float* __restrict__ pb,
    int* __restrict__ perm, float* __restrict__ tantg, int* __restrict__ locsg,
    float* __restrict__ adjp,
    const float* __restrict__ deg, const float* __restrict__ xdeg,
    float* __restrict__ gt, float* __restrict__ pred) {
  __shared__ float ys[40], dinv[40], scs[40];
  __shared__ int locs[40];
  int b = blockIdx.x;
  int i = threadIdx.x;
  if (i < n) {
    ys[i] = ysg[b * n + i];
    const float* ar = adj_in + ((size_t)b * n + i) * n;
    float sum = 1.f;
    for (int j = 0; j < n; ++j) sum += ar[j];
    dinv[i] = 1.f / sqrtf(sum);
  }
  __syncthreads();
  if (i < n) {
    const float* ar = adj_in + ((size_t)b * n + i) * n;
    float acc = 0.f;
    for (int j = 0; j < n; ++j) {
      float a = ar[j] + (i == j ? 1.f : 0.f);
      acc += a * dinv[j] * ys[j];
    }
    scs[i] = dinv[i] * acc + pb[0];
  }
  __syncthreads();
  if (i < n) {   // rank-based stable descending top-k (ties -> lowest index)
    float si = scs[i];
    int rank = 0;
    for (int j = 0; j < n; ++j) {
      float sj = scs[j];
      rank += (sj > si || (sj == si && j < i)) ? 1 : 0;
    }
    if (rank < k) {
      tantg[b * k + rank] = tanhf(si);
      locsg[b * k + rank] = i;
      locs[rank] = i;
      perm[b * k + rank] = b * n + i;
    }
  }
  __syncthreads();
  if (adjp) {
    for (int e = threadIdx.x; e < k * k; e += 256) {
      int t1i = e / k, t2i = e - t1i * k;
      adjp[(size_t)b * k * k + e] = adj_in[((size_t)b * n + locs[t1i]) * n + locs[t2i]];
    }
  }
  if (gt && threadIdx.x < k) {
    int p = b * n + locs[threadIdx.x];
    gt[b * k + threadIdx.x] = deg[p];
    pred[b * k + threadIdx.x] = xdeg[p];
  }
}

// -------- pool scatter: per-element gather+BN+tanh-scale -> xp triple + xout (h,m) --------
__global__ void pool_scatter_kernel(
    const float* __restrict__ t1, const float* __restrict__ scsh,
    const float* __restrict__ tantg, const int* __restrict__ locsg,
    const int* __restrict__ remap, int n, int k,
    short* __restrict__ xph, short* __restrict__ xpm, short* __restrict__ xpl,
    short* __restrict__ soh, short* __restrict__ som) {
  int t = blockIdx.x * blockDim.x + threadIdx.x;
  if (t >= B_ * k * H_) return;
  int r = t >> 8, hc = t & 255;
  int b = r / k, rr = r - b * k;
  int own = b * n + locsg[b * k + rr];
  float v = fmaxf(t1[(size_t)own * H_ + hc] * scsh[hc] + scsh[H_ + hc], 0.f) * tantg[b * k + rr];
  short hh, mm, ll;
  f2b3(v, hh, mm, ll);
  xph[t] = hh; xpm[t] = mm; xpl[t] = ll;
  int tgt = remap ? remap[own] : own;
  size_t so = (size_t)tgt * H_ + hc;
  soh[so] = hh; som[so] = mm;
}

// -------- readout: z[b] = [max_r xp, mean_r xp] from triple --------
__global__ void readout_kernel(const short* __restrict__ xph, const short* __restrict__ xpm,
                               const short* __restrict__ xpl, int k, int accum,
                               float* __restrict__ z) {
  int t = blockIdx.x * blockDim.x + threadIdx.x;
  if (t >= B_ * H_) return;
  int b = t >> 8, hc = t & 255;
  float mx = -INFINITY, sm = 0.f;
  for (int r = 0; r < k; ++r) {
    size_t o = ((size_t)(b * k + r)) * H_ + hc;
    float v = b2f(xph[o]) + b2f(xpm[o]) + b2f(xpl[o]);
    mx = fmaxf(mx, v);
    sm += v;
  }
  float* zb = z + (size_t)b * 2 * H_;
  float mean = sm / (float)k;
  if (accum) { zb[hc] += mx; zb[H_ + hc] += mean; }
  else       { zb[hc] = mx;  zb[H_ + hc] = mean; }
}

__global__ void gtpred_kernel(const float* __restrict__ deg, const float* __restrict__ xdeg,
                              const int* __restrict__ perm, int M,
                              float* __restrict__ gt, float* __restrict__ pred) {
  int t = blockIdx.x * blockDim.x + threadIdx.x;
  if (t >= M) return;
  int p = perm[t];
  gt[t] = deg[p];
  pred[t] = xdeg[p];
}

__global__ void softmax2_kernel(const float* __restrict__ logits, float* __restrict__ probs) {
  int b = blockIdx.x * blockDim.x + threadIdx.x;
  if (b >= B_) return;
  float a = logits[2 * b], c = logits[2 * b + 1];
  float m = fmaxf(a, c);
  float ea = expf(a - m), ec = expf(c - m);
  float inv = 1.f / (ea + ec);
  probs[2 * b] = ea * inv;
  probs[2 * b + 1] = ec * inv;
}

extern "C" void kernel_launch(void* const* d_in, const int* in_sizes, int n_in,
                              void* d_out, int out_size, void* d_ws, size_t ws_size,
                              hipStream_t stream) {
  auto in = [&](int i) { return (const float*)d_in[i]; };
  const float* x      = in(0);
  const float* adj    = in(1);
  const float* w_mlp1 = in(2);  const float* b_mlp1 = in(3);
  const float* w_mlp2 = in(4);  const float* b_mlp2 = in(5);
  const float* w_mlp3 = in(6);  const float* b_mlp3 = in(7);
  const float* w_mlp6 = in(8);  const float* b_mlp6 = in(9);
  const float* bn1_g = in(10);  const float* bn1_b = in(11);
  const float* bn2_g = in(12);  const float* bn2_b = in(13);
  const float* bn3_g = in(14);  const float* bn3_b = in(15);
  const float* p1_w = in(16);   const float* p1_b = in(17);
  const float* p2_w = in(18);   const float* p2_b = in(19);
  const float* p3_w = in(20);   const float* p3_b = in(21);
  const float* lin1_w = in(22); const float* lin1_b = in(23);
  const float* lin2_w = in(24); const float* lin2_b = in(25);
  const float* lin3_w = in(26); const float* lin3_b = in(27);
  const float* lin4_w = in(28); const float* lin4_b = in(29);
  const float* lin5_w = in(30); const float* lin5_b = in(31);
  const float* lin6_w = in(32); const float* lin6_b = in(33);

  float* out = (float*)d_out;
  float* out_probs = out;
  float* out_dec1  = out_probs + 256;            // 3 x 4992*39 contiguous
  float* out_gt1   = out_dec1 + 3 * 4992 * 39;
  float* out_pred1 = out_gt1 + 4096;
  float* out_gt2   = out_pred1 + 4096;
  float* out_pred2 = out_gt2 + 3328;
  float* out_gt3   = out_pred2 + 3328;
  float* out_pred3 = out_gt3 + 2688;

  char* base = (char*)d_ws;
  size_t off = 0;
  auto allocf = [&](size_t n) -> float* {
    float* p = (float*)(base + off);
    off += ((n * sizeof(float) + 255) & ~(size_t)255);
    return p;
  };
  auto alloci = [&](size_t n) -> int* {
    int* p = (int*)(base + off);
    off += ((n * sizeof(int) + 255) & ~(size_t)255);
    return p;
  };
  auto allocs = [&](size_t n) -> short* {
    short* p = (short*)(base + off);
    off += ((n * sizeof(short) + 255) & ~(size_t)255);
    return p;
  };

  const size_t S = (size_t)4992 * 256;
  const size_t AB_S = (size_t)4992 * 512;
  const int SI = 4992 * KNN_;

  short* wt1h = allocs(512 * 64); short* wt1m = allocs(512 * 64); short* wt1l = allocs(512 * 64);
  short* wt2h = allocs(512 * 256); short* wt2m = allocs(512 * 256); short* wt2l = allocs(512 * 256);
  short* wt3h = allocs(512 * 256); short* wt3m = allocs(512 * 256); short* wt3l = allocs(512 * 256);
  short* wt6h = allocs(78 * 256);  short* wt6m = allocs(78 * 256);
  short* l4h = allocs(256 * 256);  short* l4m = allocs(256 * 256);
  short* l5h = allocs(128 * 256);  short* l5m = allocs(128 * 256);
  short* xsph = allocs(4992 * 64); short* xspm = allocs(4992 * 64); short* xspl = allocs(4992 * 64);
  float* deg  = allocf(4992);
  float* xdeg = allocf(4992);
  float* ysg  = allocf(4992);
  int* idxb = alloci(3 * SI);
  float* AB3 = allocf(3 * AB_S);
  float* trunk_t1 = allocf(S);
  float* scsh = allocf(512);
  float* tantg = allocf(4096);
  int* locsg = alloci(4096);
  short* xph = allocs((size_t)4096 * 256); short* xpm = allocs((size_t)4096 * 256); short* xpl = allocs((size_t)4096 * 256);
  size_t ms0 = off;
  short* xoutb_h = allocs(3 * S);
  short* xoutb_m = allocs(3 * S);
  size_t msz = off - ms0;
  short* t1b_h = allocs(3 * S);
  short* t1b_m = allocs(3 * S);
  float* adj1 = allocf(128 * 32 * 32);
  float* adj2 = allocf(128 * 26 * 26);
  int* perm1 = alloci(4096); int* perm2 = alloci(3328); int* perm3 = alloci(2688);
  float* z  = allocf(128 * 512);
  float* z1 = allocf(128 * 256);
  float* z2 = allocf(128 * 128);
  float* logits = allocf(256);
  if (off > ws_size) return;

  // t2b aliases xoutb (dead after decoder stage 1)
  short* t2b_h = xoutb_h; short* t2b_m = xoutb_m;

  const size_t LDS3 = 6 * 128 * 40 * sizeof(short);          // 61440 (>= knn 21.2KB)
  const size_t LDS2 = 4 * 128 * 40 * sizeof(short);          // 40960

  // ---- prep + zero scatter targets ----
  prep_kernel<<<dim3(1248, 8), 256, 0, stream>>>(
      w_mlp1, w_mlp2, w_mlp3, w_mlp6, lin4_w, lin5_w, x, adj,
      wt1h, wt1m, wt1l, wt2h, wt2m, wt2l, wt3h, wt3m, wt3l, wt6h, wt6m,
      l4h, l4m, l5h, l5m, xsph, xspm, xspl, deg);
  hipMemsetAsync(xoutb_h, 0, msz, stream);

  // ---- level 1: fused knn+gemm, then agg/bn/select/pool ----
  knn_gemm_kernel<<<B_ + 4 * 39, 512, LDS3, stream>>>(
      xsph, xspm, xspl, 3, 64, N_, 64, idxb, B_,
      xsph, xspm, xspl, 3, 64, wt1h, wt1m, wt1l, AB3, 4992, 512, 39, 0, 0);
  edge_agg_kernel<<<cdiv(4992 * 256, 256), 256, 0, stream>>>(AB3, b_mlp1, idxb, N_, 256, 0, 4992, 4992,
                                                             trunk_t1, nullptr, nullptr, nullptr);
  bn_stats_kernel<<<H_, 256, 0, stream>>>(trunk_t1, 4992, bn1_g, bn1_b, scsh);
  bnrowdot_kernel<<<cdiv(4992 * 64, 256), 256, 0, stream>>>(trunk_t1, scsh, p1_w, 4992, ysg);
  sag_select_kernel<<<B_, 256, 0, stream>>>(ysg, adj, N_, K1_, p1_b,
                                            perm1, tantg, locsg, adj1,
                                            nullptr, nullptr, nullptr, nullptr);
  pool_scatter_kernel<<<cdiv(B_ * K1_ * H_, 256), 256, 0, stream>>>(
      trunk_t1, scsh, tantg, locsg, nullptr, N_, K1_, xph, xpm, xpl, xoutb_h, xoutb_m);
  readout_kernel<<<cdiv(B_ * H_, 256), 256, 0, stream>>>(xph, xpm, xpl, K1_, 0, z);
  {  // degree head from x_out1
    dim3 g4(2, 39);
    mfma_gemm_split_kernel<<<g4, 256, 0, stream>>>(xoutb_h, xoutb_m, l4h, l4m, lin4_b,
                                                   trunk_t1, t1b_h, t1b_m, 4992, 256, 256, 1);
    dim3 g5(1, 39);
    mfma_gemm_split_kernel<<<g5, 256, 0, stream>>>(t1b_h, t1b_m, l5h, l5m, lin5_b,
                                                   AB3, nullptr, nullptr, 4992, 128, 256, 1);
  }
  rowdot_kernel<<<cdiv(4992 * 64, 256), 256, 0, stream>>>(AB3, lin6_w, 4992, 128, lin6_b, 1, xdeg);
  gtpred_kernel<<<cdiv(4096, 256), 256, 0, stream>>>(deg, xdeg, perm1, 4096, out_gt1, out_pred1);

  // ---- level 2 ----
  knn_gemm_kernel<<<B_ + 4 * 32, 512, LDS3, stream>>>(
      xph, xpm, xpl, 3, 256, K1_, 256, idxb, B_,
      xph, xpm, xpl, 3, 256, wt2h, wt2m, wt2l, AB3, 4096, 512, 32, 0, 0);
  edge_agg_kernel<<<cdiv(4096 * 256, 256), 256, 0, stream>>>(AB3, b_mlp2, idxb, K1_, 256, 0, 4096, 4096,
                                                             trunk_t1, nullptr, nullptr, nullptr);
  bn_stats_kernel<<<H_, 256, 0, stream>>>(trunk_t1, 4096, bn2_g, bn2_b, scsh);
  bnrowdot_kernel<<<cdiv(4096 * 64, 256), 256, 0, stream>>>(trunk_t1, scsh, p2_w, 4096, ysg);
  sag_select_kernel<<<B_, 256, 0, stream>>>(ysg, adj1, K1_, K2_, p2_b,
                                            perm2, tantg, locsg, adj2,
                                            deg, xdeg, out_gt2, out_pred2);
  pool_scatter_kernel<<<cdiv(B_ * K2_ * H_, 256), 256, 0, stream>>>(
      trunk_t1, scsh, tantg, locsg, perm1, K1_, K2_, xph, xpm, xpl, xoutb_h + S, xoutb_m + S);
  readout_kernel<<<cdiv(B_ * H_, 256), 256, 0, stream>>>(xph, xpm, xpl, K2_, 1, z);

  // ---- level 3 ----
  knn_gemm_kernel<<<B_ + 4 * 26, 512, LDS3, stream>>>(
      xph, xpm, xpl, 3, 256, K2_, 256, idxb, B_,
      xph, xpm, xpl, 3, 256, wt3h, wt3m, wt3l, AB3, 3328, 512, 26, 0, 0);
  edge_agg_kernel<<<cdiv(3328 * 256, 256), 256, 0, stream>>>(AB3, b_mlp3, idxb, K2_, 256, 0, 3328, 3328,
                                                             trunk_t1, nullptr, nullptr, nullptr);
  bn_stats_kernel<<<H_, 256, 0, stream>>>(trunk_t1, 3328, bn3_g, bn3_b, scsh);
  bnrowdot_kernel<<<cdiv(3328 * 64, 256), 256, 0, stream>>>(trunk_t1, scsh, p3_w, 3328, ysg);
  sag_select_kernel<<<B_, 256, 0, stream>>>(ysg, adj2, K2_, K3_, p3_b,
                                            perm3, tantg, locsg, nullptr,
                                            deg, xdeg, out_gt3, out_pred3);
  pool_scatter_kernel<<<cdiv(B_ * K3_ * H_, 256), 256, 0, stream>>>(
      trunk_t1, scsh, tantg, locsg, perm2, K2_, K3_, xph, xpm, xpl, xoutb_h + 2 * S, xoutb_m + 2 * S);
  readout_kernel<<<cdiv(B_ * H_, 256), 256, 0, stream>>>(xph, xpm, xpl, K3_, 1, z);

  // ---- classifier head ----
  rowgemm_kernel<<<128, 256, 0, stream>>>(z, lin1_w, lin1_b, z1, 256, 512, 1);
  rowgemm_kernel<<<128, 256, 0, stream>>>(z1, lin2_w, lin2_b, z2, 128, 256, 1);
  wavedot_gemm_kernel<<<cdiv(128 * 2 * 64, 256), 256, 0, stream>>>(z2, lin3_w, lin3_b, logits, 128, 2, 128, 0);
  softmax2_kernel<<<1, 128, 0, stream>>>(logits, out_probs);

  // ---- batched decoders (3 independent; fused knn+gemm per stage) ----
  // stage 1: wcat3, tanh
  knn_gemm_kernel<<<3 * B_ + 4 * 39 * 3, 512, LDS2, stream>>>(
      xoutb_h, xoutb_m, nullptr, 2, 256, N_, 256, idxb, 3 * B_,
      xoutb_h, xoutb_m, nullptr, 2, 256, wt3h, wt3m, nullptr, AB3, 4992, 512, 39, S, AB_S);
  edge_agg_kernel<<<cdiv(3 * 4992 * 256, 256), 256, 0, stream>>>(
      AB3, b_mlp3, idxb, N_, 256, 2, 3 * 4992, 4992, nullptr, t1b_h, t1b_m, nullptr);
  // stage 2: wcat2, tanh
  knn_gemm_kernel<<<3 * B_ + 4 * 39 * 3, 512, LDS2, stream>>>(
      t1b_h, t1b_m, nullptr, 2, 256, N_, 256, idxb, 3 * B_,
      t1b_h, t1b_m, nullptr, 2, 256, wt2h, wt2m, nullptr, AB3, 4992, 512, 39, S, AB_S);
  edge_agg_kernel<<<cdiv(3 * 4992 * 256, 256), 256, 0, stream>>>(
      AB3, b_mlp2, idxb, N_, 256, 2, 3 * 4992, 4992, nullptr, t2b_h, t2b_m, nullptr);
  // stage 3: wcat6, linear -> out_dec
  knn_gemm_kernel<<<3 * B_ + 1 * 39 * 3, 512, LDS2, stream>>>(
      t2b_h, t2b_m, nullptr, 2, 256, N_, 256, idxb, 3 * B_,
      t2b_h, t2b_m, nullptr, 2, 256, wt6h, wt6m, nullptr, AB3, 4992, 78, 39, S, (size_t)4992 * 78);
  edge_agg_kernel<<<cdiv(3 * 4992 * 39, 256), 256, 0, stream>>>(
      AB3, b_mlp6, idxb, N_, 39, 0, 3 * 4992, 4992, out_dec1, nullptr, nullptr, nullptr);
}